// Round 4
// baseline (801.792 us; speedup 1.0000x reference)
//
#include <hip/hip_runtime.h>
#include <math.h>

#define T_TOK 4096
#define HD    2048
#define NEXP  32
#define IR    1408
#define ISH   2816
#define NPAIR (T_TOK*4)
#define SRK   136      // padded bf16 row stride (cold paths only)
#define MTILES 11      // I-tiles (of 64) per chunk: routed 2 chunks, shared 4

typedef unsigned short ushort_t;
typedef __attribute__((ext_vector_type(8))) short    short8;
typedef __attribute__((ext_vector_type(8))) __bf16   bf16x8;
typedef __attribute__((ext_vector_type(4))) float    f32x4;

__device__ __forceinline__ f32x4 MF(short8 a, short8 b, f32x4 c) {
  return __builtin_amdgcn_mfma_f32_16x16x32_bf16(
      __builtin_bit_cast(bf16x8, a), __builtin_bit_cast(bf16x8, b), c, 0, 0, 0);
}
__device__ __forceinline__ ushort_t f2b(float f) {
  unsigned u = __float_as_uint(f);
  unsigned r = (u + 0x7fffu + ((u >> 16) & 1u)) >> 16;   // RNE
  return (ushort_t)r;
}
__device__ __forceinline__ float b2f(ushort_t b) {
  return __uint_as_float(((unsigned)b) << 16);
}

// async global->LDS 16B; LDS dst must be wave-uniform base (+lane*16 implicit)
__device__ __forceinline__ void gll16(const ushort_t* g, ushort_t* l) {
  __builtin_amdgcn_global_load_lds(
      (const __attribute__((address_space(1))) unsigned int*)(const void*)g,
      (__attribute__((address_space(3))) unsigned int*)(void*)l, 16, 0, 0);
}

// ---- swizzled tile loader (XOR swizzle: phys chunk = logical ^ (row&mask)) ----
// 64 rows x 128 cols bf16 (16 chunks/row). One instr = 4 rows.
__device__ __forceinline__ void load_64x128_swz(
    const ushort_t* __restrict__ g, size_t gstride, ushort_t* lds, int tid)
{
  const int lane = tid & 63, w = tid >> 6;
  #pragma unroll
  for (int s = 0; s < 4; ++s) {
    int rbase = s*16 + w*4;
    int r = rbase + (lane >> 4);
    int p = lane & 15;
    gll16(g + (size_t)r*gstride + ((p ^ (r & 15)) << 3), lds + rbase*128);
  }
}
// read elem(row r, chunk c of 8hw): lds[r*128 + ((c^(r&15))<<3)]

// ---------------------------------------------------------------- fused cvt
#define NSEG 19
struct CvtSegs {
  const float* s[NSEG];
  ushort_t* d[NSEG];
  int n4[NSEG];
  int blk0[NSEG+1];
};
__global__ __launch_bounds__(256) void cvt_all_kernel(CvtSegs cs)
{
  int b = blockIdx.x;
  int k = 0;
  #pragma unroll 1
  while (k+1 < NSEG && b >= cs.blk0[k+1]) ++k;
  int i = (b - cs.blk0[k])*256 + threadIdx.x;
  if (i < cs.n4[k]) {
    float4 v = ((const float4*)cs.s[k])[i];
    ushort4 o; o.x=f2b(v.x); o.y=f2b(v.y); o.z=f2b(v.z); o.w=f2b(v.w);
    ((ushort4*)cs.d[k])[i] = o;
  }
}

// ---------------------------------------------------------------- gate
// 4 tokens/block (4 waves); gw staged through LDS per 128-k chunk.
__global__ __launch_bounds__(256) void gate_kernel(
    const float* __restrict__ x, const float* __restrict__ gw,
    int* __restrict__ topk_idx, float* __restrict__ topk_w, int* __restrict__ cnt)
{
  __shared__ float gws[32*132];
  __shared__ float xs[4*132];
  const int tid = threadIdx.x;
  const int w = tid >> 6, lane = tid & 63;
  const int t0 = blockIdx.x * 4;
  const int e = lane & 31, half = lane >> 5;

  float acc = 0.f;
  for (int ck = 0; ck < HD/128; ++ck) {
    for (int li = tid; li < 1024; li += 256) {        // gw chunk 32x128
      int r = li >> 5, c4 = li & 31;
      *(float4*)(gws + r*132 + c4*4) = *(const float4*)(gw + (size_t)r*HD + ck*128 + c4*4);
    }
    for (int li = tid; li < 128; li += 256) {          // x chunk 4x128
      int r = li >> 5, c4 = li & 31;
      *(float4*)(xs + r*132 + c4*4) = *(const float4*)(x + (size_t)(t0+r)*HD + ck*128 + c4*4);
    }
    __syncthreads();
    #pragma unroll
    for (int k4 = 0; k4 < 16; ++k4) {
      float4 xv = *(const float4*)(xs + w*132 + half*64 + k4*4);
      float4 wv = *(const float4*)(gws + e*132 + half*64 + k4*4);
      acc += xv.x*wv.x + xv.y*wv.y + xv.z*wv.z + xv.w*wv.w;
    }
    __syncthreads();
  }
  float p = acc;
  p += __shfl_down(p, 32);
  float logit = (lane < 32) ? p : -INFINITY;
  float m = logit;
  #pragma unroll
  for (int o = 32; o >= 1; o >>= 1) m = fmaxf(m, __shfl_xor(m, o));
  float ex = (lane < 32) ? expf(logit - m) : 0.f;
  float se = ex;
  #pragma unroll
  for (int o = 32; o >= 1; o >>= 1) se += __shfl_xor(se, o);
  float score = ex / se;

  bool taken = false;
  float selw[4]; int seli[4];
  for (int k = 0; k < 4; ++k) {
    float cur = (lane < 32 && !taken) ? score : -1.f;
    float mm = cur;
    #pragma unroll
    for (int o = 32; o >= 1; o >>= 1) mm = fmaxf(mm, __shfl_xor(mm, o));
    unsigned long long b = __ballot(cur == mm);
    int il = __ffsll(b) - 1;
    if (lane == il) taken = true;
    selw[k] = mm; seli[k] = il;
  }
  float wsum = selw[0]+selw[1]+selw[2]+selw[3] + 1e-20f;
  int t = t0 + w;
  if (lane < 4) {
    topk_idx[t*4+lane] = seli[lane];
    topk_w[t*4+lane]  = selw[lane] / wsum;
    atomicAdd(&cnt[seli[lane]], 1);
  }
}

__global__ void scan_kernel(const int* __restrict__ cnt, int* __restrict__ offA)
{
  if (threadIdx.x == 0) {
    int a = 0;
    for (int e = 0; e < NEXP; ++e) { offA[e] = a; a += cnt[e]; }
    offA[NEXP] = a;
  }
}

__global__ __launch_bounds__(256) void scatter_kernel(
    const int* __restrict__ topk_idx, const float* __restrict__ topk_w,
    const int* __restrict__ offA, int* __restrict__ fill,
    int* __restrict__ list_tok, int* __restrict__ slot_of)
{
  int t = blockIdx.x*256 + threadIdx.x;
  if (t >= T_TOK) return;
  #pragma unroll
  for (int k = 0; k < 4; ++k) {
    int e = topk_idx[t*4+k];
    int pos = atomicAdd(&fill[e], 1);
    int s = offA[e] + pos;
    list_tok[s] = t;
    slot_of[t*4+k] = s;     // inverse map for non-atomic combine
  }
}

// ------------------------------------------------- R projections (pipelined)
// Y[T,128] = Xb[T,2048] @ W[128,2048]^T. A via gll dbuf; B-frags from global (L2-hot).
__global__ __launch_bounds__(256) void rproj_kernel(
    const ushort_t* __restrict__ xb,
    const ushort_t* __restrict__ Rg, const ushort_t* __restrict__ Ru,
    const ushort_t* __restrict__ sRg, const ushort_t* __restrict__ sRu,
    ushort_t* __restrict__ rg, ushort_t* __restrict__ ru,
    ushort_t* __restrict__ sa, ushort_t* __restrict__ su)
{
  __shared__ ushort_t abuf[2][64*128];
  const ushort_t* W; ushort_t* Y;
  switch (blockIdx.y) {
    case 0:  W = Rg;  Y = rg; break;
    case 1:  W = Ru;  Y = ru; break;
    case 2:  W = sRg; Y = sa; break;
    default: W = sRu; Y = su; break;
  }
  const int tid = threadIdx.x;
  const int lane = tid & 63, ln = lane & 15, q = lane >> 4;
  const int wv = tid >> 6, mh = wv >> 1, nh = wv & 1;
  const int r0 = blockIdx.x * 64;

  f32x4 acc[2][4];
  #pragma unroll
  for (int i = 0; i < 2; ++i)
    #pragma unroll
    for (int j = 0; j < 4; ++j) acc[i][j] = (f32x4){0.f,0.f,0.f,0.f};

  load_64x128_swz(xb + (size_t)r0*HD, HD, abuf[0], tid);
  for (int kt = 0; kt < 16; ++kt) {
    __syncthreads();                       // abuf[kt&1] ready
    if (kt+1 < 16)
      load_64x128_swz(xb + (size_t)r0*HD + (kt+1)*128, HD, abuf[(kt+1)&1], tid);
    const ushort_t* A = abuf[kt&1];
    #pragma unroll
    for (int c = 0; c < 4; ++c) {
      short8 a[2], b[4];
      #pragma unroll
      for (int i = 0; i < 2; ++i) {
        int rr = mh*32 + i*16 + ln;
        a[i] = *(const short8*)(A + rr*128 + (((c*4+q) ^ (rr&15)) << 3));
      }
      #pragma unroll
      for (int j = 0; j < 4; ++j)
        b[j] = *(const short8*)(W + (size_t)(nh*64 + j*16 + ln)*HD + kt*128 + c*32 + q*8);
      #pragma unroll
      for (int i = 0; i < 2; ++i)
        #pragma unroll
        for (int j = 0; j < 4; ++j) acc[i][j] = MF(a[i], b[j], acc[i][j]);
    }
  }
  #pragma unroll
  for (int i = 0; i < 2; ++i)
    #pragma unroll
    for (int j = 0; j < 4; ++j)
      #pragma unroll
      for (int r = 0; r < 4; ++r)
        Y[(size_t)(r0 + mh*32 + i*16 + q*4 + r)*128 + nh*64 + j*16 + ln] = f2b(acc[i][j][r]);
}

// -------- helper (cold path): acc = A_lds[64][SRK] @ Wg[128][128]^T, C in regs
__device__ __forceinline__ void gemm64x128_regs(
    int tid, const ushort_t* __restrict__ A, const ushort_t* __restrict__ Wg,
    ushort_t* __restrict__ stage, f32x4 acc[2][2][2])
{
  const int lane = tid & 63, ln = lane & 15, q = lane >> 4;
  const int wv = tid >> 6, mh = wv >> 1, nh = wv & 1;
  #pragma unroll
  for (int h = 0; h < 2; ++h)
    #pragma unroll
    for (int i = 0; i < 2; ++i)
      #pragma unroll
      for (int j = 0; j < 2; ++j) acc[h][i][j] = (f32x4){0.f,0.f,0.f,0.f};
  for (int h = 0; h < 2; ++h) {
    for (int li = tid; li < 64*16; li += 256) {
      int r = li >> 4, c = (li & 15) << 3;
      *(short8*)(stage + r*SRK + c) = *(const short8*)(Wg + (size_t)(h*64 + r)*128 + c);
    }
    __syncthreads();
    #pragma unroll
    for (int c = 0; c < 4; ++c) {
      short8 a[2], b[2];
      #pragma unroll
      for (int i = 0; i < 2; ++i)
        a[i] = *(const short8*)(A + (mh*32 + i*16 + ln)*SRK + c*32 + q*8);
      #pragma unroll
      for (int j = 0; j < 2; ++j)
        b[j] = *(const short8*)(stage + (nh*32 + j*16 + ln)*SRK + c*32 + q*8);
      #pragma unroll
      for (int i = 0; i < 2; ++i)
        #pragma unroll
        for (int j = 0; j < 2; ++j) acc[h][i][j] = MF(a[i], b[j], acc[h][i][j]);
    }
    __syncthreads();
  }
}

// ---------------------------------------------------------------- pair_proj
// t1[slot] = rg[tok(slot)] @ Ug_e^T ; t2 = ru @ Uu_e^T ; shared rows direct.
__global__ __launch_bounds__(256) void pair_proj_kernel(
    const ushort_t* __restrict__ rgb, const ushort_t* __restrict__ rub,
    const ushort_t* __restrict__ sab, const ushort_t* __restrict__ sub,
    const ushort_t* __restrict__ Ug, const ushort_t* __restrict__ Uu,
    const ushort_t* __restrict__ sUg, const ushort_t* __restrict__ sUu,
    const int* __restrict__ offA, const int* __restrict__ cntA,
    const int* __restrict__ list_tok,
    ushort_t* __restrict__ t1R, ushort_t* __restrict__ t2R,
    ushort_t* __restrict__ t1S, ushort_t* __restrict__ t2S)
{
  __shared__ ushort_t ldsX[64*SRK];
  __shared__ ushort_t stage[64*SRK];
  __shared__ int toks[64];
  const int tid = threadIdx.x;
  const int by = blockIdx.y;
  const bool shm = (by == NEXP);
  const int nrows = shm ? T_TOK : cntA[by];
  const int s0 = blockIdx.x * 64;
  if (s0 >= nrows) return;
  const int base = shm ? 0 : offA[by];
  const ushort_t* pUg = shm ? sUg : Ug + (size_t)by*128*128;
  const ushort_t* pUu = shm ? sUu : Uu + (size_t)by*128*128;
  const int lane = tid & 63, ln = lane & 15, q = lane >> 4;
  const int wv = tid >> 6, mh = wv >> 1, nh = wv & 1;

  if (tid < 64) {
    int sc = s0 + tid; if (sc > nrows-1) sc = nrows-1;
    toks[tid] = shm ? sc : list_tok[base + sc];
  }
  __syncthreads();

  f32x4 acc[2][2][2];
  // t1
  for (int li = tid; li < 64*16; li += 256) {
    int r = li >> 4, c = (li & 15) << 3;
    const ushort_t* src = shm ? sab : rgb;
    *(short8*)(ldsX + r*SRK + c) = *(const short8*)(src + (size_t)toks[r]*128 + c);
  }
  __syncthreads();
  gemm64x128_regs(tid, ldsX, pUg, stage, acc);
  {
    ushort_t* dst = shm ? t1S : (t1R + (size_t)base*128);
    #pragma unroll
    for (int h = 0; h < 2; ++h)
      #pragma unroll
      for (int i = 0; i < 2; ++i)
        #pragma unroll
        for (int r = 0; r < 4; ++r) {
          int gs = s0 + mh*32 + i*16 + q*4 + r;
          if (gs < nrows) {
            #pragma unroll
            for (int j = 0; j < 2; ++j)
              dst[(size_t)gs*128 + h*64 + nh*32 + j*16 + ln] = f2b(acc[h][i][j][r]);
          }
        }
  }
  // t2
  for (int li = tid; li < 64*16; li += 256) {
    int r = li >> 4, c = (li & 15) << 3;
    const ushort_t* src = shm ? sub : rub;
    *(short8*)(ldsX + r*SRK + c) = *(const short8*)(src + (size_t)toks[r]*128 + c);
  }
  __syncthreads();
  gemm64x128_regs(tid, ldsX, pUu, stage, acc);
  {
    ushort_t* dst = shm ? t2S : (t2R + (size_t)base*128);
    #pragma unroll
    for (int h = 0; h < 2; ++h)
      #pragma unroll
      for (int i = 0; i < 2; ++i)
        #pragma unroll
        for (int r = 0; r < 4; ++r) {
          int gs = s0 + mh*32 + i*16 + q*4 + r;
          if (gs < nrows) {
            #pragma unroll
            for (int j = 0; j < 2; ++j)
              dst[(size_t)gs*128 + h*64 + nh*32 + j*16 + ln] = f2b(acc[h][i][j][r]);
          }
        }
  }
}

// ---------------------------------------------------------------- mid (v3 hybrid)
// grid (64, 33, 4). Cg/Cu gll-staged in LDS (latency amortized over whole tile,
// as in the 137us version); Rd B-frags DIRECT from global (Rd is 360KB shared
// across all routed experts -> chip-wide L2-resident; only 8 loads/wave/tile).
// Dropping ldsRd cuts LDS 56->40KB -> 4 blocks/CU (was 2). XCD swizzle (proven
// in r2: FETCH 111->30MB) makes the gll drains L2-latency instead of HBM.
__global__ __launch_bounds__(256, 4) void mid_kernel(
    const ushort_t* __restrict__ t1R, const ushort_t* __restrict__ t2R,
    const ushort_t* __restrict__ t1S, const ushort_t* __restrict__ t2S,
    const ushort_t* __restrict__ Cg, const ushort_t* __restrict__ Cu,
    const ushort_t* __restrict__ Rd,
    const ushort_t* __restrict__ sCg, const ushort_t* __restrict__ sCu,
    const ushort_t* __restrict__ sRd,
    const int* __restrict__ offA, const int* __restrict__ cntA,
    float* __restrict__ rdRp, float* __restrict__ rdSp)
{
  __shared__ ushort_t ldsCg[64*128];   // 16 KB
  __shared__ ushort_t ldsCu[64*128];   // 16 KB
  __shared__ ushort_t ldsH [64*64];    //  8 KB

  // XCD swizzle: 64*33*4 = 8448, 8448/8 = 1056 (bijective).
  const int hh = blockIdx.x + 64*(blockIdx.y + 33*blockIdx.z);
  const int L = (hh & 7) * 1056 + (hh >> 3);
  const int bx  = L & 63;
  const int rem = L >> 6;          // 0..131
  const int by  = rem % 33;
  const int bz  = rem / 33;

  const bool shm = (by == NEXP);
  if (bz >= (shm ? 4 : 2)) return;
  const int nrows = shm ? T_TOK : cntA[by];
  const int s0 = bx * 64;
  if (s0 >= nrows) return;
  const int base = shm ? 0 : offA[by];
  const int Ifull = shm ? ISH : IR;
  const ushort_t* pCg = shm ? sCg : Cg + (size_t)by*IR*128;
  const ushort_t* pCu = shm ? sCu : Cu + (size_t)by*IR*128;
  const ushort_t* pRd = shm ? sRd : Rd;

  const int tid = threadIdx.x;
  const int lane = tid & 63, ln = lane & 15, q = lane >> 4;
  const int wv = tid >> 6, mh = wv >> 1, nh = wv & 1;
  const int it0 = bz * MTILES;

  // t1/t2 A-fragments -> registers (held across the whole K loop)
  short8 t1f[2][4], t2f[2][4];
  const ushort_t* srcT1 = shm ? t1S : (t1R + (size_t)base*128);
  const ushort_t* srcT2 = shm ? t2S : (t2R + (size_t)base*128);
  #pragma unroll
  for (int i = 0; i < 2; ++i) {
    int r = s0 + mh*32 + i*16 + ln; if (r > nrows-1) r = nrows-1;
    #pragma unroll
    for (int c = 0; c < 4; ++c) {
      t1f[i][c] = *(const short8*)(srcT1 + (size_t)r*128 + c*32 + q*8);
      t2f[i][c] = *(const short8*)(srcT2 + (size_t)r*128 + c*32 + q*8);
    }
  }

  load_64x128_swz(pCg + (size_t)it0*64*128, 128, ldsCg, tid);
  load_64x128_swz(pCu + (size_t)it0*64*128, 128, ldsCu, tid);

  f32x4 rdacc[2][4];
  #pragma unroll
  for (int i = 0; i < 2; ++i)
    #pragma unroll
    for (int j = 0; j < 4; ++j) rdacc[i][j] = (f32x4){0.f,0.f,0.f,0.f};

  // invariant per-lane Rd offset: row (nh*64+ln), chunk q
  const size_t rdRow = (size_t)(nh*64 + ln)*Ifull + q*8;   // + j*16*Ifull + i0 + c2*32

  __syncthreads();   // Cg/Cu tile 0 ready (gll drained by barrier)

  for (int it = 0; it < MTILES; ++it) {
    const int i0 = (it0 + it) * 64;
    // phase A: g,u MFMA from regs x ldsCg/Cu; silu; h -> ldsH
    f32x4 g[2][2], u[2][2];
    #pragma unroll
    for (int i = 0; i < 2; ++i)
      #pragma unroll
      for (int j = 0; j < 2; ++j) { g[i][j] = (f32x4){0.f,0.f,0.f,0.f}; u[i][j] = (f32x4){0.f,0.f,0.f,0.f}; }
    #pragma unroll
    for (int c = 0; c < 4; ++c) {
      #pragma unroll
      for (int j = 0; j < 2; ++j) {
        int rr = nh*32 + j*16 + ln;
        int off = rr*128 + (((c*4+q) ^ (rr&15)) << 3);
        short8 bg = *(const short8*)(ldsCg + off);
        short8 bu = *(const short8*)(ldsCu + off);
        #pragma unroll
        for (int i = 0; i < 2; ++i) {
          g[i][j] = MF(t1f[i][c], bg, g[i][j]);
          u[i][j] = MF(t2f[i][c], bu, u[i][j]);
        }
      }
    }
    #pragma unroll
    for (int i = 0; i < 2; ++i)
      #pragma unroll
      for (int j = 0; j < 2; ++j)
        #pragma unroll
        for (int r = 0; r < 4; ++r) {
          float gv = g[i][j][r];
          gv = gv / (1.f + __expf(-gv));
          float hv = gv * u[i][j][r];
          int hr = mh*32 + i*16 + q*4 + r;
          int hc = nh*32 + j*16 + ln;
          ldsH[hr*64 + (((hc>>3) ^ (hr&7)) << 3) + (hc&7)] = f2b(hv);
        }
    __syncthreads();   // h visible; all Cg/Cu reads done
    // phase B: issue Cg/Cu(it+1) gll (overwrite safe); rd += h @ Rd^T (Rd direct)
    if (it+1 < MTILES) {
      load_64x128_swz(pCg + (size_t)(i0+64)*128, 128, ldsCg, tid);
      load_64x128_swz(pCu + (size_t)(i0+64)*128, 128, ldsCu, tid);
    }
    #pragma unroll
    for (int c2 = 0; c2 < 2; ++c2) {
      short8 a[2];
      #pragma unroll
      for (int i = 0; i < 2; ++i) {
        int rr = mh*32 + i*16 + ln;
        a[i] = *(const short8*)(ldsH + rr*64 + (((c2*4+q) ^ (rr&7)) << 3));
      }
      #pragma unroll
      for (int j = 0; j < 4; ++j) {
        short8 b = *(const short8*)(pRd + rdRow + (size_t)(j*16)*Ifull + i0 + c2*32);
        #pragma unroll
        for (int i = 0; i < 2; ++i) rdacc[i][j] = MF(a[i], b, rdacc[i][j]);
      }
    }
    __syncthreads();   // Cg/Cu(it+1) landed; ldsH reads done
  }

  // plain disjoint stores (no atomics): part bz of 2 (routed) or 4 (shared)
  float* dst = shm ? (rdSp + (size_t)bz*T_TOK*128)
                   : (rdRp + (size_t)bz*NPAIR*128 + (size_t)base*128);
  #pragma unroll
  for (int i = 0; i < 2; ++i) {
    #pragma unroll
    for (int r = 0; r < 4; ++r) {
      int gs = s0 + mh*32 + i*16 + q*4 + r;
      if (gs < nrows) {
        #pragma unroll
        for (int j = 0; j < 4; ++j)
          dst[(size_t)gs*128 + nh*64 + j*16 + ln] = rdacc[i][j][r];
      }
    }
  }
}

// ---------------------------------------------------------------- out
// grid (64, 33, 2). t3 frags in regs; Cd double-buffered via gll; 1 barrier/tile.
// XCD swizzle for Cd L2 locality. NO atomics: routed y -> ybufR (bf16, per-slot,
// unweighted); shared y -> out directly (fp32 plain stores; sole writer).
__global__ __launch_bounds__(256) void out_kernel(
    const float* __restrict__ rdRp, const float* __restrict__ rdSp,
    const ushort_t* __restrict__ Ud, const ushort_t* __restrict__ Cd,
    const ushort_t* __restrict__ sUd, const ushort_t* __restrict__ sCd,
    const int* __restrict__ offA, const int* __restrict__ cntA,
    ushort_t* __restrict__ ybufR, float* __restrict__ out)
{
  __shared__ ushort_t smem[3*64*SRK];   // prologue: ldsA | stage | ldsT ; loop: cd0,cd1
  ushort_t* ldsA  = smem;
  ushort_t* stage = smem + 64*SRK;
  ushort_t* ldsT  = smem + 2*64*SRK;
  ushort_t* cd0   = smem;
  ushort_t* cd1   = smem + 64*128;

  // XCD swizzle: 64*33*2 = 4224, 4224/8 = 528 (bijective).
  const int hh = blockIdx.x + 64*(blockIdx.y + 33*blockIdx.z);
  const int L = (hh & 7) * 528 + (hh >> 3);
  const int bx  = L & 63;
  const int rem = L >> 6;          // 0..65
  const int by  = rem % 33;
  const int bzz = rem / 33;

  const int tid = threadIdx.x;
  const bool shm = (by == NEXP);
  const int nrows = shm ? T_TOK : cntA[by];
  const int s0 = bx * 64;
  if (s0 >= nrows) return;
  const int base = shm ? 0 : offA[by];
  const int ct0 = bzz * 16;
  const ushort_t* pUd = shm ? sUd : Ud + (size_t)by*128*128;
  const ushort_t* pCd = shm ? sCd : Cd + (size_t)by*HD*128;

  const int lane = tid & 63, ln = lane & 15, q = lane >> 4;
  const int wv = tid >> 6, mh = wv >> 1, nh = wv & 1;

  // gather rd rows: sum the per-bz partials (fp32) -> bf16 ldsA
  for (int li = tid; li < 64*32; li += 256) {
    int r = li >> 5, c4 = li & 31;
    int row = s0 + r; if (row > nrows-1) row = nrows-1;
    float4 v;
    if (shm) {
      const float* p = rdSp + (size_t)row*128 + c4*4;
      v = *(const float4*)p;
      #pragma unroll
      for (int pp = 1; pp < 4; ++pp) {
        float4 w2 = *(const float4*)(p + (size_t)pp*T_TOK*128);
        v.x += w2.x; v.y += w2.y; v.z += w2.z; v.w += w2.w;
      }
    } else {
      const float* p = rdRp + (size_t)(base+row)*128 + c4*4;
      v = *(const float4*)p;
      float4 w2 = *(const float4*)(p + (size_t)NPAIR*128);
      v.x += w2.x; v.y += w2.y; v.z += w2.z; v.w += w2.w;
    }
    ushort4 o; o.x=f2b(v.x); o.y=f2b(v.y); o.z=f2b(v.z); o.w=f2b(v.w);
    *(ushort4*)(ldsA + r*SRK + c4*4) = o;
  }
  __syncthreads();

  f32x4 acc[2][2][2];
  gemm64x128_regs(tid, ldsA, pUd, stage, acc);
  // C -> ldsT (padded), then extract A-frags
  #pragma unroll
  for (int h = 0; h < 2; ++h)
    #pragma unroll
    for (int i = 0; i < 2; ++i)
      #pragma unroll
      for (int j = 0; j < 2; ++j)
        #pragma unroll
        for (int r = 0; r < 4; ++r)
          ldsT[(mh*32 + i*16 + q*4 + r)*SRK + h*64 + nh*32 + j*16 + ln] = f2b(acc[h][i][j][r]);
  __syncthreads();
  short8 t3f[2][4];
  #pragma unroll
  for (int i = 0; i < 2; ++i)
    #pragma unroll
    for (int c = 0; c < 4; ++c)
      t3f[i][c] = *(const short8*)(ldsT + (mh*32 + i*16 + ln)*SRK + c*32 + q*8);
  __syncthreads();   // smem free for cd buffers

  load_64x128_swz(pCd + (size_t)ct0*64*128, 128, cd0, tid);
  for (int tt = 0; tt < 16; ++tt) {
    __syncthreads();                      // cd[tt&1] ready; prior reads drained
    ushort_t* cur = (tt & 1) ? cd1 : cd0;
    ushort_t* nxt = (tt & 1) ? cd0 : cd1;
    if (tt+1 < 16)
      load_64x128_swz(pCd + (size_t)(ct0+tt+1)*64*128, 128, nxt, tid);
    f32x4 y[2][2];
    #pragma unroll
    for (int i = 0; i < 2; ++i)
      #pragma unroll
      for (int j = 0; j < 2; ++j) y[i][j] = (f32x4){0.f,0.f,0.f,0.f};
    #pragma unroll
    for (int c = 0; c < 4; ++c) {
      #pragma unroll
      for (int j = 0; j < 2; ++j) {
        int rr = nh*32 + j*16 + ln;
        short8 b = *(const short8*)(cur + rr*128 + (((c*4+q) ^ (rr&15)) << 3));
        #pragma unroll
        for (int i = 0; i < 2; ++i) y[i][j] = MF(t3f[i][c], b, y[i][j]);
      }
    }
    #pragma unroll
    for (int i = 0; i < 2; ++i) {
      #pragma unroll
      for (int r = 0; r < 4; ++r) {
        int lr = mh*32 + i*16 + q*4 + r;
        int gs = s0 + lr;
        if (gs < nrows) {
          if (shm) {
            size_t ob = (size_t)gs*HD + (ct0 + tt)*64;
            #pragma unroll
            for (int j = 0; j < 2; ++j)
              out[ob + nh*32 + j*16 + ln] = y[i][j][r];
          } else {
            size_t ob = (size_t)(base + gs)*HD + (ct0 + tt)*64;
            #pragma unroll
            for (int j = 0; j < 2; ++j)
              ybufR[ob + nh*32 + j*16 + ln] = f2b(y[i][j][r]);
          }
        }
      }
    }
  }
}

// ---------------------------------------------------------------- combine
// out[t] = out[t] (shared, already stored) + sum_k w_k * ybufR[slot_of[t,k]]
// One block per token row; fully coalesced, no atomics.
__global__ __launch_bounds__(256) void combine_kernel(
    const ushort_t* __restrict__ ybufR,
    const int* __restrict__ slot_of, const float* __restrict__ topk_w,
    float* __restrict__ out)
{
  __shared__ int   ss[4];
  __shared__ float ww[4];
  const int t = blockIdx.x;
  if (threadIdx.x < 4) {
    ss[threadIdx.x] = slot_of[t*4 + threadIdx.x];
    ww[threadIdx.x] = topk_w[t*4 + threadIdx.x];
  }
  __syncthreads();
  const int c = threadIdx.x * 8;
  const size_t tb = (size_t)t*HD + c;
  float o[8];
  float4 a0 = *(const float4*)(out + tb);
  float4 a1 = *(const float4*)(out + tb + 4);
  o[0]=a0.x; o[1]=a0.y; o[2]=a0.z; o[3]=a0.w;
  o[4]=a1.x; o[5]=a1.y; o[6]=a1.z; o[7]=a1.w;
  #pragma unroll
  for (int k = 0; k < 4; ++k) {
    short8 rv = *(const short8*)(ybufR + (size_t)ss[k]*HD + c);
    float wk = ww[k];
    #pragma unroll
    for (int u = 0; u < 8; ++u)
      o[u] += wk * b2f((ushort_t)rv[u]);
  }
  float4 b0 = {o[0],o[1],o[2],o[3]};
  float4 b1 = {o[4],o[5],o[6],o[7]};
  *(float4*)(out + tb)     = b0;
  *(float4*)(out + tb + 4) = b1;
}

// ---------------------------------------------------------------- launch
extern "C" void kernel_launch(void* const* d_in, const int* in_sizes, int n_in,
                              void* d_out, int out_size, void* d_ws, size_t ws_size,
                              hipStream_t stream) {
  const float* x    = (const float*)d_in[0];
  const float* gw   = (const float*)d_in[1];
  const float* Rg   = (const float*)d_in[2];
  const float* Ru   = (const float*)d_in[3];
  const float* Rd   = (const float*)d_in[4];
  const float* Ug   = (const float*)d_in[5];
  const float* Cg   = (const float*)d_in[6];
  const float* Uu   = (const float*)d_in[7];
  const float* Cu   = (const float*)d_in[8];
  const float* Ud   = (const float*)d_in[9];
  const float* Cd   = (const float*)d_in[10];
  const float* sRg  = (const float*)d_in[11];
  const float* sUg  = (const float*)d_in[12];
  const float* sCg  = (const float*)d_in[13];
  const float* sRu  = (const float*)d_in[14];
  const float* sUu  = (const float*)d_in[15];
  const float* sCu  = (const float*)d_in[16];
  const float* sRd  = (const float*)d_in[17];
  const float* sUd  = (const float*)d_in[18];
  const float* sCd  = (const float*)d_in[19];
  float* out = (float*)d_out;

  char* w = (char*)d_ws;
  auto alloc = [&](size_t bytes) -> void* {
    void* p = (void*)w; w += (bytes + 255) & ~(size_t)255; return p;
  };
  int*   cnt      = (int*)  alloc(NEXP*sizeof(int));
  int*   offA     = (int*)  alloc((NEXP+1)*sizeof(int));
  int*   fill     = (int*)  alloc(NEXP*sizeof(int));
  int*   topk_idx = (int*)  alloc((size_t)T_TOK*4*sizeof(int));
  float* topk_w   = (float*)alloc((size_t)T_TOK*4*sizeof(float));
  int*   list_tok = (int*)  alloc((size_t)NPAIR*sizeof(int));
  int*   slot_of  = (int*)  alloc((size_t)T_TOK*4*sizeof(int));
  ushort_t* xb   = (ushort_t*)alloc((size_t)T_TOK*HD*2);   // later reused as rdRp (fp32, 2 parts)
  ushort_t* Rgb  = (ushort_t*)alloc((size_t)128*HD*2);
  ushort_t* Rub  = (ushort_t*)alloc((size_t)128*HD*2);
  ushort_t* Rdb  = (ushort_t*)alloc((size_t)128*IR*2);
  ushort_t* Ugb  = (ushort_t*)alloc((size_t)NEXP*128*128*2);
  ushort_t* Cgb  = (ushort_t*)alloc((size_t)NEXP*IR*128*2);
  ushort_t* Uub  = (ushort_t*)alloc((size_t)NEXP*128*128*2);
  ushort_t* Cub  = (ushort_t*)alloc((size_t)NEXP*IR*128*2);
  ushort_t* Udb  = (ushort_t*)alloc((size_t)NEXP*128*128*2);
  ushort_t* Cdb  = (ushort_t*)alloc((size_t)NEXP*HD*128*2);
  ushort_t* sRgb = (ushort_t*)alloc((size_t)128*HD*2);
  ushort_t* sUgb = (ushort_t*)alloc((size_t)128*128*2);
  ushort_t* sCgb = (ushort_t*)alloc((size_t)ISH*128*2);
  ushort_t* sRub = (ushort_t*)alloc((size_t)128*HD*2);
  ushort_t* sUub = (ushort_t*)alloc((size_t)128*128*2);
  ushort_t* sCub = (ushort_t*)alloc((size_t)ISH*128*2);
  ushort_t* sRdb = (ushort_t*)alloc((size_t)128*ISH*2);
  ushort_t* sUdb = (ushort_t*)alloc((size_t)128*128*2);
  ushort_t* sCdb = (ushort_t*)alloc((size_t)HD*128*2);
  ushort_t* rg   = (ushort_t*)alloc((size_t)T_TOK*128*2);
  ushort_t* ru   = (ushort_t*)alloc((size_t)T_TOK*128*2);
  ushort_t* sa   = (ushort_t*)alloc((size_t)T_TOK*128*2);
  ushort_t* su   = (ushort_t*)alloc((size_t)T_TOK*128*2);
  ushort_t* t1R  = (ushort_t*)alloc((size_t)NPAIR*128*2);
  ushort_t* t2R  = (ushort_t*)alloc((size_t)NPAIR*128*2);
  ushort_t* t1S  = (ushort_t*)alloc((size_t)T_TOK*128*2);
  ushort_t* t2S  = (ushort_t*)alloc((size_t)T_TOK*128*2);
  float*    rdSp = (float*)   alloc((size_t)4*T_TOK*128*sizeof(float));  // 4 shared partials
  ushort_t* ybufR= (ushort_t*)alloc((size_t)NPAIR*HD*2);                 // per-slot routed y (bf16)
  (void)ws_size; (void)in_sizes; (void)n_in;

  // routed rd partials (fp32, 2 parts) alias xb exactly:
  // 2*NPAIR*128*4 = 16.78 MB == T_TOK*HD*2. xb is dead after rproj; mid writes it after.
  float* rdRp = (float*)xb;

  hipMemsetAsync(cnt,  0, NEXP*sizeof(int), stream);
  hipMemsetAsync(fill, 0, NEXP*sizeof(int), stream);
  // no out memset: out_kernel's shared path fully writes out; combine RMWs it.

  // fused cvt
  CvtSegs cs;
  const float* ss[NSEG] = {x,Rg,Ru,Rd,Ug,Cg,Uu,Cu,Ud,Cd,sRg,sUg,sCg,sRu,sUu,sCu,sRd,sUd,sCd};
  ushort_t* dd[NSEG] = {xb,Rgb,Rub,Rdb,Ugb,Cgb,Uub,Cub,Udb,Cdb,sRgb,sUgb,sCgb,sRub,sUub,sCub,sRdb,sUdb,sCdb};
  size_t nn[NSEG] = {(size_t)T_TOK*HD,(size_t)128*HD,(size_t)128*HD,(size_t)128*IR,
                     (size_t)NEXP*128*128,(size_t)NEXP*IR*128,(size_t)NEXP*128*128,(size_t)NEXP*IR*128,
                     (size_t)NEXP*128*128,(size_t)NEXP*HD*128,(size_t)128*HD,(size_t)128*128,
                     (size_t)ISH*128,(size_t)128*HD,(size_t)128*128,(size_t)ISH*128,
                     (size_t)128*ISH,(size_t)128*128,(size_t)HD*128};
  int tot_blk = 0;
  for (int k = 0; k < NSEG; ++k) {
    cs.s[k] = ss[k]; cs.d[k] = dd[k];
    cs.n4[k] = (int)(nn[k] >> 2);
    cs.blk0[k] = tot_blk;
    tot_blk += (cs.n4[k] + 255) / 256;
  }
  cs.blk0[NSEG] = tot_blk;
  cvt_all_kernel<<<tot_blk, 256, 0, stream>>>(cs);

  gate_kernel<<<T_TOK/4, 256, 0, stream>>>(x, gw, topk_idx, topk_w, cnt);
  scan_kernel<<<1, 64, 0, stream>>>(cnt, offA);
  scatter_kernel<<<T_TOK/256, 256, 0, stream>>>(topk_idx, topk_w, offA, fill, list_tok, slot_of);
  rproj_kernel<<<dim3(T_TOK/64, 4), 256, 0, stream>>>(xb, Rgb, Rub, sRgb, sRub, rg, ru, sa, su);
  pair_proj_kernel<<<dim3(64, NEXP+1), 256, 0, stream>>>(
      rg, ru, sa, su, Ugb, Uub, sUgb, sUub, offA, cnt, list_tok, t1R, t2R, t1S, t2S);
  mid_kernel<<<dim3(64, NEXP+1, 4), 256, 0, stream>>>(
      t1R, t2R, t1S, t2S, Cgb, Cub, Rdb, sCgb, sCub, sRdb, offA, cnt, rdRp, rdSp);
  out_kernel<<<dim3(64, NEXP+1, 2), 256, 0, stream>>>(
      rdRp, rdSp, Udb, Cdb, sUdb, sCdb, offA, cnt, ybufR, out);
  combine_kernel<<<T_TOK, 256, 0, stream>>>(ybufR, slot_of, topk_w, out);
}

// Round 5
// 679.533 us; speedup vs baseline: 1.1799x; 1.1799x over previous
//
#include <hip/hip_runtime.h>
#include <math.h>

#define T_TOK 4096
#define HD    2048
#define NEXP  32
#define IR    1408
#define ISH   2816
#define NPAIR (T_TOK*4)
#define SRK   136      // padded bf16 row stride (cold paths only)
#define MTILES 11      // I-tiles (of 64) per chunk: routed 2 chunks, shared 4

typedef unsigned short ushort_t;
typedef __attribute__((ext_vector_type(8))) short    short8;
typedef __attribute__((ext_vector_type(8))) __bf16   bf16x8;
typedef __attribute__((ext_vector_type(4))) float    f32x4;

__device__ __forceinline__ f32x4 MF(short8 a, short8 b, f32x4 c) {
  return __builtin_amdgcn_mfma_f32_16x16x32_bf16(
      __builtin_bit_cast(bf16x8, a), __builtin_bit_cast(bf16x8, b), c, 0, 0, 0);
}
__device__ __forceinline__ ushort_t f2b(float f) {
  unsigned u = __float_as_uint(f);
  unsigned r = (u + 0x7fffu + ((u >> 16) & 1u)) >> 16;   // RNE
  return (ushort_t)r;
}
__device__ __forceinline__ float b2f(ushort_t b) {
  return __uint_as_float(((unsigned)b) << 16);
}

// async global->LDS 16B; LDS dst must be wave-uniform base (+lane*16 implicit)
__device__ __forceinline__ void gll16(const ushort_t* g, ushort_t* l) {
  __builtin_amdgcn_global_load_lds(
      (const __attribute__((address_space(1))) unsigned int*)(const void*)g,
      (__attribute__((address_space(3))) unsigned int*)(void*)l, 16, 0, 0);
}

// ---- swizzled tile loader (XOR swizzle: phys chunk = logical ^ (row&mask)) ----
// 64 rows x 128 cols bf16 (16 chunks/row). One instr = 4 rows.
__device__ __forceinline__ void load_64x128_swz(
    const ushort_t* __restrict__ g, size_t gstride, ushort_t* lds, int tid)
{
  const int lane = tid & 63, w = tid >> 6;
  #pragma unroll
  for (int s = 0; s < 4; ++s) {
    int rbase = s*16 + w*4;
    int r = rbase + (lane >> 4);
    int p = lane & 15;
    gll16(g + (size_t)r*gstride + ((p ^ (r & 15)) << 3), lds + rbase*128);
  }
}
// read elem(row r, chunk c of 8hw): lds[r*128 + ((c^(r&15))<<3)]

// ---------------------------------------------------------------- fused cvt
#define NSEG 19
struct CvtSegs {
  const float* s[NSEG];
  ushort_t* d[NSEG];
  int n4[NSEG];
  int blk0[NSEG+1];
};
__global__ __launch_bounds__(256) void cvt_all_kernel(CvtSegs cs)
{
  int b = blockIdx.x;
  int k = 0;
  #pragma unroll 1
  while (k+1 < NSEG && b >= cs.blk0[k+1]) ++k;
  int i = (b - cs.blk0[k])*256 + threadIdx.x;
  if (i < cs.n4[k]) {
    float4 v = ((const float4*)cs.s[k])[i];
    ushort4 o; o.x=f2b(v.x); o.y=f2b(v.y); o.z=f2b(v.z); o.w=f2b(v.w);
    ((ushort4*)cs.d[k])[i] = o;
  }
}

// ---------------------------------------------------------------- gate
// 4 tokens/block (4 waves); gw staged through LDS per 128-k chunk.
__global__ __launch_bounds__(256) void gate_kernel(
    const float* __restrict__ x, const float* __restrict__ gw,
    int* __restrict__ topk_idx, float* __restrict__ topk_w, int* __restrict__ cnt)
{
  __shared__ float gws[32*132];
  __shared__ float xs[4*132];
  const int tid = threadIdx.x;
  const int w = tid >> 6, lane = tid & 63;
  const int t0 = blockIdx.x * 4;
  const int e = lane & 31, half = lane >> 5;

  float acc = 0.f;
  for (int ck = 0; ck < HD/128; ++ck) {
    for (int li = tid; li < 1024; li += 256) {        // gw chunk 32x128
      int r = li >> 5, c4 = li & 31;
      *(float4*)(gws + r*132 + c4*4) = *(const float4*)(gw + (size_t)r*HD + ck*128 + c4*4);
    }
    for (int li = tid; li < 128; li += 256) {          // x chunk 4x128
      int r = li >> 5, c4 = li & 31;
      *(float4*)(xs + r*132 + c4*4) = *(const float4*)(x + (size_t)(t0+r)*HD + ck*128 + c4*4);
    }
    __syncthreads();
    #pragma unroll
    for (int k4 = 0; k4 < 16; ++k4) {
      float4 xv = *(const float4*)(xs + w*132 + half*64 + k4*4);
      float4 wv = *(const float4*)(gws + e*132 + half*64 + k4*4);
      acc += xv.x*wv.x + xv.y*wv.y + xv.z*wv.z + xv.w*wv.w;
    }
    __syncthreads();
  }
  float p = acc;
  p += __shfl_down(p, 32);
  float logit = (lane < 32) ? p : -INFINITY;
  float m = logit;
  #pragma unroll
  for (int o = 32; o >= 1; o >>= 1) m = fmaxf(m, __shfl_xor(m, o));
  float ex = (lane < 32) ? expf(logit - m) : 0.f;
  float se = ex;
  #pragma unroll
  for (int o = 32; o >= 1; o >>= 1) se += __shfl_xor(se, o);
  float score = ex / se;

  bool taken = false;
  float selw[4]; int seli[4];
  for (int k = 0; k < 4; ++k) {
    float cur = (lane < 32 && !taken) ? score : -1.f;
    float mm = cur;
    #pragma unroll
    for (int o = 32; o >= 1; o >>= 1) mm = fmaxf(mm, __shfl_xor(mm, o));
    unsigned long long b = __ballot(cur == mm);
    int il = __ffsll(b) - 1;
    if (lane == il) taken = true;
    selw[k] = mm; seli[k] = il;
  }
  float wsum = selw[0]+selw[1]+selw[2]+selw[3] + 1e-20f;
  int t = t0 + w;
  if (lane < 4) {
    topk_idx[t*4+lane] = seli[lane];
    topk_w[t*4+lane]  = selw[lane] / wsum;
    atomicAdd(&cnt[seli[lane]], 1);
  }
}

__global__ void scan_kernel(const int* __restrict__ cnt, int* __restrict__ offA)
{
  if (threadIdx.x == 0) {
    int a = 0;
    for (int e = 0; e < NEXP; ++e) { offA[e] = a; a += cnt[e]; }
    offA[NEXP] = a;
  }
}

__global__ __launch_bounds__(256) void scatter_kernel(
    const int* __restrict__ topk_idx, const float* __restrict__ topk_w,
    const int* __restrict__ offA, int* __restrict__ fill,
    int* __restrict__ list_tok, int* __restrict__ slot_of)
{
  int t = blockIdx.x*256 + threadIdx.x;
  if (t >= T_TOK) return;
  #pragma unroll
  for (int k = 0; k < 4; ++k) {
    int e = topk_idx[t*4+k];
    int pos = atomicAdd(&fill[e], 1);
    int s = offA[e] + pos;
    list_tok[s] = t;
    slot_of[t*4+k] = s;     // inverse map for non-atomic combine
  }
}

// ------------------------------------------------- R projections (pipelined)
// Y[T,128] = Xb[T,2048] @ W[128,2048]^T. A via gll dbuf; B-frags from global (L2-hot).
__global__ __launch_bounds__(256) void rproj_kernel(
    const ushort_t* __restrict__ xb,
    const ushort_t* __restrict__ Rg, const ushort_t* __restrict__ Ru,
    const ushort_t* __restrict__ sRg, const ushort_t* __restrict__ sRu,
    ushort_t* __restrict__ rg, ushort_t* __restrict__ ru,
    ushort_t* __restrict__ sa, ushort_t* __restrict__ su)
{
  __shared__ ushort_t abuf[2][64*128];
  const ushort_t* W; ushort_t* Y;
  switch (blockIdx.y) {
    case 0:  W = Rg;  Y = rg; break;
    case 1:  W = Ru;  Y = ru; break;
    case 2:  W = sRg; Y = sa; break;
    default: W = sRu; Y = su; break;
  }
  const int tid = threadIdx.x;
  const int lane = tid & 63, ln = lane & 15, q = lane >> 4;
  const int wv = tid >> 6, mh = wv >> 1, nh = wv & 1;
  const int r0 = blockIdx.x * 64;

  f32x4 acc[2][4];
  #pragma unroll
  for (int i = 0; i < 2; ++i)
    #pragma unroll
    for (int j = 0; j < 4; ++j) acc[i][j] = (f32x4){0.f,0.f,0.f,0.f};

  load_64x128_swz(xb + (size_t)r0*HD, HD, abuf[0], tid);
  for (int kt = 0; kt < 16; ++kt) {
    __syncthreads();                       // abuf[kt&1] ready
    if (kt+1 < 16)
      load_64x128_swz(xb + (size_t)r0*HD + (kt+1)*128, HD, abuf[(kt+1)&1], tid);
    const ushort_t* A = abuf[kt&1];
    #pragma unroll
    for (int c = 0; c < 4; ++c) {
      short8 a[2], b[4];
      #pragma unroll
      for (int i = 0; i < 2; ++i) {
        int rr = mh*32 + i*16 + ln;
        a[i] = *(const short8*)(A + rr*128 + (((c*4+q) ^ (rr&15)) << 3));
      }
      #pragma unroll
      for (int j = 0; j < 4; ++j)
        b[j] = *(const short8*)(W + (size_t)(nh*64 + j*16 + ln)*HD + kt*128 + c*32 + q*8);
      #pragma unroll
      for (int i = 0; i < 2; ++i)
        #pragma unroll
        for (int j = 0; j < 4; ++j) acc[i][j] = MF(a[i], b[j], acc[i][j]);
    }
  }
  #pragma unroll
  for (int i = 0; i < 2; ++i)
    #pragma unroll
    for (int j = 0; j < 4; ++j)
      #pragma unroll
      for (int r = 0; r < 4; ++r)
        Y[(size_t)(r0 + mh*32 + i*16 + q*4 + r)*128 + nh*64 + j*16 + ln] = f2b(acc[i][j][r]);
}

// -------- helper (cold path): acc = A_lds[64][SRK] @ Wg[128][128]^T, C in regs
__device__ __forceinline__ void gemm64x128_regs(
    int tid, const ushort_t* __restrict__ A, const ushort_t* __restrict__ Wg,
    ushort_t* __restrict__ stage, f32x4 acc[2][2][2])
{
  const int lane = tid & 63, ln = lane & 15, q = lane >> 4;
  const int wv = tid >> 6, mh = wv >> 1, nh = wv & 1;
  #pragma unroll
  for (int h = 0; h < 2; ++h)
    #pragma unroll
    for (int i = 0; i < 2; ++i)
      #pragma unroll
      for (int j = 0; j < 2; ++j) acc[h][i][j] = (f32x4){0.f,0.f,0.f,0.f};
  for (int h = 0; h < 2; ++h) {
    for (int li = tid; li < 64*16; li += 256) {
      int r = li >> 4, c = (li & 15) << 3;
      *(short8*)(stage + r*SRK + c) = *(const short8*)(Wg + (size_t)(h*64 + r)*128 + c);
    }
    __syncthreads();
    #pragma unroll
    for (int c = 0; c < 4; ++c) {
      short8 a[2], b[2];
      #pragma unroll
      for (int i = 0; i < 2; ++i)
        a[i] = *(const short8*)(A + (mh*32 + i*16 + ln)*SRK + c*32 + q*8);
      #pragma unroll
      for (int j = 0; j < 2; ++j)
        b[j] = *(const short8*)(stage + (nh*32 + j*16 + ln)*SRK + c*32 + q*8);
      #pragma unroll
      for (int i = 0; i < 2; ++i)
        #pragma unroll
        for (int j = 0; j < 2; ++j) acc[h][i][j] = MF(a[i], b[j], acc[h][i][j]);
    }
    __syncthreads();
  }
}

// ---------------------------------------------------------------- pair_proj
// t1[slot] = rg[tok(slot)] @ Ug_e^T ; t2 = ru @ Uu_e^T ; shared rows direct.
__global__ __launch_bounds__(256) void pair_proj_kernel(
    const ushort_t* __restrict__ rgb, const ushort_t* __restrict__ rub,
    const ushort_t* __restrict__ sab, const ushort_t* __restrict__ sub,
    const ushort_t* __restrict__ Ug, const ushort_t* __restrict__ Uu,
    const ushort_t* __restrict__ sUg, const ushort_t* __restrict__ sUu,
    const int* __restrict__ offA, const int* __restrict__ cntA,
    const int* __restrict__ list_tok,
    ushort_t* __restrict__ t1R, ushort_t* __restrict__ t2R,
    ushort_t* __restrict__ t1S, ushort_t* __restrict__ t2S)
{
  __shared__ ushort_t ldsX[64*SRK];
  __shared__ ushort_t stage[64*SRK];
  __shared__ int toks[64];
  const int tid = threadIdx.x;
  const int by = blockIdx.y;
  const bool shm = (by == NEXP);
  const int nrows = shm ? T_TOK : cntA[by];
  const int s0 = blockIdx.x * 64;
  if (s0 >= nrows) return;
  const int base = shm ? 0 : offA[by];
  const ushort_t* pUg = shm ? sUg : Ug + (size_t)by*128*128;
  const ushort_t* pUu = shm ? sUu : Uu + (size_t)by*128*128;
  const int lane = tid & 63, ln = lane & 15, q = lane >> 4;
  const int wv = tid >> 6, mh = wv >> 1, nh = wv & 1;

  if (tid < 64) {
    int sc = s0 + tid; if (sc > nrows-1) sc = nrows-1;
    toks[tid] = shm ? sc : list_tok[base + sc];
  }
  __syncthreads();

  f32x4 acc[2][2][2];
  // t1
  for (int li = tid; li < 64*16; li += 256) {
    int r = li >> 4, c = (li & 15) << 3;
    const ushort_t* src = shm ? sab : rgb;
    *(short8*)(ldsX + r*SRK + c) = *(const short8*)(src + (size_t)toks[r]*128 + c);
  }
  __syncthreads();
  gemm64x128_regs(tid, ldsX, pUg, stage, acc);
  {
    ushort_t* dst = shm ? t1S : (t1R + (size_t)base*128);
    #pragma unroll
    for (int h = 0; h < 2; ++h)
      #pragma unroll
      for (int i = 0; i < 2; ++i)
        #pragma unroll
        for (int r = 0; r < 4; ++r) {
          int gs = s0 + mh*32 + i*16 + q*4 + r;
          if (gs < nrows) {
            #pragma unroll
            for (int j = 0; j < 2; ++j)
              dst[(size_t)gs*128 + h*64 + nh*32 + j*16 + ln] = f2b(acc[h][i][j][r]);
          }
        }
  }
  // t2
  for (int li = tid; li < 64*16; li += 256) {
    int r = li >> 4, c = (li & 15) << 3;
    const ushort_t* src = shm ? sub : rub;
    *(short8*)(ldsX + r*SRK + c) = *(const short8*)(src + (size_t)toks[r]*128 + c);
  }
  __syncthreads();
  gemm64x128_regs(tid, ldsX, pUu, stage, acc);
  {
    ushort_t* dst = shm ? t2S : (t2R + (size_t)base*128);
    #pragma unroll
    for (int h = 0; h < 2; ++h)
      #pragma unroll
      for (int i = 0; i < 2; ++i)
        #pragma unroll
        for (int r = 0; r < 4; ++r) {
          int gs = s0 + mh*32 + i*16 + q*4 + r;
          if (gs < nrows) {
            #pragma unroll
            for (int j = 0; j < 2; ++j)
              dst[(size_t)gs*128 + h*64 + nh*32 + j*16 + ln] = f2b(acc[h][i][j][r]);
          }
        }
  }
}

// ---------------------------------------------------------------- mid (v3 hybrid, spill-fixed)
// grid (64, 33, 4). Cg/Cu gll-staged in LDS; Rd B-frags DIRECT from global
// (L2-resident, shared across experts). LDS 40KB -> 4 blocks/CU. XCD swizzle.
// launch_bounds (256,3): VGPR cap 170 -> compiler lands ~112-130, NO SPILL.
// (r4's (256,4) forced 64 VGPR -> scratch spill storm: FETCH 328MB, WRITE 91MB.)
__global__ __launch_bounds__(256, 3) void mid_kernel(
    const ushort_t* __restrict__ t1R, const ushort_t* __restrict__ t2R,
    const ushort_t* __restrict__ t1S, const ushort_t* __restrict__ t2S,
    const ushort_t* __restrict__ Cg, const ushort_t* __restrict__ Cu,
    const ushort_t* __restrict__ Rd,
    const ushort_t* __restrict__ sCg, const ushort_t* __restrict__ sCu,
    const ushort_t* __restrict__ sRd,
    const int* __restrict__ offA, const int* __restrict__ cntA,
    float* __restrict__ rdRp, float* __restrict__ rdSp)
{
  __shared__ ushort_t ldsCg[64*128];   // 16 KB
  __shared__ ushort_t ldsCu[64*128];   // 16 KB
  __shared__ ushort_t ldsH [64*64];    //  8 KB

  // XCD swizzle: 64*33*4 = 8448, 8448/8 = 1056 (bijective).
  const int hh = blockIdx.x + 64*(blockIdx.y + 33*blockIdx.z);
  const int L = (hh & 7) * 1056 + (hh >> 3);
  const int bx  = L & 63;
  const int rem = L >> 6;          // 0..131
  const int by  = rem % 33;
  const int bz  = rem / 33;

  const bool shm = (by == NEXP);
  if (bz >= (shm ? 4 : 2)) return;
  const int nrows = shm ? T_TOK : cntA[by];
  const int s0 = bx * 64;
  if (s0 >= nrows) return;
  const int base = shm ? 0 : offA[by];
  const int Ifull = shm ? ISH : IR;
  const ushort_t* pCg = shm ? sCg : Cg + (size_t)by*IR*128;
  const ushort_t* pCu = shm ? sCu : Cu + (size_t)by*IR*128;
  const ushort_t* pRd = shm ? sRd : Rd;

  const int tid = threadIdx.x;
  const int lane = tid & 63, ln = lane & 15, q = lane >> 4;
  const int wv = tid >> 6, mh = wv >> 1, nh = wv & 1;
  const int it0 = bz * MTILES;

  // t1/t2 A-fragments -> registers (held across the whole K loop)
  short8 t1f[2][4], t2f[2][4];
  const ushort_t* srcT1 = shm ? t1S : (t1R + (size_t)base*128);
  const ushort_t* srcT2 = shm ? t2S : (t2R + (size_t)base*128);
  #pragma unroll
  for (int i = 0; i < 2; ++i) {
    int r = s0 + mh*32 + i*16 + ln; if (r > nrows-1) r = nrows-1;
    #pragma unroll
    for (int c = 0; c < 4; ++c) {
      t1f[i][c] = *(const short8*)(srcT1 + (size_t)r*128 + c*32 + q*8);
      t2f[i][c] = *(const short8*)(srcT2 + (size_t)r*128 + c*32 + q*8);
    }
  }

  load_64x128_swz(pCg + (size_t)it0*64*128, 128, ldsCg, tid);
  load_64x128_swz(pCu + (size_t)it0*64*128, 128, ldsCu, tid);

  f32x4 rdacc[2][4];
  #pragma unroll
  for (int i = 0; i < 2; ++i)
    #pragma unroll
    for (int j = 0; j < 4; ++j) rdacc[i][j] = (f32x4){0.f,0.f,0.f,0.f};

  // invariant per-lane Rd offset: row (nh*64+ln), chunk q
  const size_t rdRow = (size_t)(nh*64 + ln)*Ifull + q*8;   // + j*16*Ifull + i0 + c2*32

  __syncthreads();   // Cg/Cu tile 0 ready (gll drained by barrier)

  for (int it = 0; it < MTILES; ++it) {
    const int i0 = (it0 + it) * 64;
    // phase A: g,u MFMA from regs x ldsCg/Cu; silu; h -> ldsH
    f32x4 g[2][2], u[2][2];
    #pragma unroll
    for (int i = 0; i < 2; ++i)
      #pragma unroll
      for (int j = 0; j < 2; ++j) { g[i][j] = (f32x4){0.f,0.f,0.f,0.f}; u[i][j] = (f32x4){0.f,0.f,0.f,0.f}; }
    #pragma unroll
    for (int c = 0; c < 4; ++c) {
      #pragma unroll
      for (int j = 0; j < 2; ++j) {
        int rr = nh*32 + j*16 + ln;
        int off = rr*128 + (((c*4+q) ^ (rr&15)) << 3);
        short8 bg = *(const short8*)(ldsCg + off);
        short8 bu = *(const short8*)(ldsCu + off);
        #pragma unroll
        for (int i = 0; i < 2; ++i) {
          g[i][j] = MF(t1f[i][c], bg, g[i][j]);
          u[i][j] = MF(t2f[i][c], bu, u[i][j]);
        }
      }
    }
    #pragma unroll
    for (int i = 0; i < 2; ++i)
      #pragma unroll
      for (int j = 0; j < 2; ++j)
        #pragma unroll
        for (int r = 0; r < 4; ++r) {
          float gv = g[i][j][r];
          gv = gv / (1.f + __expf(-gv));
          float hv = gv * u[i][j][r];
          int hr = mh*32 + i*16 + q*4 + r;
          int hc = nh*32 + j*16 + ln;
          ldsH[hr*64 + (((hc>>3) ^ (hr&7)) << 3) + (hc&7)] = f2b(hv);
        }
    __syncthreads();   // h visible; all Cg/Cu reads done
    // phase B: issue Cg/Cu(it+1) gll (overwrite safe); rd += h @ Rd^T (Rd direct)
    if (it+1 < MTILES) {
      load_64x128_swz(pCg + (size_t)(i0+64)*128, 128, ldsCg, tid);
      load_64x128_swz(pCu + (size_t)(i0+64)*128, 128, ldsCu, tid);
    }
    #pragma unroll
    for (int c2 = 0; c2 < 2; ++c2) {
      short8 a[2];
      #pragma unroll
      for (int i = 0; i < 2; ++i) {
        int rr = mh*32 + i*16 + ln;
        a[i] = *(const short8*)(ldsH + rr*64 + (((c2*4+q) ^ (rr&7)) << 3));
      }
      #pragma unroll
      for (int j = 0; j < 4; ++j) {
        short8 b = *(const short8*)(pRd + rdRow + (size_t)(j*16)*Ifull + i0 + c2*32);
        #pragma unroll
        for (int i = 0; i < 2; ++i) rdacc[i][j] = MF(a[i], b, rdacc[i][j]);
      }
    }
    __syncthreads();   // Cg/Cu(it+1) landed; ldsH reads done
  }

  // plain disjoint stores (no atomics): part bz of 2 (routed) or 4 (shared)
  float* dst = shm ? (rdSp + (size_t)bz*T_TOK*128)
                   : (rdRp + (size_t)bz*NPAIR*128 + (size_t)base*128);
  #pragma unroll
  for (int i = 0; i < 2; ++i) {
    #pragma unroll
    for (int r = 0; r < 4; ++r) {
      int gs = s0 + mh*32 + i*16 + q*4 + r;
      if (gs < nrows) {
        #pragma unroll
        for (int j = 0; j < 4; ++j)
          dst[(size_t)gs*128 + nh*64 + j*16 + ln] = rdacc[i][j][r];
      }
    }
  }
}

// ---------------------------------------------------------------- out
// grid (64, 33, 2). t3 frags in regs; Cd double-buffered via gll; 1 barrier/tile.
// XCD swizzle for Cd L2 locality. NO atomics: routed y -> ybufR (bf16, per-slot,
// unweighted); shared y -> out directly (fp32 plain stores; sole writer).
__global__ __launch_bounds__(256) void out_kernel(
    const float* __restrict__ rdRp, const float* __restrict__ rdSp,
    const ushort_t* __restrict__ Ud, const ushort_t* __restrict__ Cd,
    const ushort_t* __restrict__ sUd, const ushort_t* __restrict__ sCd,
    const int* __restrict__ offA, const int* __restrict__ cntA,
    ushort_t* __restrict__ ybufR, float* __restrict__ out)
{
  __shared__ ushort_t smem[3*64*SRK];   // prologue: ldsA | stage | ldsT ; loop: cd0,cd1
  ushort_t* ldsA  = smem;
  ushort_t* stage = smem + 64*SRK;
  ushort_t* ldsT  = smem + 2*64*SRK;
  ushort_t* cd0   = smem;
  ushort_t* cd1   = smem + 64*128;

  // XCD swizzle: 64*33*2 = 4224, 4224/8 = 528 (bijective).
  const int hh = blockIdx.x + 64*(blockIdx.y + 33*blockIdx.z);
  const int L = (hh & 7) * 528 + (hh >> 3);
  const int bx  = L & 63;
  const int rem = L >> 6;          // 0..65
  const int by  = rem % 33;
  const int bzz = rem / 33;

  const int tid = threadIdx.x;
  const bool shm = (by == NEXP);
  const int nrows = shm ? T_TOK : cntA[by];
  const int s0 = bx * 64;
  if (s0 >= nrows) return;
  const int base = shm ? 0 : offA[by];
  const int ct0 = bzz * 16;
  const ushort_t* pUd = shm ? sUd : Ud + (size_t)by*128*128;
  const ushort_t* pCd = shm ? sCd : Cd + (size_t)by*HD*128;

  const int lane = tid & 63, ln = lane & 15, q = lane >> 4;
  const int wv = tid >> 6, mh = wv >> 1, nh = wv & 1;

  // gather rd rows: sum the per-bz partials (fp32) -> bf16 ldsA
  for (int li = tid; li < 64*32; li += 256) {
    int r = li >> 5, c4 = li & 31;
    int row = s0 + r; if (row > nrows-1) row = nrows-1;
    float4 v;
    if (shm) {
      const float* p = rdSp + (size_t)row*128 + c4*4;
      v = *(const float4*)p;
      #pragma unroll
      for (int pp = 1; pp < 4; ++pp) {
        float4 w2 = *(const float4*)(p + (size_t)pp*T_TOK*128);
        v.x += w2.x; v.y += w2.y; v.z += w2.z; v.w += w2.w;
      }
    } else {
      const float* p = rdRp + (size_t)(base+row)*128 + c4*4;
      v = *(const float4*)p;
      float4 w2 = *(const float4*)(p + (size_t)NPAIR*128);
      v.x += w2.x; v.y += w2.y; v.z += w2.z; v.w += w2.w;
    }
    ushort4 o; o.x=f2b(v.x); o.y=f2b(v.y); o.z=f2b(v.z); o.w=f2b(v.w);
    *(ushort4*)(ldsA + r*SRK + c4*4) = o;
  }
  __syncthreads();

  f32x4 acc[2][2][2];
  gemm64x128_regs(tid, ldsA, pUd, stage, acc);
  // C -> ldsT (padded), then extract A-frags
  #pragma unroll
  for (int h = 0; h < 2; ++h)
    #pragma unroll
    for (int i = 0; i < 2; ++i)
      #pragma unroll
      for (int j = 0; j < 2; ++j)
        #pragma unroll
        for (int r = 0; r < 4; ++r)
          ldsT[(mh*32 + i*16 + q*4 + r)*SRK + h*64 + nh*32 + j*16 + ln] = f2b(acc[h][i][j][r]);
  __syncthreads();
  short8 t3f[2][4];
  #pragma unroll
  for (int i = 0; i < 2; ++i)
    #pragma unroll
    for (int c = 0; c < 4; ++c)
      t3f[i][c] = *(const short8*)(ldsT + (mh*32 + i*16 + ln)*SRK + c*32 + q*8);
  __syncthreads();   // smem free for cd buffers

  load_64x128_swz(pCd + (size_t)ct0*64*128, 128, cd0, tid);
  for (int tt = 0; tt < 16; ++tt) {
    __syncthreads();                      // cd[tt&1] ready; prior reads drained
    ushort_t* cur = (tt & 1) ? cd1 : cd0;
    ushort_t* nxt = (tt & 1) ? cd0 : cd1;
    if (tt+1 < 16)
      load_64x128_swz(pCd + (size_t)(ct0+tt+1)*64*128, 128, nxt, tid);
    f32x4 y[2][2];
    #pragma unroll
    for (int i = 0; i < 2; ++i)
      #pragma unroll
      for (int j = 0; j < 2; ++j) y[i][j] = (f32x4){0.f,0.f,0.f,0.f};
    #pragma unroll
    for (int c = 0; c < 4; ++c) {
      #pragma unroll
      for (int j = 0; j < 2; ++j) {
        int rr = nh*32 + j*16 + ln;
        short8 b = *(const short8*)(cur + rr*128 + (((c*4+q) ^ (rr&15)) << 3));
        #pragma unroll
        for (int i = 0; i < 2; ++i) y[i][j] = MF(t3f[i][c], b, y[i][j]);
      }
    }
    #pragma unroll
    for (int i = 0; i < 2; ++i) {
      #pragma unroll
      for (int r = 0; r < 4; ++r) {
        int lr = mh*32 + i*16 + q*4 + r;
        int gs = s0 + lr;
        if (gs < nrows) {
          if (shm) {
            size_t ob = (size_t)gs*HD + (ct0 + tt)*64;
            #pragma unroll
            for (int j = 0; j < 2; ++j)
              out[ob + nh*32 + j*16 + ln] = y[i][j][r];
          } else {
            size_t ob = (size_t)(base + gs)*HD + (ct0 + tt)*64;
            #pragma unroll
            for (int j = 0; j < 2; ++j)
              ybufR[ob + nh*32 + j*16 + ln] = f2b(y[i][j][r]);
          }
        }
      }
    }
  }
}

// ---------------------------------------------------------------- combine
// out[t] = out[t] (shared, already stored) + sum_k w_k * ybufR[slot_of[t,k]]
// One block per token row; fully coalesced, no atomics.
__global__ __launch_bounds__(256) void combine_kernel(
    const ushort_t* __restrict__ ybufR,
    const int* __restrict__ slot_of, const float* __restrict__ topk_w,
    float* __restrict__ out)
{
  __shared__ int   ss[4];
  __shared__ float ww[4];
  const int t = blockIdx.x;
  if (threadIdx.x < 4) {
    ss[threadIdx.x] = slot_of[t*4 + threadIdx.x];
    ww[threadIdx.x] = topk_w[t*4 + threadIdx.x];
  }
  __syncthreads();
  const int c = threadIdx.x * 8;
  const size_t tb = (size_t)t*HD + c;
  float o[8];
  float4 a0 = *(const float4*)(out + tb);
  float4 a1 = *(const float4*)(out + tb + 4);
  o[0]=a0.x; o[1]=a0.y; o[2]=a0.z; o[3]=a0.w;
  o[4]=a1.x; o[5]=a1.y; o[6]=a1.z; o[7]=a1.w;
  #pragma unroll
  for (int k = 0; k < 4; ++k) {
    short8 rv = *(const short8*)(ybufR + (size_t)ss[k]*HD + c);
    float wk = ww[k];
    #pragma unroll
    for (int u = 0; u < 8; ++u)
      o[u] += wk * b2f((ushort_t)rv[u]);
  }
  float4 b0 = {o[0],o[1],o[2],o[3]};
  float4 b1 = {o[4],o[5],o[6],o[7]};
  *(float4*)(out + tb)     = b0;
  *(float4*)(out + tb + 4) = b1;
}

// ---------------------------------------------------------------- launch
extern "C" void kernel_launch(void* const* d_in, const int* in_sizes, int n_in,
                              void* d_out, int out_size, void* d_ws, size_t ws_size,
                              hipStream_t stream) {
  const float* x    = (const float*)d_in[0];
  const float* gw   = (const float*)d_in[1];
  const float* Rg   = (const float*)d_in[2];
  const float* Ru   = (const float*)d_in[3];
  const float* Rd   = (const float*)d_in[4];
  const float* Ug   = (const float*)d_in[5];
  const float* Cg   = (const float*)d_in[6];
  const float* Uu   = (const float*)d_in[7];
  const float* Cu   = (const float*)d_in[8];
  const float* Ud   = (const float*)d_in[9];
  const float* Cd   = (const float*)d_in[10];
  const float* sRg  = (const float*)d_in[11];
  const float* sUg  = (const float*)d_in[12];
  const float* sCg  = (const float*)d_in[13];
  const float* sRu  = (const float*)d_in[14];
  const float* sUu  = (const float*)d_in[15];
  const float* sCu  = (const float*)d_in[16];
  const float* sRd  = (const float*)d_in[17];
  const float* sUd  = (const float*)d_in[18];
  const float* sCd  = (const float*)d_in[19];
  float* out = (float*)d_out;

  char* w = (char*)d_ws;
  auto alloc = [&](size_t bytes) -> void* {
    void* p = (void*)w; w += (bytes + 255) & ~(size_t)255; return p;
  };
  int*   cnt      = (int*)  alloc(NEXP*sizeof(int));
  int*   offA     = (int*)  alloc((NEXP+1)*sizeof(int));
  int*   fill     = (int*)  alloc(NEXP*sizeof(int));
  int*   topk_idx = (int*)  alloc((size_t)T_TOK*4*sizeof(int));
  float* topk_w   = (float*)alloc((size_t)T_TOK*4*sizeof(float));
  int*   list_tok = (int*)  alloc((size_t)NPAIR*sizeof(int));
  int*   slot_of  = (int*)  alloc((size_t)T_TOK*4*sizeof(int));
  ushort_t* xb   = (ushort_t*)alloc((size_t)T_TOK*HD*2);   // later reused as rdRp (fp32, 2 parts)
  ushort_t* Rgb  = (ushort_t*)alloc((size_t)128*HD*2);
  ushort_t* Rub  = (ushort_t*)alloc((size_t)128*HD*2);
  ushort_t* Rdb  = (ushort_t*)alloc((size_t)128*IR*2);
  ushort_t* Ugb  = (ushort_t*)alloc((size_t)NEXP*128*128*2);
  ushort_t* Cgb  = (ushort_t*)alloc((size_t)NEXP*IR*128*2);
  ushort_t* Uub  = (ushort_t*)alloc((size_t)NEXP*128*128*2);
  ushort_t* Cub  = (ushort_t*)alloc((size_t)NEXP*IR*128*2);
  ushort_t* Udb  = (ushort_t*)alloc((size_t)NEXP*128*128*2);
  ushort_t* Cdb  = (ushort_t*)alloc((size_t)NEXP*HD*128*2);
  ushort_t* sRgb = (ushort_t*)alloc((size_t)128*HD*2);
  ushort_t* sUgb = (ushort_t*)alloc((size_t)128*128*2);
  ushort_t* sCgb = (ushort_t*)alloc((size_t)ISH*128*2);
  ushort_t* sRub = (ushort_t*)alloc((size_t)128*HD*2);
  ushort_t* sUub = (ushort_t*)alloc((size_t)128*128*2);
  ushort_t* sCub = (ushort_t*)alloc((size_t)ISH*128*2);
  ushort_t* sRdb = (ushort_t*)alloc((size_t)128*ISH*2);
  ushort_t* sUdb = (ushort_t*)alloc((size_t)128*128*2);
  ushort_t* sCdb = (ushort_t*)alloc((size_t)HD*128*2);
  ushort_t* rg   = (ushort_t*)alloc((size_t)T_TOK*128*2);
  ushort_t* ru   = (ushort_t*)alloc((size_t)T_TOK*128*2);
  ushort_t* sa   = (ushort_t*)alloc((size_t)T_TOK*128*2);
  ushort_t* su   = (ushort_t*)alloc((size_t)T_TOK*128*2);
  ushort_t* t1R  = (ushort_t*)alloc((size_t)NPAIR*128*2);
  ushort_t* t2R  = (ushort_t*)alloc((size_t)NPAIR*128*2);
  ushort_t* t1S  = (ushort_t*)alloc((size_t)T_TOK*128*2);
  ushort_t* t2S  = (ushort_t*)alloc((size_t)T_TOK*128*2);
  float*    rdSp = (float*)   alloc((size_t)4*T_TOK*128*sizeof(float));  // 4 shared partials
  ushort_t* ybufR= (ushort_t*)alloc((size_t)NPAIR*HD*2);                 // per-slot routed y (bf16)
  (void)ws_size; (void)in_sizes; (void)n_in;

  // routed rd partials (fp32, 2 parts) alias xb exactly:
  // 2*NPAIR*128*4 = 16.78 MB == T_TOK*HD*2. xb is dead after rproj; mid writes it after.
  float* rdRp = (float*)xb;

  hipMemsetAsync(cnt,  0, NEXP*sizeof(int), stream);
  hipMemsetAsync(fill, 0, NEXP*sizeof(int), stream);
  // no out memset: out_kernel's shared path fully writes out; combine RMWs it.

  // fused cvt
  CvtSegs cs;
  const float* ss[NSEG] = {x,Rg,Ru,Rd,Ug,Cg,Uu,Cu,Ud,Cd,sRg,sUg,sCg,sRu,sUu,sCu,sRd,sUd,sCd};
  ushort_t* dd[NSEG] = {xb,Rgb,Rub,Rdb,Ugb,Cgb,Uub,Cub,Udb,Cdb,sRgb,sUgb,sCgb,sRub,sUub,sCub,sRdb,sUdb,sCdb};
  size_t nn[NSEG] = {(size_t)T_TOK*HD,(size_t)128*HD,(size_t)128*HD,(size_t)128*IR,
                     (size_t)NEXP*128*128,(size_t)NEXP*IR*128,(size_t)NEXP*128*128,(size_t)NEXP*IR*128,
                     (size_t)NEXP*128*128,(size_t)NEXP*HD*128,(size_t)128*HD,(size_t)128*128,
                     (size_t)ISH*128,(size_t)128*HD,(size_t)128*128,(size_t)ISH*128,
                     (size_t)128*ISH,(size_t)128*128,(size_t)HD*128};
  int tot_blk = 0;
  for (int k = 0; k < NSEG; ++k) {
    cs.s[k] = ss[k]; cs.d[k] = dd[k];
    cs.n4[k] = (int)(nn[k] >> 2);
    cs.blk0[k] = tot_blk;
    tot_blk += (cs.n4[k] + 255) / 256;
  }
  cs.blk0[NSEG] = tot_blk;
  cvt_all_kernel<<<tot_blk, 256, 0, stream>>>(cs);

  gate_kernel<<<T_TOK/4, 256, 0, stream>>>(x, gw, topk_idx, topk_w, cnt);
  scan_kernel<<<1, 64, 0, stream>>>(cnt, offA);
  scatter_kernel<<<T_TOK/256, 256, 0, stream>>>(topk_idx, topk_w, offA, fill, list_tok, slot_of);
  rproj_kernel<<<dim3(T_TOK/64, 4), 256, 0, stream>>>(xb, Rgb, Rub, sRgb, sRub, rg, ru, sa, su);
  pair_proj_kernel<<<dim3(64, NEXP+1), 256, 0, stream>>>(
      rg, ru, sa, su, Ugb, Uub, sUgb, sUub, offA, cnt, list_tok, t1R, t2R, t1S, t2S);
  mid_kernel<<<dim3(64, NEXP+1, 4), 256, 0, stream>>>(
      t1R, t2R, t1S, t2S, Cgb, Cub, Rdb, sCgb, sCub, sRdb, offA, cnt, rdRp, rdSp);
  out_kernel<<<dim3(64, NEXP+1, 2), 256, 0, stream>>>(
      rdRp, rdSp, Udb, Cdb, sUdb, sCdb, offA, cnt, ybufR, out);
  combine_kernel<<<T_TOK, 256, 0, stream>>>(ybufR, slot_of, topk_w, out);
}

// Round 6
// 607.451 us; speedup vs baseline: 1.3199x; 1.1187x over previous
//
#include <hip/hip_runtime.h>
#include <math.h>

#define T_TOK 4096
#define HD    2048
#define NEXP  32
#define IR    1408
#define ISH   2816
#define NPAIR (T_TOK*4)
#define SRK   136      // padded bf16 row stride (cold paths only)
#define MTILES 11      // I-tiles (of 64) per chunk: routed 2 chunks, shared 4

typedef unsigned short ushort_t;
typedef __attribute__((ext_vector_type(8))) short    short8;
typedef __attribute__((ext_vector_type(8))) __bf16   bf16x8;
typedef __attribute__((ext_vector_type(4))) float    f32x4;

__device__ __forceinline__ f32x4 MF(short8 a, short8 b, f32x4 c) {
  return __builtin_amdgcn_mfma_f32_16x16x32_bf16(
      __builtin_bit_cast(bf16x8, a), __builtin_bit_cast(bf16x8, b), c, 0, 0, 0);
}
__device__ __forceinline__ ushort_t f2b(float f) {
  unsigned u = __float_as_uint(f);
  unsigned r = (u + 0x7fffu + ((u >> 16) & 1u)) >> 16;   // RNE
  return (ushort_t)r;
}
__device__ __forceinline__ float b2f(ushort_t b) {
  return __uint_as_float(((unsigned)b) << 16);
}

// async global->LDS 16B; LDS dst must be wave-uniform base (+lane*16 implicit)
__device__ __forceinline__ void gll16(const ushort_t* g, ushort_t* l) {
  __builtin_amdgcn_global_load_lds(
      (const __attribute__((address_space(1))) unsigned int*)(const void*)g,
      (__attribute__((address_space(3))) unsigned int*)(void*)l, 16, 0, 0);
}

// ---- swizzled tile loader (XOR swizzle: phys chunk = logical ^ (row&mask)) ----
// 64 rows x 128 cols bf16 (16 chunks/row). One instr = 4 rows.
__device__ __forceinline__ void load_64x128_swz(
    const ushort_t* __restrict__ g, size_t gstride, ushort_t* lds, int tid)
{
  const int lane = tid & 63, w = tid >> 6;
  #pragma unroll
  for (int s = 0; s < 4; ++s) {
    int rbase = s*16 + w*4;
    int r = rbase + (lane >> 4);
    int p = lane & 15;
    gll16(g + (size_t)r*gstride + ((p ^ (r & 15)) << 3), lds + rbase*128);
  }
}
// read elem(row r, chunk c of 8hw): lds[r*128 + ((c^(r&15))<<3)]

// ---------------------------------------------------------------- fused cvt
#define NSEG 19
struct CvtSegs {
  const float* s[NSEG];
  ushort_t* d[NSEG];
  int n4[NSEG];
  int blk0[NSEG+1];
};
__global__ __launch_bounds__(256) void cvt_all_kernel(CvtSegs cs)
{
  int b = blockIdx.x;
  int k = 0;
  #pragma unroll 1
  while (k+1 < NSEG && b >= cs.blk0[k+1]) ++k;
  int i = (b - cs.blk0[k])*256 + threadIdx.x;
  if (i < cs.n4[k]) {
    float4 v = ((const float4*)cs.s[k])[i];
    ushort4 o; o.x=f2b(v.x); o.y=f2b(v.y); o.z=f2b(v.z); o.w=f2b(v.w);
    ((ushort4*)cs.d[k])[i] = o;
  }
}

// ---------------------------------------------------------------- gate
// 4 tokens/block (4 waves); gw staged through LDS per 128-k chunk.
__global__ __launch_bounds__(256) void gate_kernel(
    const float* __restrict__ x, const float* __restrict__ gw,
    int* __restrict__ topk_idx, float* __restrict__ topk_w, int* __restrict__ cnt)
{
  __shared__ float gws[32*132];
  __shared__ float xs[4*132];
  const int tid = threadIdx.x;
  const int w = tid >> 6, lane = tid & 63;
  const int t0 = blockIdx.x * 4;
  const int e = lane & 31, half = lane >> 5;

  float acc = 0.f;
  for (int ck = 0; ck < HD/128; ++ck) {
    for (int li = tid; li < 1024; li += 256) {        // gw chunk 32x128
      int r = li >> 5, c4 = li & 31;
      *(float4*)(gws + r*132 + c4*4) = *(const float4*)(gw + (size_t)r*HD + ck*128 + c4*4);
    }
    for (int li = tid; li < 128; li += 256) {          // x chunk 4x128
      int r = li >> 5, c4 = li & 31;
      *(float4*)(xs + r*132 + c4*4) = *(const float4*)(x + (size_t)(t0+r)*HD + ck*128 + c4*4);
    }
    __syncthreads();
    #pragma unroll
    for (int k4 = 0; k4 < 16; ++k4) {
      float4 xv = *(const float4*)(xs + w*132 + half*64 + k4*4);
      float4 wv = *(const float4*)(gws + e*132 + half*64 + k4*4);
      acc += xv.x*wv.x + xv.y*wv.y + xv.z*wv.z + xv.w*wv.w;
    }
    __syncthreads();
  }
  float p = acc;
  p += __shfl_down(p, 32);
  float logit = (lane < 32) ? p : -INFINITY;
  float m = logit;
  #pragma unroll
  for (int o = 32; o >= 1; o >>= 1) m = fmaxf(m, __shfl_xor(m, o));
  float ex = (lane < 32) ? expf(logit - m) : 0.f;
  float se = ex;
  #pragma unroll
  for (int o = 32; o >= 1; o >>= 1) se += __shfl_xor(se, o);
  float score = ex / se;

  bool taken = false;
  float selw[4]; int seli[4];
  for (int k = 0; k < 4; ++k) {
    float cur = (lane < 32 && !taken) ? score : -1.f;
    float mm = cur;
    #pragma unroll
    for (int o = 32; o >= 1; o >>= 1) mm = fmaxf(mm, __shfl_xor(mm, o));
    unsigned long long b = __ballot(cur == mm);
    int il = __ffsll(b) - 1;
    if (lane == il) taken = true;
    selw[k] = mm; seli[k] = il;
  }
  float wsum = selw[0]+selw[1]+selw[2]+selw[3] + 1e-20f;
  int t = t0 + w;
  if (lane < 4) {
    topk_idx[t*4+lane] = seli[lane];
    topk_w[t*4+lane]  = selw[lane] / wsum;
    atomicAdd(&cnt[seli[lane]], 1);
  }
}

__global__ void scan_kernel(const int* __restrict__ cnt, int* __restrict__ offA)
{
  if (threadIdx.x == 0) {
    int a = 0;
    for (int e = 0; e < NEXP; ++e) { offA[e] = a; a += cnt[e]; }
    offA[NEXP] = a;
  }
}

__global__ __launch_bounds__(256) void scatter_kernel(
    const int* __restrict__ topk_idx, const float* __restrict__ topk_w,
    const int* __restrict__ offA, int* __restrict__ fill,
    int* __restrict__ list_tok, int* __restrict__ slot_of)
{
  int t = blockIdx.x*256 + threadIdx.x;
  if (t >= T_TOK) return;
  #pragma unroll
  for (int k = 0; k < 4; ++k) {
    int e = topk_idx[t*4+k];
    int pos = atomicAdd(&fill[e], 1);
    int s = offA[e] + pos;
    list_tok[s] = t;
    slot_of[t*4+k] = s;     // inverse map for non-atomic combine
  }
}

// ------------------------------------------------- R projections (pipelined)
// Y[T,128] = Xb[T,2048] @ W[128,2048]^T. A via gll dbuf; B-frags from global (L2-hot).
__global__ __launch_bounds__(256) void rproj_kernel(
    const ushort_t* __restrict__ xb,
    const ushort_t* __restrict__ Rg, const ushort_t* __restrict__ Ru,
    const ushort_t* __restrict__ sRg, const ushort_t* __restrict__ sRu,
    ushort_t* __restrict__ rg, ushort_t* __restrict__ ru,
    ushort_t* __restrict__ sa, ushort_t* __restrict__ su)
{
  __shared__ ushort_t abuf[2][64*128];
  const ushort_t* W; ushort_t* Y;
  switch (blockIdx.y) {
    case 0:  W = Rg;  Y = rg; break;
    case 1:  W = Ru;  Y = ru; break;
    case 2:  W = sRg; Y = sa; break;
    default: W = sRu; Y = su; break;
  }
  const int tid = threadIdx.x;
  const int lane = tid & 63, ln = lane & 15, q = lane >> 4;
  const int wv = tid >> 6, mh = wv >> 1, nh = wv & 1;
  const int r0 = blockIdx.x * 64;

  f32x4 acc[2][4];
  #pragma unroll
  for (int i = 0; i < 2; ++i)
    #pragma unroll
    for (int j = 0; j < 4; ++j) acc[i][j] = (f32x4){0.f,0.f,0.f,0.f};

  load_64x128_swz(xb + (size_t)r0*HD, HD, abuf[0], tid);
  for (int kt = 0; kt < 16; ++kt) {
    __syncthreads();                       // abuf[kt&1] ready
    if (kt+1 < 16)
      load_64x128_swz(xb + (size_t)r0*HD + (kt+1)*128, HD, abuf[(kt+1)&1], tid);
    const ushort_t* A = abuf[kt&1];
    #pragma unroll
    for (int c = 0; c < 4; ++c) {
      short8 a[2], b[4];
      #pragma unroll
      for (int i = 0; i < 2; ++i) {
        int rr = mh*32 + i*16 + ln;
        a[i] = *(const short8*)(A + rr*128 + (((c*4+q) ^ (rr&15)) << 3));
      }
      #pragma unroll
      for (int j = 0; j < 4; ++j)
        b[j] = *(const short8*)(W + (size_t)(nh*64 + j*16 + ln)*HD + kt*128 + c*32 + q*8);
      #pragma unroll
      for (int i = 0; i < 2; ++i)
        #pragma unroll
        for (int j = 0; j < 4; ++j) acc[i][j] = MF(a[i], b[j], acc[i][j]);
    }
  }
  #pragma unroll
  for (int i = 0; i < 2; ++i)
    #pragma unroll
    for (int j = 0; j < 4; ++j)
      #pragma unroll
      for (int r = 0; r < 4; ++r)
        Y[(size_t)(r0 + mh*32 + i*16 + q*4 + r)*128 + nh*64 + j*16 + ln] = f2b(acc[i][j][r]);
}

// -------- helper (cold path): acc = A_lds[64][SRK] @ Wg[128][128]^T, C in regs
__device__ __forceinline__ void gemm64x128_regs(
    int tid, const ushort_t* __restrict__ A, const ushort_t* __restrict__ Wg,
    ushort_t* __restrict__ stage, f32x4 acc[2][2][2])
{
  const int lane = tid & 63, ln = lane & 15, q = lane >> 4;
  const int wv = tid >> 6, mh = wv >> 1, nh = wv & 1;
  #pragma unroll
  for (int h = 0; h < 2; ++h)
    #pragma unroll
    for (int i = 0; i < 2; ++i)
      #pragma unroll
      for (int j = 0; j < 2; ++j) acc[h][i][j] = (f32x4){0.f,0.f,0.f,0.f};
  for (int h = 0; h < 2; ++h) {
    for (int li = tid; li < 64*16; li += 256) {
      int r = li >> 4, c = (li & 15) << 3;
      *(short8*)(stage + r*SRK + c) = *(const short8*)(Wg + (size_t)(h*64 + r)*128 + c);
    }
    __syncthreads();
    #pragma unroll
    for (int c = 0; c < 4; ++c) {
      short8 a[2], b[2];
      #pragma unroll
      for (int i = 0; i < 2; ++i)
        a[i] = *(const short8*)(A + (mh*32 + i*16 + ln)*SRK + c*32 + q*8);
      #pragma unroll
      for (int j = 0; j < 2; ++j)
        b[j] = *(const short8*)(stage + (nh*32 + j*16 + ln)*SRK + c*32 + q*8);
      #pragma unroll
      for (int i = 0; i < 2; ++i)
        #pragma unroll
        for (int j = 0; j < 2; ++j) acc[h][i][j] = MF(a[i], b[j], acc[h][i][j]);
    }
    __syncthreads();
  }
}

// ---------------------------------------------------------------- pair_proj
// t1[slot] = rg[tok(slot)] @ Ug_e^T ; t2 = ru @ Uu_e^T ; shared rows direct.
__global__ __launch_bounds__(256) void pair_proj_kernel(
    const ushort_t* __restrict__ rgb, const ushort_t* __restrict__ rub,
    const ushort_t* __restrict__ sab, const ushort_t* __restrict__ sub,
    const ushort_t* __restrict__ Ug, const ushort_t* __restrict__ Uu,
    const ushort_t* __restrict__ sUg, const ushort_t* __restrict__ sUu,
    const int* __restrict__ offA, const int* __restrict__ cntA,
    const int* __restrict__ list_tok,
    ushort_t* __restrict__ t1R, ushort_t* __restrict__ t2R,
    ushort_t* __restrict__ t1S, ushort_t* __restrict__ t2S)
{
  __shared__ ushort_t ldsX[64*SRK];
  __shared__ ushort_t stage[64*SRK];
  __shared__ int toks[64];
  const int tid = threadIdx.x;
  const int by = blockIdx.y;
  const bool shm = (by == NEXP);
  const int nrows = shm ? T_TOK : cntA[by];
  const int s0 = blockIdx.x * 64;
  if (s0 >= nrows) return;
  const int base = shm ? 0 : offA[by];
  const ushort_t* pUg = shm ? sUg : Ug + (size_t)by*128*128;
  const ushort_t* pUu = shm ? sUu : Uu + (size_t)by*128*128;
  const int lane = tid & 63, ln = lane & 15, q = lane >> 4;
  const int wv = tid >> 6, mh = wv >> 1, nh = wv & 1;

  if (tid < 64) {
    int sc = s0 + tid; if (sc > nrows-1) sc = nrows-1;
    toks[tid] = shm ? sc : list_tok[base + sc];
  }
  __syncthreads();

  f32x4 acc[2][2][2];
  // t1
  for (int li = tid; li < 64*16; li += 256) {
    int r = li >> 4, c = (li & 15) << 3;
    const ushort_t* src = shm ? sab : rgb;
    *(short8*)(ldsX + r*SRK + c) = *(const short8*)(src + (size_t)toks[r]*128 + c);
  }
  __syncthreads();
  gemm64x128_regs(tid, ldsX, pUg, stage, acc);
  {
    ushort_t* dst = shm ? t1S : (t1R + (size_t)base*128);
    #pragma unroll
    for (int h = 0; h < 2; ++h)
      #pragma unroll
      for (int i = 0; i < 2; ++i)
        #pragma unroll
        for (int r = 0; r < 4; ++r) {
          int gs = s0 + mh*32 + i*16 + q*4 + r;
          if (gs < nrows) {
            #pragma unroll
            for (int j = 0; j < 2; ++j)
              dst[(size_t)gs*128 + h*64 + nh*32 + j*16 + ln] = f2b(acc[h][i][j][r]);
          }
        }
  }
  // t2
  for (int li = tid; li < 64*16; li += 256) {
    int r = li >> 4, c = (li & 15) << 3;
    const ushort_t* src = shm ? sub : rub;
    *(short8*)(ldsX + r*SRK + c) = *(const short8*)(src + (size_t)toks[r]*128 + c);
  }
  __syncthreads();
  gemm64x128_regs(tid, ldsX, pUu, stage, acc);
  {
    ushort_t* dst = shm ? t2S : (t2R + (size_t)base*128);
    #pragma unroll
    for (int h = 0; h < 2; ++h)
      #pragma unroll
      for (int i = 0; i < 2; ++i)
        #pragma unroll
        for (int r = 0; r < 4; ++r) {
          int gs = s0 + mh*32 + i*16 + q*4 + r;
          if (gs < nrows) {
            #pragma unroll
            for (int j = 0; j < 2; ++j)
              dst[(size_t)gs*128 + h*64 + nh*32 + j*16 + ln] = f2b(acc[h][i][j][r]);
          }
        }
  }
}

// ---------------------------------------------------------------- mid (v3 hybrid, launch-bounds-calibrated)
// grid (64, 33, 4). Cg/Cu gll-staged in LDS; Rd B-frags DIRECT from global
// (L2-resident, shared across experts). LDS 40KB. XCD swizzle.
// EMPIRICAL launch_bounds calibration on this toolchain (3 datapoints):
//   arg n -> VGPR cap ~256/n: (256,2)->112used, (256,3)->84 SPILL, (256,4)->64 SPILL.
// Kernel needs ~112 VGPR -> (256,2) is the only no-spill setting. At VGPR<=128
// HW allows 4 waves/SIMD and LDS 40KB allows 4 blocks/CU -> occupancy target
// achieved WITHOUT spilling (r4/r5's spill storms: WRITE 91/59MB vs 25MB own).
__global__ __launch_bounds__(256, 2) void mid_kernel(
    const ushort_t* __restrict__ t1R, const ushort_t* __restrict__ t2R,
    const ushort_t* __restrict__ t1S, const ushort_t* __restrict__ t2S,
    const ushort_t* __restrict__ Cg, const ushort_t* __restrict__ Cu,
    const ushort_t* __restrict__ Rd,
    const ushort_t* __restrict__ sCg, const ushort_t* __restrict__ sCu,
    const ushort_t* __restrict__ sRd,
    const int* __restrict__ offA, const int* __restrict__ cntA,
    float* __restrict__ rdRp, float* __restrict__ rdSp)
{
  __shared__ ushort_t ldsCg[64*128];   // 16 KB
  __shared__ ushort_t ldsCu[64*128];   // 16 KB
  __shared__ ushort_t ldsH [64*64];    //  8 KB

  // XCD swizzle: 64*33*4 = 8448, 8448/8 = 1056 (bijective).
  const int hh = blockIdx.x + 64*(blockIdx.y + 33*blockIdx.z);
  const int L = (hh & 7) * 1056 + (hh >> 3);
  const int bx  = L & 63;
  const int rem = L >> 6;          // 0..131
  const int by  = rem % 33;
  const int bz  = rem / 33;

  const bool shm = (by == NEXP);
  if (bz >= (shm ? 4 : 2)) return;
  const int nrows = shm ? T_TOK : cntA[by];
  const int s0 = bx * 64;
  if (s0 >= nrows) return;
  const int base = shm ? 0 : offA[by];
  const int Ifull = shm ? ISH : IR;
  const ushort_t* pCg = shm ? sCg : Cg + (size_t)by*IR*128;
  const ushort_t* pCu = shm ? sCu : Cu + (size_t)by*IR*128;
  const ushort_t* pRd = shm ? sRd : Rd;

  const int tid = threadIdx.x;
  const int lane = tid & 63, ln = lane & 15, q = lane >> 4;
  const int wv = tid >> 6, mh = wv >> 1, nh = wv & 1;
  const int it0 = bz * MTILES;

  // t1/t2 A-fragments -> registers (held across the whole K loop)
  short8 t1f[2][4], t2f[2][4];
  const ushort_t* srcT1 = shm ? t1S : (t1R + (size_t)base*128);
  const ushort_t* srcT2 = shm ? t2S : (t2R + (size_t)base*128);
  #pragma unroll
  for (int i = 0; i < 2; ++i) {
    int r = s0 + mh*32 + i*16 + ln; if (r > nrows-1) r = nrows-1;
    #pragma unroll
    for (int c = 0; c < 4; ++c) {
      t1f[i][c] = *(const short8*)(srcT1 + (size_t)r*128 + c*32 + q*8);
      t2f[i][c] = *(const short8*)(srcT2 + (size_t)r*128 + c*32 + q*8);
    }
  }

  load_64x128_swz(pCg + (size_t)it0*64*128, 128, ldsCg, tid);
  load_64x128_swz(pCu + (size_t)it0*64*128, 128, ldsCu, tid);

  f32x4 rdacc[2][4];
  #pragma unroll
  for (int i = 0; i < 2; ++i)
    #pragma unroll
    for (int j = 0; j < 4; ++j) rdacc[i][j] = (f32x4){0.f,0.f,0.f,0.f};

  // invariant per-lane Rd offset: row (nh*64+ln), chunk q
  const size_t rdRow = (size_t)(nh*64 + ln)*Ifull + q*8;   // + j*16*Ifull + i0 + c2*32

  __syncthreads();   // Cg/Cu tile 0 ready (gll drained by barrier)

  for (int it = 0; it < MTILES; ++it) {
    const int i0 = (it0 + it) * 64;
    // phase A: g,u MFMA from regs x ldsCg/Cu; silu; h -> ldsH
    f32x4 g[2][2], u[2][2];
    #pragma unroll
    for (int i = 0; i < 2; ++i)
      #pragma unroll
      for (int j = 0; j < 2; ++j) { g[i][j] = (f32x4){0.f,0.f,0.f,0.f}; u[i][j] = (f32x4){0.f,0.f,0.f,0.f}; }
    #pragma unroll
    for (int c = 0; c < 4; ++c) {
      #pragma unroll
      for (int j = 0; j < 2; ++j) {
        int rr = nh*32 + j*16 + ln;
        int off = rr*128 + (((c*4+q) ^ (rr&15)) << 3);
        short8 bg = *(const short8*)(ldsCg + off);
        short8 bu = *(const short8*)(ldsCu + off);
        #pragma unroll
        for (int i = 0; i < 2; ++i) {
          g[i][j] = MF(t1f[i][c], bg, g[i][j]);
          u[i][j] = MF(t2f[i][c], bu, u[i][j]);
        }
      }
    }
    #pragma unroll
    for (int i = 0; i < 2; ++i)
      #pragma unroll
      for (int j = 0; j < 2; ++j)
        #pragma unroll
        for (int r = 0; r < 4; ++r) {
          float gv = g[i][j][r];
          gv = gv / (1.f + __expf(-gv));
          float hv = gv * u[i][j][r];
          int hr = mh*32 + i*16 + q*4 + r;
          int hc = nh*32 + j*16 + ln;
          ldsH[hr*64 + (((hc>>3) ^ (hr&7)) << 3) + (hc&7)] = f2b(hv);
        }
    __syncthreads();   // h visible; all Cg/Cu reads done
    // phase B: issue Cg/Cu(it+1) gll (overwrite safe); rd += h @ Rd^T (Rd direct)
    if (it+1 < MTILES) {
      load_64x128_swz(pCg + (size_t)(i0+64)*128, 128, ldsCg, tid);
      load_64x128_swz(pCu + (size_t)(i0+64)*128, 128, ldsCu, tid);
    }
    #pragma unroll
    for (int c2 = 0; c2 < 2; ++c2) {
      short8 a[2];
      #pragma unroll
      for (int i = 0; i < 2; ++i) {
        int rr = mh*32 + i*16 + ln;
        a[i] = *(const short8*)(ldsH + rr*64 + (((c2*4+q) ^ (rr&7)) << 3));
      }
      #pragma unroll
      for (int j = 0; j < 4; ++j) {
        short8 b = *(const short8*)(pRd + rdRow + (size_t)(j*16)*Ifull + i0 + c2*32);
        #pragma unroll
        for (int i = 0; i < 2; ++i) rdacc[i][j] = MF(a[i], b, rdacc[i][j]);
      }
    }
    __syncthreads();   // Cg/Cu(it+1) landed; ldsH reads done
  }

  // plain disjoint stores (no atomics): part bz of 2 (routed) or 4 (shared)
  float* dst = shm ? (rdSp + (size_t)bz*T_TOK*128)
                   : (rdRp + (size_t)bz*NPAIR*128 + (size_t)base*128);
  #pragma unroll
  for (int i = 0; i < 2; ++i) {
    #pragma unroll
    for (int r = 0; r < 4; ++r) {
      int gs = s0 + mh*32 + i*16 + q*4 + r;
      if (gs < nrows) {
        #pragma unroll
        for (int j = 0; j < 4; ++j)
          dst[(size_t)gs*128 + nh*64 + j*16 + ln] = rdacc[i][j][r];
      }
    }
  }
}

// ---------------------------------------------------------------- out
// grid (64, 33, 2). t3 frags in regs; Cd double-buffered via gll; 1 barrier/tile.
// XCD swizzle for Cd L2 locality. NO atomics: routed y -> ybufR (bf16, per-slot,
// unweighted); shared y -> out directly (fp32 plain stores; sole writer).
__global__ __launch_bounds__(256) void out_kernel(
    const float* __restrict__ rdRp, const float* __restrict__ rdSp,
    const ushort_t* __restrict__ Ud, const ushort_t* __restrict__ Cd,
    const ushort_t* __restrict__ sUd, const ushort_t* __restrict__ sCd,
    const int* __restrict__ offA, const int* __restrict__ cntA,
    ushort_t* __restrict__ ybufR, float* __restrict__ out)
{
  __shared__ ushort_t smem[3*64*SRK];   // prologue: ldsA | stage | ldsT ; loop: cd0,cd1
  ushort_t* ldsA  = smem;
  ushort_t* stage = smem + 64*SRK;
  ushort_t* ldsT  = smem + 2*64*SRK;
  ushort_t* cd0   = smem;
  ushort_t* cd1   = smem + 64*128;

  // XCD swizzle: 64*33*2 = 4224, 4224/8 = 528 (bijective).
  const int hh = blockIdx.x + 64*(blockIdx.y + 33*blockIdx.z);
  const int L = (hh & 7) * 528 + (hh >> 3);
  const int bx  = L & 63;
  const int rem = L >> 6;          // 0..65
  const int by  = rem % 33;
  const int bzz = rem / 33;

  const int tid = threadIdx.x;
  const bool shm = (by == NEXP);
  const int nrows = shm ? T_TOK : cntA[by];
  const int s0 = bx * 64;
  if (s0 >= nrows) return;
  const int base = shm ? 0 : offA[by];
  const int ct0 = bzz * 16;
  const ushort_t* pUd = shm ? sUd : Ud + (size_t)by*128*128;
  const ushort_t* pCd = shm ? sCd : Cd + (size_t)by*HD*128;

  const int lane = tid & 63, ln = lane & 15, q = lane >> 4;
  const int wv = tid >> 6, mh = wv >> 1, nh = wv & 1;

  // gather rd rows: sum the per-bz partials (fp32) -> bf16 ldsA
  for (int li = tid; li < 64*32; li += 256) {
    int r = li >> 5, c4 = li & 31;
    int row = s0 + r; if (row > nrows-1) row = nrows-1;
    float4 v;
    if (shm) {
      const float* p = rdSp + (size_t)row*128 + c4*4;
      v = *(const float4*)p;
      #pragma unroll
      for (int pp = 1; pp < 4; ++pp) {
        float4 w2 = *(const float4*)(p + (size_t)pp*T_TOK*128);
        v.x += w2.x; v.y += w2.y; v.z += w2.z; v.w += w2.w;
      }
    } else {
      const float* p = rdRp + (size_t)(base+row)*128 + c4*4;
      v = *(const float4*)p;
      float4 w2 = *(const float4*)(p + (size_t)NPAIR*128);
      v.x += w2.x; v.y += w2.y; v.z += w2.z; v.w += w2.w;
    }
    ushort4 o; o.x=f2b(v.x); o.y=f2b(v.y); o.z=f2b(v.z); o.w=f2b(v.w);
    *(ushort4*)(ldsA + r*SRK + c4*4) = o;
  }
  __syncthreads();

  f32x4 acc[2][2][2];
  gemm64x128_regs(tid, ldsA, pUd, stage, acc);
  // C -> ldsT (padded), then extract A-frags
  #pragma unroll
  for (int h = 0; h < 2; ++h)
    #pragma unroll
    for (int i = 0; i < 2; ++i)
      #pragma unroll
      for (int j = 0; j < 2; ++j)
        #pragma unroll
        for (int r = 0; r < 4; ++r)
          ldsT[(mh*32 + i*16 + q*4 + r)*SRK + h*64 + nh*32 + j*16 + ln] = f2b(acc[h][i][j][r]);
  __syncthreads();
  short8 t3f[2][4];
  #pragma unroll
  for (int i = 0; i < 2; ++i)
    #pragma unroll
    for (int c = 0; c < 4; ++c)
      t3f[i][c] = *(const short8*)(ldsT + (mh*32 + i*16 + ln)*SRK + c*32 + q*8);
  __syncthreads();   // smem free for cd buffers

  load_64x128_swz(pCd + (size_t)ct0*64*128, 128, cd0, tid);
  for (int tt = 0; tt < 16; ++tt) {
    __syncthreads();                      // cd[tt&1] ready; prior reads drained
    ushort_t* cur = (tt & 1) ? cd1 : cd0;
    ushort_t* nxt = (tt & 1) ? cd0 : cd1;
    if (tt+1 < 16)
      load_64x128_swz(pCd + (size_t)(ct0+tt+1)*64*128, 128, nxt, tid);
    f32x4 y[2][2];
    #pragma unroll
    for (int i = 0; i < 2; ++i)
      #pragma unroll
      for (int j = 0; j < 2; ++j) y[i][j] = (f32x4){0.f,0.f,0.f,0.f};
    #pragma unroll
    for (int c = 0; c < 4; ++c) {
      #pragma unroll
      for (int j = 0; j < 2; ++j) {
        int rr = nh*32 + j*16 + ln;
        short8 b = *(const short8*)(cur + rr*128 + (((c*4+q) ^ (rr&15)) << 3));
        #pragma unroll
        for (int i = 0; i < 2; ++i) y[i][j] = MF(t3f[i][c], b, y[i][j]);
      }
    }
    #pragma unroll
    for (int i = 0; i < 2; ++i) {
      #pragma unroll
      for (int r = 0; r < 4; ++r) {
        int lr = mh*32 + i*16 + q*4 + r;
        int gs = s0 + lr;
        if (gs < nrows) {
          if (shm) {
            size_t ob = (size_t)gs*HD + (ct0 + tt)*64;
            #pragma unroll
            for (int j = 0; j < 2; ++j)
              out[ob + nh*32 + j*16 + ln] = y[i][j][r];
          } else {
            size_t ob = (size_t)(base + gs)*HD + (ct0 + tt)*64;
            #pragma unroll
            for (int j = 0; j < 2; ++j)
              ybufR[ob + nh*32 + j*16 + ln] = f2b(y[i][j][r]);
          }
        }
      }
    }
  }
}

// ---------------------------------------------------------------- combine
// out[t] = out[t] (shared, already stored) + sum_k w_k * ybufR[slot_of[t,k]]
// One block per token row; fully coalesced, no atomics.
__global__ __launch_bounds__(256) void combine_kernel(
    const ushort_t* __restrict__ ybufR,
    const int* __restrict__ slot_of, const float* __restrict__ topk_w,
    float* __restrict__ out)
{
  __shared__ int   ss[4];
  __shared__ float ww[4];
  const int t = blockIdx.x;
  if (threadIdx.x < 4) {
    ss[threadIdx.x] = slot_of[t*4 + threadIdx.x];
    ww[threadIdx.x] = topk_w[t*4 + threadIdx.x];
  }
  __syncthreads();
  const int c = threadIdx.x * 8;
  const size_t tb = (size_t)t*HD + c;
  float o[8];
  float4 a0 = *(const float4*)(out + tb);
  float4 a1 = *(const float4*)(out + tb + 4);
  o[0]=a0.x; o[1]=a0.y; o[2]=a0.z; o[3]=a0.w;
  o[4]=a1.x; o[5]=a1.y; o[6]=a1.z; o[7]=a1.w;
  #pragma unroll
  for (int k = 0; k < 4; ++k) {
    short8 rv = *(const short8*)(ybufR + (size_t)ss[k]*HD + c);
    float wk = ww[k];
    #pragma unroll
    for (int u = 0; u < 8; ++u)
      o[u] += wk * b2f((ushort_t)rv[u]);
  }
  float4 b0 = {o[0],o[1],o[2],o[3]};
  float4 b1 = {o[4],o[5],o[6],o[7]};
  *(float4*)(out + tb)     = b0;
  *(float4*)(out + tb + 4) = b1;
}

// ---------------------------------------------------------------- launch
extern "C" void kernel_launch(void* const* d_in, const int* in_sizes, int n_in,
                              void* d_out, int out_size, void* d_ws, size_t ws_size,
                              hipStream_t stream) {
  const float* x    = (const float*)d_in[0];
  const float* gw   = (const float*)d_in[1];
  const float* Rg   = (const float*)d_in[2];
  const float* Ru   = (const float*)d_in[3];
  const float* Rd   = (const float*)d_in[4];
  const float* Ug   = (const float*)d_in[5];
  const float* Cg   = (const float*)d_in[6];
  const float* Uu   = (const float*)d_in[7];
  const float* Cu   = (const float*)d_in[8];
  const float* Ud   = (const float*)d_in[9];
  const float* Cd   = (const float*)d_in[10];
  const float* sRg  = (const float*)d_in[11];
  const float* sUg  = (const float*)d_in[12];
  const float* sCg  = (const float*)d_in[13];
  const float* sRu  = (const float*)d_in[14];
  const float* sUu  = (const float*)d_in[15];
  const float* sCu  = (const float*)d_in[16];
  const float* sRd  = (const float*)d_in[17];
  const float* sUd  = (const float*)d_in[18];
  const float* sCd  = (const float*)d_in[19];
  float* out = (float*)d_out;

  char* w = (char*)d_ws;
  auto alloc = [&](size_t bytes) -> void* {
    void* p = (void*)w; w += (bytes + 255) & ~(size_t)255; return p;
  };
  int*   cnt      = (int*)  alloc(NEXP*sizeof(int));
  int*   offA     = (int*)  alloc((NEXP+1)*sizeof(int));
  int*   fill     = (int*)  alloc(NEXP*sizeof(int));
  int*   topk_idx = (int*)  alloc((size_t)T_TOK*4*sizeof(int));
  float* topk_w   = (float*)alloc((size_t)T_TOK*4*sizeof(float));
  int*   list_tok = (int*)  alloc((size_t)NPAIR*sizeof(int));
  int*   slot_of  = (int*)  alloc((size_t)T_TOK*4*sizeof(int));
  ushort_t* xb   = (ushort_t*)alloc((size_t)T_TOK*HD*2);   // later reused as rdRp (fp32, 2 parts)
  ushort_t* Rgb  = (ushort_t*)alloc((size_t)128*HD*2);
  ushort_t* Rub  = (ushort_t*)alloc((size_t)128*HD*2);
  ushort_t* Rdb  = (ushort_t*)alloc((size_t)128*IR*2);
  ushort_t* Ugb  = (ushort_t*)alloc((size_t)NEXP*128*128*2);
  ushort_t* Cgb  = (ushort_t*)alloc((size_t)NEXP*IR*128*2);
  ushort_t* Uub  = (ushort_t*)alloc((size_t)NEXP*128*128*2);
  ushort_t* Cub  = (ushort_t*)alloc((size_t)NEXP*IR*128*2);
  ushort_t* Udb  = (ushort_t*)alloc((size_t)NEXP*128*128*2);
  ushort_t* Cdb  = (ushort_t*)alloc((size_t)NEXP*HD*128*2);
  ushort_t* sRgb = (ushort_t*)alloc((size_t)128*HD*2);
  ushort_t* sUgb = (ushort_t*)alloc((size_t)128*128*2);
  ushort_t* sCgb = (ushort_t*)alloc((size_t)ISH*128*2);
  ushort_t* sRub = (ushort_t*)alloc((size_t)128*HD*2);
  ushort_t* sUub = (ushort_t*)alloc((size_t)128*128*2);
  ushort_t* sCub = (ushort_t*)alloc((size_t)ISH*128*2);
  ushort_t* sRdb = (ushort_t*)alloc((size_t)128*ISH*2);
  ushort_t* sUdb = (ushort_t*)alloc((size_t)128*128*2);
  ushort_t* sCdb = (ushort_t*)alloc((size_t)HD*128*2);
  ushort_t* rg   = (ushort_t*)alloc((size_t)T_TOK*128*2);
  ushort_t* ru   = (ushort_t*)alloc((size_t)T_TOK*128*2);
  ushort_t* sa   = (ushort_t*)alloc((size_t)T_TOK*128*2);
  ushort_t* su   = (ushort_t*)alloc((size_t)T_TOK*128*2);
  ushort_t* t1R  = (ushort_t*)alloc((size_t)NPAIR*128*2);
  ushort_t* t2R  = (ushort_t*)alloc((size_t)NPAIR*128*2);
  ushort_t* t1S  = (ushort_t*)alloc((size_t)T_TOK*128*2);
  ushort_t* t2S  = (ushort_t*)alloc((size_t)T_TOK*128*2);
  float*    rdSp = (float*)   alloc((size_t)4*T_TOK*128*sizeof(float));  // 4 shared partials
  ushort_t* ybufR= (ushort_t*)alloc((size_t)NPAIR*HD*2);                 // per-slot routed y (bf16)
  (void)ws_size; (void)in_sizes; (void)n_in;

  // routed rd partials (fp32, 2 parts) alias xb exactly:
  // 2*NPAIR*128*4 = 16.78 MB == T_TOK*HD*2. xb is dead after rproj; mid writes it after.
  float* rdRp = (float*)xb;

  hipMemsetAsync(cnt,  0, NEXP*sizeof(int), stream);
  hipMemsetAsync(fill, 0, NEXP*sizeof(int), stream);
  // no out memset: out_kernel's shared path fully writes out; combine RMWs it.

  // fused cvt
  CvtSegs cs;
  const float* ss[NSEG] = {x,Rg,Ru,Rd,Ug,Cg,Uu,Cu,Ud,Cd,sRg,sUg,sCg,sRu,sUu,sCu,sRd,sUd,sCd};
  ushort_t* dd[NSEG] = {xb,Rgb,Rub,Rdb,Ugb,Cgb,Uub,Cub,Udb,Cdb,sRgb,sUgb,sCgb,sRub,sUub,sCub,sRdb,sUdb,sCdb};
  size_t nn[NSEG] = {(size_t)T_TOK*HD,(size_t)128*HD,(size_t)128*HD,(size_t)128*IR,
                     (size_t)NEXP*128*128,(size_t)NEXP*IR*128,(size_t)NEXP*128*128,(size_t)NEXP*IR*128,
                     (size_t)NEXP*128*128,(size_t)NEXP*HD*128,(size_t)128*HD,(size_t)128*128,
                     (size_t)ISH*128,(size_t)128*HD,(size_t)128*128,(size_t)ISH*128,
                     (size_t)128*ISH,(size_t)128*128,(size_t)HD*128};
  int tot_blk = 0;
  for (int k = 0; k < NSEG; ++k) {
    cs.s[k] = ss[k]; cs.d[k] = dd[k];
    cs.n4[k] = (int)(nn[k] >> 2);
    cs.blk0[k] = tot_blk;
    tot_blk += (cs.n4[k] + 255) / 256;
  }
  cs.blk0[NSEG] = tot_blk;
  cvt_all_kernel<<<tot_blk, 256, 0, stream>>>(cs);

  gate_kernel<<<T_TOK/4, 256, 0, stream>>>(x, gw, topk_idx, topk_w, cnt);
  scan_kernel<<<1, 64, 0, stream>>>(cnt, offA);
  scatter_kernel<<<T_TOK/256, 256, 0, stream>>>(topk_idx, topk_w, offA, fill, list_tok, slot_of);
  rproj_kernel<<<dim3(T_TOK/64, 4), 256, 0, stream>>>(xb, Rgb, Rub, sRgb, sRub, rg, ru, sa, su);
  pair_proj_kernel<<<dim3(64, NEXP+1), 256, 0, stream>>>(
      rg, ru, sa, su, Ugb, Uub, sUgb, sUub, offA, cnt, list_tok, t1R, t2R, t1S, t2S);
  mid_kernel<<<dim3(64, NEXP+1, 4), 256, 0, stream>>>(
      t1R, t2R, t1S, t2S, Cgb, Cub, Rdb, sCgb, sCub, sRdb, offA, cnt, rdRp, rdSp);
  out_kernel<<<dim3(64, NEXP+1, 2), 256, 0, stream>>>(
      rdRp, rdSp, Udb, Cdb, sUdb, sCdb, offA, cnt, ybufR, out);
  combine_kernel<<<T_TOK, 256, 0, stream>>>(ybufR, slot_of, topk_w, out);
}

// Round 7
// 587.171 us; speedup vs baseline: 1.3655x; 1.0345x over previous
//
#include <hip/hip_runtime.h>
#include <math.h>

#define T_TOK 4096
#define HD    2048
#define NEXP  32
#define IR    1408
#define ISH   2816
#define NPAIR (T_TOK*4)
#define SRK   136      // padded bf16 row stride (cold paths only)
#define MTILES 11      // I-tiles (of 64) per chunk: routed 2 chunks, shared 4

typedef unsigned short ushort_t;
typedef __attribute__((ext_vector_type(8))) short    short8;
typedef __attribute__((ext_vector_type(8))) __bf16   bf16x8;
typedef __attribute__((ext_vector_type(4))) float    f32x4;

__device__ __forceinline__ f32x4 MF(short8 a, short8 b, f32x4 c) {
  return __builtin_amdgcn_mfma_f32_16x16x32_bf16(
      __builtin_bit_cast(bf16x8, a), __builtin_bit_cast(bf16x8, b), c, 0, 0, 0);
}
__device__ __forceinline__ ushort_t f2b(float f) {
  unsigned u = __float_as_uint(f);
  unsigned r = (u + 0x7fffu + ((u >> 16) & 1u)) >> 16;   // RNE
  return (ushort_t)r;
}
__device__ __forceinline__ float b2f(ushort_t b) {
  return __uint_as_float(((unsigned)b) << 16);
}

// async global->LDS 16B; LDS dst must be wave-uniform base (+lane*16 implicit)
__device__ __forceinline__ void gll16(const ushort_t* g, ushort_t* l) {
  __builtin_amdgcn_global_load_lds(
      (const __attribute__((address_space(1))) unsigned int*)(const void*)g,
      (__attribute__((address_space(3))) unsigned int*)(void*)l, 16, 0, 0);
}

// ---- swizzled tile loader (XOR swizzle: phys chunk = logical ^ (row&mask)) ----
// 64 rows x 128 cols bf16 (16 chunks/row). One instr = 4 rows.
__device__ __forceinline__ void load_64x128_swz(
    const ushort_t* __restrict__ g, size_t gstride, ushort_t* lds, int tid)
{
  const int lane = tid & 63, w = tid >> 6;
  #pragma unroll
  for (int s = 0; s < 4; ++s) {
    int rbase = s*16 + w*4;
    int r = rbase + (lane >> 4);
    int p = lane & 15;
    gll16(g + (size_t)r*gstride + ((p ^ (r & 15)) << 3), lds + rbase*128);
  }
}
// read elem(row r, chunk c of 8hw): lds[r*128 + ((c^(r&15))<<3)]

// ---------------------------------------------------------------- fused cvt
#define NSEG 19
struct CvtSegs {
  const float* s[NSEG];
  ushort_t* d[NSEG];
  int n4[NSEG];
  int blk0[NSEG+1];
};
__global__ __launch_bounds__(256) void cvt_all_kernel(CvtSegs cs)
{
  int b = blockIdx.x;
  int k = 0;
  #pragma unroll 1
  while (k+1 < NSEG && b >= cs.blk0[k+1]) ++k;
  int i = (b - cs.blk0[k])*256 + threadIdx.x;
  if (i < cs.n4[k]) {
    float4 v = ((const float4*)cs.s[k])[i];
    ushort4 o; o.x=f2b(v.x); o.y=f2b(v.y); o.z=f2b(v.z); o.w=f2b(v.w);
    ((ushort4*)cs.d[k])[i] = o;
  }
}

// ---------------------------------------------------------------- gate
// 4 tokens/block (4 waves); gw staged through LDS per 128-k chunk.
__global__ __launch_bounds__(256) void gate_kernel(
    const float* __restrict__ x, const float* __restrict__ gw,
    int* __restrict__ topk_idx, float* __restrict__ topk_w, int* __restrict__ cnt)
{
  __shared__ float gws[32*132];
  __shared__ float xs[4*132];
  const int tid = threadIdx.x;
  const int w = tid >> 6, lane = tid & 63;
  const int t0 = blockIdx.x * 4;
  const int e = lane & 31, half = lane >> 5;

  float acc = 0.f;
  for (int ck = 0; ck < HD/128; ++ck) {
    for (int li = tid; li < 1024; li += 256) {        // gw chunk 32x128
      int r = li >> 5, c4 = li & 31;
      *(float4*)(gws + r*132 + c4*4) = *(const float4*)(gw + (size_t)r*HD + ck*128 + c4*4);
    }
    for (int li = tid; li < 128; li += 256) {          // x chunk 4x128
      int r = li >> 5, c4 = li & 31;
      *(float4*)(xs + r*132 + c4*4) = *(const float4*)(x + (size_t)(t0+r)*HD + ck*128 + c4*4);
    }
    __syncthreads();
    #pragma unroll
    for (int k4 = 0; k4 < 16; ++k4) {
      float4 xv = *(const float4*)(xs + w*132 + half*64 + k4*4);
      float4 wv = *(const float4*)(gws + e*132 + half*64 + k4*4);
      acc += xv.x*wv.x + xv.y*wv.y + xv.z*wv.z + xv.w*wv.w;
    }
    __syncthreads();
  }
  float p = acc;
  p += __shfl_down(p, 32);
  float logit = (lane < 32) ? p : -INFINITY;
  float m = logit;
  #pragma unroll
  for (int o = 32; o >= 1; o >>= 1) m = fmaxf(m, __shfl_xor(m, o));
  float ex = (lane < 32) ? expf(logit - m) : 0.f;
  float se = ex;
  #pragma unroll
  for (int o = 32; o >= 1; o >>= 1) se += __shfl_xor(se, o);
  float score = ex / se;

  bool taken = false;
  float selw[4]; int seli[4];
  for (int k = 0; k < 4; ++k) {
    float cur = (lane < 32 && !taken) ? score : -1.f;
    float mm = cur;
    #pragma unroll
    for (int o = 32; o >= 1; o >>= 1) mm = fmaxf(mm, __shfl_xor(mm, o));
    unsigned long long b = __ballot(cur == mm);
    int il = __ffsll(b) - 1;
    if (lane == il) taken = true;
    selw[k] = mm; seli[k] = il;
  }
  float wsum = selw[0]+selw[1]+selw[2]+selw[3] + 1e-20f;
  int t = t0 + w;
  if (lane < 4) {
    topk_idx[t*4+lane] = seli[lane];
    topk_w[t*4+lane]  = selw[lane] / wsum;
    atomicAdd(&cnt[seli[lane]], 1);
  }
}

__global__ void scan_kernel(const int* __restrict__ cnt, int* __restrict__ offA)
{
  if (threadIdx.x == 0) {
    int a = 0;
    for (int e = 0; e < NEXP; ++e) { offA[e] = a; a += cnt[e]; }
    offA[NEXP] = a;
  }
}

__global__ __launch_bounds__(256) void scatter_kernel(
    const int* __restrict__ topk_idx, const float* __restrict__ topk_w,
    const int* __restrict__ offA, int* __restrict__ fill,
    int* __restrict__ list_tok, int* __restrict__ slot_of)
{
  int t = blockIdx.x*256 + threadIdx.x;
  if (t >= T_TOK) return;
  #pragma unroll
  for (int k = 0; k < 4; ++k) {
    int e = topk_idx[t*4+k];
    int pos = atomicAdd(&fill[e], 1);
    int s = offA[e] + pos;
    list_tok[s] = t;
    slot_of[t*4+k] = s;     // inverse map for non-atomic combine
  }
}

// ------------------------------------------------- R projections (pipelined)
// Y[T,128] = Xb[T,2048] @ W[128,2048]^T. A via gll dbuf; B-frags from global (L2-hot).
__global__ __launch_bounds__(256) void rproj_kernel(
    const ushort_t* __restrict__ xb,
    const ushort_t* __restrict__ Rg, const ushort_t* __restrict__ Ru,
    const ushort_t* __restrict__ sRg, const ushort_t* __restrict__ sRu,
    ushort_t* __restrict__ rg, ushort_t* __restrict__ ru,
    ushort_t* __restrict__ sa, ushort_t* __restrict__ su)
{
  __shared__ ushort_t abuf[2][64*128];
  const ushort_t* W; ushort_t* Y;
  switch (blockIdx.y) {
    case 0:  W = Rg;  Y = rg; break;
    case 1:  W = Ru;  Y = ru; break;
    case 2:  W = sRg; Y = sa; break;
    default: W = sRu; Y = su; break;
  }
  const int tid = threadIdx.x;
  const int lane = tid & 63, ln = lane & 15, q = lane >> 4;
  const int wv = tid >> 6, mh = wv >> 1, nh = wv & 1;
  const int r0 = blockIdx.x * 64;

  f32x4 acc[2][4];
  #pragma unroll
  for (int i = 0; i < 2; ++i)
    #pragma unroll
    for (int j = 0; j < 4; ++j) acc[i][j] = (f32x4){0.f,0.f,0.f,0.f};

  load_64x128_swz(xb + (size_t)r0*HD, HD, abuf[0], tid);
  for (int kt = 0; kt < 16; ++kt) {
    __syncthreads();                       // abuf[kt&1] ready
    if (kt+1 < 16)
      load_64x128_swz(xb + (size_t)r0*HD + (kt+1)*128, HD, abuf[(kt+1)&1], tid);
    const ushort_t* A = abuf[kt&1];
    #pragma unroll
    for (int c = 0; c < 4; ++c) {
      short8 a[2], b[4];
      #pragma unroll
      for (int i = 0; i < 2; ++i) {
        int rr = mh*32 + i*16 + ln;
        a[i] = *(const short8*)(A + rr*128 + (((c*4+q) ^ (rr&15)) << 3));
      }
      #pragma unroll
      for (int j = 0; j < 4; ++j)
        b[j] = *(const short8*)(W + (size_t)(nh*64 + j*16 + ln)*HD + kt*128 + c*32 + q*8);
      #pragma unroll
      for (int i = 0; i < 2; ++i)
        #pragma unroll
        for (int j = 0; j < 4; ++j) acc[i][j] = MF(a[i], b[j], acc[i][j]);
    }
  }
  #pragma unroll
  for (int i = 0; i < 2; ++i)
    #pragma unroll
    for (int j = 0; j < 4; ++j)
      #pragma unroll
      for (int r = 0; r < 4; ++r)
        Y[(size_t)(r0 + mh*32 + i*16 + q*4 + r)*128 + nh*64 + j*16 + ln] = f2b(acc[i][j][r]);
}

// -------- helper (cold path): acc = A_lds[64][SRK] @ Wg[128][128]^T, C in regs
__device__ __forceinline__ void gemm64x128_regs(
    int tid, const ushort_t* __restrict__ A, const ushort_t* __restrict__ Wg,
    ushort_t* __restrict__ stage, f32x4 acc[2][2][2])
{
  const int lane = tid & 63, ln = lane & 15, q = lane >> 4;
  const int wv = tid >> 6, mh = wv >> 1, nh = wv & 1;
  #pragma unroll
  for (int h = 0; h < 2; ++h)
    #pragma unroll
    for (int i = 0; i < 2; ++i)
      #pragma unroll
      for (int j = 0; j < 2; ++j) acc[h][i][j] = (f32x4){0.f,0.f,0.f,0.f};
  for (int h = 0; h < 2; ++h) {
    for (int li = tid; li < 64*16; li += 256) {
      int r = li >> 4, c = (li & 15) << 3;
      *(short8*)(stage + r*SRK + c) = *(const short8*)(Wg + (size_t)(h*64 + r)*128 + c);
    }
    __syncthreads();
    #pragma unroll
    for (int c = 0; c < 4; ++c) {
      short8 a[2], b[2];
      #pragma unroll
      for (int i = 0; i < 2; ++i)
        a[i] = *(const short8*)(A + (mh*32 + i*16 + ln)*SRK + c*32 + q*8);
      #pragma unroll
      for (int j = 0; j < 2; ++j)
        b[j] = *(const short8*)(stage + (nh*32 + j*16 + ln)*SRK + c*32 + q*8);
      #pragma unroll
      for (int i = 0; i < 2; ++i)
        #pragma unroll
        for (int j = 0; j < 2; ++j) acc[h][i][j] = MF(a[i], b[j], acc[h][i][j]);
    }
    __syncthreads();
  }
}

// ---------------------------------------------------------------- pair_proj
// t1[slot] = rg[tok(slot)] @ Ug_e^T ; t2 = ru @ Uu_e^T ; shared rows direct.
__global__ __launch_bounds__(256) void pair_proj_kernel(
    const ushort_t* __restrict__ rgb, const ushort_t* __restrict__ rub,
    const ushort_t* __restrict__ sab, const ushort_t* __restrict__ sub,
    const ushort_t* __restrict__ Ug, const ushort_t* __restrict__ Uu,
    const ushort_t* __restrict__ sUg, const ushort_t* __restrict__ sUu,
    const int* __restrict__ offA, const int* __restrict__ cntA,
    const int* __restrict__ list_tok,
    ushort_t* __restrict__ t1R, ushort_t* __restrict__ t2R,
    ushort_t* __restrict__ t1S, ushort_t* __restrict__ t2S)
{
  __shared__ ushort_t ldsX[64*SRK];
  __shared__ ushort_t stage[64*SRK];
  __shared__ int toks[64];
  const int tid = threadIdx.x;
  const int by = blockIdx.y;
  const bool shm = (by == NEXP);
  const int nrows = shm ? T_TOK : cntA[by];
  const int s0 = blockIdx.x * 64;
  if (s0 >= nrows) return;
  const int base = shm ? 0 : offA[by];
  const ushort_t* pUg = shm ? sUg : Ug + (size_t)by*128*128;
  const ushort_t* pUu = shm ? sUu : Uu + (size_t)by*128*128;
  const int lane = tid & 63, ln = lane & 15, q = lane >> 4;
  const int wv = tid >> 6, mh = wv >> 1, nh = wv & 1;

  if (tid < 64) {
    int sc = s0 + tid; if (sc > nrows-1) sc = nrows-1;
    toks[tid] = shm ? sc : list_tok[base + sc];
  }
  __syncthreads();

  f32x4 acc[2][2][2];
  // t1
  for (int li = tid; li < 64*16; li += 256) {
    int r = li >> 4, c = (li & 15) << 3;
    const ushort_t* src = shm ? sab : rgb;
    *(short8*)(ldsX + r*SRK + c) = *(const short8*)(src + (size_t)toks[r]*128 + c);
  }
  __syncthreads();
  gemm64x128_regs(tid, ldsX, pUg, stage, acc);
  {
    ushort_t* dst = shm ? t1S : (t1R + (size_t)base*128);
    #pragma unroll
    for (int h = 0; h < 2; ++h)
      #pragma unroll
      for (int i = 0; i < 2; ++i)
        #pragma unroll
        for (int r = 0; r < 4; ++r) {
          int gs = s0 + mh*32 + i*16 + q*4 + r;
          if (gs < nrows) {
            #pragma unroll
            for (int j = 0; j < 2; ++j)
              dst[(size_t)gs*128 + h*64 + nh*32 + j*16 + ln] = f2b(acc[h][i][j][r]);
          }
        }
  }
  // t2
  for (int li = tid; li < 64*16; li += 256) {
    int r = li >> 4, c = (li & 15) << 3;
    const ushort_t* src = shm ? sub : rub;
    *(short8*)(ldsX + r*SRK + c) = *(const short8*)(src + (size_t)toks[r]*128 + c);
  }
  __syncthreads();
  gemm64x128_regs(tid, ldsX, pUu, stage, acc);
  {
    ushort_t* dst = shm ? t2S : (t2R + (size_t)base*128);
    #pragma unroll
    for (int h = 0; h < 2; ++h)
      #pragma unroll
      for (int i = 0; i < 2; ++i)
        #pragma unroll
        for (int r = 0; r < 4; ++r) {
          int gs = s0 + mh*32 + i*16 + q*4 + r;
          if (gs < nrows) {
            #pragma unroll
            for (int j = 0; j < 2; ++j)
              dst[(size_t)gs*128 + h*64 + nh*32 + j*16 + ln] = f2b(acc[h][i][j][r]);
          }
        }
  }
}

// ---------------------------------------------------------------- mid (v5: 1-barrier pipeline + balanced XCD map)
// grid (64, 33, 4). Cg/Cu DOUBLE-buffered via gll (prefetch covered by a full
// iteration of compute: 48 MFMA + silu, vs ~16 MFMA before); ldsH double-buffered
// so phaseB(it-1) runs in the same inter-barrier window as phaseA(it) ->
// ONE barrier per I-tile (was 2). Rd B-frags preloaded to regs at iteration top
// (L2-resident; latency covered by phaseA). LDS 80KB -> 2 blocks/CU.
// Balanced XCD map: XCD x gets experts e%8==x (4 routed each + 1/8 of shared)
// -- the old range-swizzle left XCD4/XCD6 with ZERO active blocks.
// launch_bounds (256,1): VGPR cap 256 (empirical: cap=256/n); needs ~150, no spill.
__global__ __launch_bounds__(256, 1) void mid_kernel(
    const ushort_t* __restrict__ t1R, const ushort_t* __restrict__ t2R,
    const ushort_t* __restrict__ t1S, const ushort_t* __restrict__ t2S,
    const ushort_t* __restrict__ Cg, const ushort_t* __restrict__ Cu,
    const ushort_t* __restrict__ Rd,
    const ushort_t* __restrict__ sCg, const ushort_t* __restrict__ sCu,
    const ushort_t* __restrict__ sRd,
    const int* __restrict__ offA, const int* __restrict__ cntA,
    float* __restrict__ rdRp, float* __restrict__ rdSp)
{
  __shared__ ushort_t ldsCg[2][64*128];   // 32 KB
  __shared__ ushort_t ldsCu[2][64*128];   // 32 KB
  __shared__ ushort_t ldsH [2][64*64];    // 16 KB  -> 80 KB total

  // balanced expert-clustered XCD map (8448 blocks, 1056 per XCD):
  //   XCD x: routed m<1024: by=(m>>8)*8+x, bz=(m>>6)&3, bx=m&63
  //          shared m>=1024: by=32, bz=(m-1024)>>3, bx=((m-1024)&7)*8+x
  const int hh = blockIdx.x + 64*(blockIdx.y + 33*blockIdx.z);
  const int xc = hh & 7, m = hh >> 3;
  int bx, by, bz;
  if (m < 1024) { by = (m >> 8)*8 + xc; bz = (m >> 6) & 3; bx = m & 63; }
  else          { int mm = m - 1024; by = NEXP; bz = mm >> 3; bx = ((mm & 7) << 3) + xc; }

  const bool shm = (by == NEXP);
  if (bz >= (shm ? 4 : 2)) return;
  const int nrows = shm ? T_TOK : cntA[by];
  const int s0 = bx * 64;
  if (s0 >= nrows) return;
  const int base = shm ? 0 : offA[by];
  const int Ifull = shm ? ISH : IR;
  const ushort_t* pCg = shm ? sCg : Cg + (size_t)by*IR*128;
  const ushort_t* pCu = shm ? sCu : Cu + (size_t)by*IR*128;
  const ushort_t* pRd = shm ? sRd : Rd;

  const int tid = threadIdx.x;
  const int lane = tid & 63, ln = lane & 15, q = lane >> 4;
  const int wv = tid >> 6, mh = wv >> 1, nh = wv & 1;
  const int it0 = bz * MTILES;

  // t1/t2 A-fragments -> registers (held across the whole K loop)
  short8 t1f[2][4], t2f[2][4];
  const ushort_t* srcT1 = shm ? t1S : (t1R + (size_t)base*128);
  const ushort_t* srcT2 = shm ? t2S : (t2R + (size_t)base*128);
  #pragma unroll
  for (int i = 0; i < 2; ++i) {
    int r = s0 + mh*32 + i*16 + ln; if (r > nrows-1) r = nrows-1;
    #pragma unroll
    for (int c = 0; c < 4; ++c) {
      t1f[i][c] = *(const short8*)(srcT1 + (size_t)r*128 + c*32 + q*8);
      t2f[i][c] = *(const short8*)(srcT2 + (size_t)r*128 + c*32 + q*8);
    }
  }

  load_64x128_swz(pCg + (size_t)it0*64*128, 128, ldsCg[0], tid);
  load_64x128_swz(pCu + (size_t)it0*64*128, 128, ldsCu[0], tid);

  f32x4 rdacc[2][4];
  #pragma unroll
  for (int i = 0; i < 2; ++i)
    #pragma unroll
    for (int j = 0; j < 4; ++j) rdacc[i][j] = (f32x4){0.f,0.f,0.f,0.f};

  // invariant per-lane Rd offset: row (nh*64+ln), chunk q
  const size_t rdRow = (size_t)(nh*64 + ln)*Ifull + q*8;   // + j*16*Ifull + i0 + c2*32

  __syncthreads();   // tile 0 staged

  for (int it = 0; it < MTILES; ++it) {
    const int i0 = (it0 + it) * 64;
    const int cb = it & 1;
    // 1. prefetch Cg/Cu(it+1) into the idle buffers (drains at THIS barrier,
    //    covered by phaseA+phaseB compute below)
    if (it+1 < MTILES) {
      load_64x128_swz(pCg + (size_t)(i0+64)*128, 128, ldsCg[cb^1], tid);
      load_64x128_swz(pCu + (size_t)(i0+64)*128, 128, ldsCu[cb^1], tid);
    }
    // 2. preload Rd B-frags for phaseB(it-1) (L2-resident; lands under phaseA)
    short8 rb[2][4];
    if (it > 0) {
      const int ip = i0 - 64;
      #pragma unroll
      for (int c2 = 0; c2 < 2; ++c2)
        #pragma unroll
        for (int j = 0; j < 4; ++j)
          rb[c2][j] = *(const short8*)(pRd + rdRow + (size_t)(j*16)*Ifull + ip + c2*32);
    }
    // 3. phaseA(it): g,u from regs x ldsCg/Cu[cb]; silu; h -> ldsH[cb]
    f32x4 g[2][2], u[2][2];
    #pragma unroll
    for (int i = 0; i < 2; ++i)
      #pragma unroll
      for (int j = 0; j < 2; ++j) { g[i][j] = (f32x4){0.f,0.f,0.f,0.f}; u[i][j] = (f32x4){0.f,0.f,0.f,0.f}; }
    #pragma unroll
    for (int c = 0; c < 4; ++c) {
      #pragma unroll
      for (int j = 0; j < 2; ++j) {
        int rr = nh*32 + j*16 + ln;
        int off = rr*128 + (((c*4+q) ^ (rr&15)) << 3);
        short8 bg = *(const short8*)(ldsCg[cb] + off);
        short8 bu = *(const short8*)(ldsCu[cb] + off);
        #pragma unroll
        for (int i = 0; i < 2; ++i) {
          g[i][j] = MF(t1f[i][c], bg, g[i][j]);
          u[i][j] = MF(t2f[i][c], bu, u[i][j]);
        }
      }
    }
    #pragma unroll
    for (int i = 0; i < 2; ++i)
      #pragma unroll
      for (int j = 0; j < 2; ++j)
        #pragma unroll
        for (int r = 0; r < 4; ++r) {
          float gv = g[i][j][r];
          gv = gv / (1.f + __expf(-gv));
          float hv = gv * u[i][j][r];
          int hr = mh*32 + i*16 + q*4 + r;
          int hc = nh*32 + j*16 + ln;
          ldsH[cb][hr*64 + (((hc>>3) ^ (hr&7)) << 3) + (hc&7)] = f2b(hv);
        }
    // 4. phaseB(it-1): rd += h[cb^1] @ Rd (h written last iter, barrier'd)
    if (it > 0) {
      #pragma unroll
      for (int c2 = 0; c2 < 2; ++c2) {
        short8 a[2];
        #pragma unroll
        for (int i = 0; i < 2; ++i) {
          int rr = mh*32 + i*16 + ln;
          a[i] = *(const short8*)(ldsH[cb^1] + rr*64 + (((c2*4+q) ^ (rr&7)) << 3));
        }
        #pragma unroll
        for (int j = 0; j < 4; ++j)
          #pragma unroll
          for (int i = 0; i < 2; ++i) rdacc[i][j] = MF(a[i], rb[c2][j], rdacc[i][j]);
      }
    }
    __syncthreads();   // ONE barrier/iter: h[cb] visible next iter; gll(it+1) landed
  }
  // epilogue: phaseB(MTILES-1)
  {
    const int ip = (it0 + MTILES - 1) * 64;
    const int cb = (MTILES - 1) & 1;
    #pragma unroll
    for (int c2 = 0; c2 < 2; ++c2) {
      short8 a[2];
      #pragma unroll
      for (int i = 0; i < 2; ++i) {
        int rr = mh*32 + i*16 + ln;
        a[i] = *(const short8*)(ldsH[cb] + rr*64 + (((c2*4+q) ^ (rr&7)) << 3));
      }
      #pragma unroll
      for (int j = 0; j < 4; ++j) {
        short8 b = *(const short8*)(pRd + rdRow + (size_t)(j*16)*Ifull + ip + c2*32);
        #pragma unroll
        for (int i = 0; i < 2; ++i) rdacc[i][j] = MF(a[i], b, rdacc[i][j]);
      }
    }
  }

  // plain disjoint stores (no atomics): part bz of 2 (routed) or 4 (shared)
  float* dst = shm ? (rdSp + (size_t)bz*T_TOK*128)
                   : (rdRp + (size_t)bz*NPAIR*128 + (size_t)base*128);
  #pragma unroll
  for (int i = 0; i < 2; ++i) {
    #pragma unroll
    for (int r = 0; r < 4; ++r) {
      int gs = s0 + mh*32 + i*16 + q*4 + r;
      if (gs < nrows) {
        #pragma unroll
        for (int j = 0; j < 4; ++j)
          dst[(size_t)gs*128 + nh*64 + j*16 + ln] = rdacc[i][j][r];
      }
    }
  }
}

// ---------------------------------------------------------------- out
// grid (64, 33, 2). t3 frags in regs; Cd double-buffered via gll; 1 barrier/tile.
// Balanced expert-clustered XCD map (same rationale as mid). NO atomics:
// routed y -> ybufR (bf16, per-slot, unweighted); shared y -> out directly.
__global__ __launch_bounds__(256) void out_kernel(
    const float* __restrict__ rdRp, const float* __restrict__ rdSp,
    const ushort_t* __restrict__ Ud, const ushort_t* __restrict__ Cd,
    const ushort_t* __restrict__ sUd, const ushort_t* __restrict__ sCd,
    const int* __restrict__ offA, const int* __restrict__ cntA,
    ushort_t* __restrict__ ybufR, float* __restrict__ out)
{
  __shared__ ushort_t smem[3*64*SRK];   // prologue: ldsA | stage | ldsT ; loop: cd0,cd1
  ushort_t* ldsA  = smem;
  ushort_t* stage = smem + 64*SRK;
  ushort_t* ldsT  = smem + 2*64*SRK;
  ushort_t* cd0   = smem;
  ushort_t* cd1   = smem + 64*128;

  // balanced XCD map (4224 blocks, 528 per XCD):
  //   routed m<512: by=(m>>7)*8+x, bzz=(m>>6)&1, bx=m&63
  //   shared m>=512: by=32, bzz=(m-512)>>3, bx=((m-512)&7)*8+x
  const int hh = blockIdx.x + 64*(blockIdx.y + 33*blockIdx.z);
  const int xc = hh & 7, m = hh >> 3;
  int bx, by, bzz;
  if (m < 512) { by = (m >> 7)*8 + xc; bzz = (m >> 6) & 1; bx = m & 63; }
  else         { int mm = m - 512; by = NEXP; bzz = mm >> 3; bx = ((mm & 7) << 3) + xc; }

  const int tid = threadIdx.x;
  const bool shm = (by == NEXP);
  const int nrows = shm ? T_TOK : cntA[by];
  const int s0 = bx * 64;
  if (s0 >= nrows) return;
  const int base = shm ? 0 : offA[by];
  const int ct0 = bzz * 16;
  const ushort_t* pUd = shm ? sUd : Ud + (size_t)by*128*128;
  const ushort_t* pCd = shm ? sCd : Cd + (size_t)by*HD*128;

  const int lane = tid & 63, ln = lane & 15, q = lane >> 4;
  const int wv = tid >> 6, mh = wv >> 1, nh = wv & 1;

  // gather rd rows: sum the per-bz partials (fp32) -> bf16 ldsA
  for (int li = tid; li < 64*32; li += 256) {
    int r = li >> 5, c4 = li & 31;
    int row = s0 + r; if (row > nrows-1) row = nrows-1;
    float4 v;
    if (shm) {
      const float* p = rdSp + (size_t)row*128 + c4*4;
      v = *(const float4*)p;
      #pragma unroll
      for (int pp = 1; pp < 4; ++pp) {
        float4 w2 = *(const float4*)(p + (size_t)pp*T_TOK*128);
        v.x += w2.x; v.y += w2.y; v.z += w2.z; v.w += w2.w;
      }
    } else {
      const float* p = rdRp + (size_t)(base+row)*128 + c4*4;
      v = *(const float4*)p;
      float4 w2 = *(const float4*)(p + (size_t)NPAIR*128);
      v.x += w2.x; v.y += w2.y; v.z += w2.z; v.w += w2.w;
    }
    ushort4 o; o.x=f2b(v.x); o.y=f2b(v.y); o.z=f2b(v.z); o.w=f2b(v.w);
    *(ushort4*)(ldsA + r*SRK + c4*4) = o;
  }
  __syncthreads();

  f32x4 acc[2][2][2];
  gemm64x128_regs(tid, ldsA, pUd, stage, acc);
  // C -> ldsT (padded), then extract A-frags
  #pragma unroll
  for (int h = 0; h < 2; ++h)
    #pragma unroll
    for (int i = 0; i < 2; ++i)
      #pragma unroll
      for (int j = 0; j < 2; ++j)
        #pragma unroll
        for (int r = 0; r < 4; ++r)
          ldsT[(mh*32 + i*16 + q*4 + r)*SRK + h*64 + nh*32 + j*16 + ln] = f2b(acc[h][i][j][r]);
  __syncthreads();
  short8 t3f[2][4];
  #pragma unroll
  for (int i = 0; i < 2; ++i)
    #pragma unroll
    for (int c = 0; c < 4; ++c)
      t3f[i][c] = *(const short8*)(ldsT + (mh*32 + i*16 + ln)*SRK + c*32 + q*8);
  __syncthreads();   // smem free for cd buffers

  load_64x128_swz(pCd + (size_t)ct0*64*128, 128, cd0, tid);
  for (int tt = 0; tt < 16; ++tt) {
    __syncthreads();                      // cd[tt&1] ready; prior reads drained
    ushort_t* cur = (tt & 1) ? cd1 : cd0;
    ushort_t* nxt = (tt & 1) ? cd0 : cd1;
    if (tt+1 < 16)
      load_64x128_swz(pCd + (size_t)(ct0+tt+1)*64*128, 128, nxt, tid);
    f32x4 y[2][2];
    #pragma unroll
    for (int i = 0; i < 2; ++i)
      #pragma unroll
      for (int j = 0; j < 2; ++j) y[i][j] = (f32x4){0.f,0.f,0.f,0.f};
    #pragma unroll
    for (int c = 0; c < 4; ++c) {
      #pragma unroll
      for (int j = 0; j < 2; ++j) {
        int rr = nh*32 + j*16 + ln;
        short8 b = *(const short8*)(cur + rr*128 + (((c*4+q) ^ (rr&15)) << 3));
        #pragma unroll
        for (int i = 0; i < 2; ++i) y[i][j] = MF(t3f[i][c], b, y[i][j]);
      }
    }
    #pragma unroll
    for (int i = 0; i < 2; ++i) {
      #pragma unroll
      for (int r = 0; r < 4; ++r) {
        int lr = mh*32 + i*16 + q*4 + r;
        int gs = s0 + lr;
        if (gs < nrows) {
          if (shm) {
            size_t ob = (size_t)gs*HD + (ct0 + tt)*64;
            #pragma unroll
            for (int j = 0; j < 2; ++j)
              out[ob + nh*32 + j*16 + ln] = y[i][j][r];
          } else {
            size_t ob = (size_t)(base + gs)*HD + (ct0 + tt)*64;
            #pragma unroll
            for (int j = 0; j < 2; ++j)
              ybufR[ob + nh*32 + j*16 + ln] = f2b(y[i][j][r]);
          }
        }
      }
    }
  }
}

// ---------------------------------------------------------------- combine
// out[t] = out[t] (shared, already stored) + sum_k w_k * ybufR[slot_of[t,k]]
// One block per token row; fully coalesced, no atomics.
__global__ __launch_bounds__(256) void combine_kernel(
    const ushort_t* __restrict__ ybufR,
    const int* __restrict__ slot_of, const float* __restrict__ topk_w,
    float* __restrict__ out)
{
  __shared__ int   ss[4];
  __shared__ float ww[4];
  const int t = blockIdx.x;
  if (threadIdx.x < 4) {
    ss[threadIdx.x] = slot_of[t*4 + threadIdx.x];
    ww[threadIdx.x] = topk_w[t*4 + threadIdx.x];
  }
  __syncthreads();
  const int c = threadIdx.x * 8;
  const size_t tb = (size_t)t*HD + c;
  float o[8];
  float4 a0 = *(const float4*)(out + tb);
  float4 a1 = *(const float4*)(out + tb + 4);
  o[0]=a0.x; o[1]=a0.y; o[2]=a0.z; o[3]=a0.w;
  o[4]=a1.x; o[5]=a1.y; o[6]=a1.z; o[7]=a1.w;
  #pragma unroll
  for (int k = 0; k < 4; ++k) {
    short8 rv = *(const short8*)(ybufR + (size_t)ss[k]*HD + c);
    float wk = ww[k];
    #pragma unroll
    for (int u = 0; u < 8; ++u)
      o[u] += wk * b2f((ushort_t)rv[u]);
  }
  float4 b0 = {o[0],o[1],o[2],o[3]};
  float4 b1 = {o[4],o[5],o[6],o[7]};
  *(float4*)(out + tb)     = b0;
  *(float4*)(out + tb + 4) = b1;
}

// ---------------------------------------------------------------- launch
extern "C" void kernel_launch(void* const* d_in, const int* in_sizes, int n_in,
                              void* d_out, int out_size, void* d_ws, size_t ws_size,
                              hipStream_t stream) {
  const float* x    = (const float*)d_in[0];
  const float* gw   = (const float*)d_in[1];
  const float* Rg   = (const float*)d_in[2];
  const float* Ru   = (const float*)d_in[3];
  const float* Rd   = (const float*)d_in[4];
  const float* Ug   = (const float*)d_in[5];
  const float* Cg   = (const float*)d_in[6];
  const float* Uu   = (const float*)d_in[7];
  const float* Cu   = (const float*)d_in[8];
  const float* Ud   = (const float*)d_in[9];
  const float* Cd   = (const float*)d_in[10];
  const float* sRg  = (const float*)d_in[11];
  const float* sUg  = (const float*)d_in[12];
  const float* sCg  = (const float*)d_in[13];
  const float* sRu  = (const float*)d_in[14];
  const float* sUu  = (const float*)d_in[15];
  const float* sCu  = (const float*)d_in[16];
  const float* sRd  = (const float*)d_in[17];
  const float* sUd  = (const float*)d_in[18];
  const float* sCd  = (const float*)d_in[19];
  float* out = (float*)d_out;

  char* w = (char*)d_ws;
  auto alloc = [&](size_t bytes) -> void* {
    void* p = (void*)w; w += (bytes + 255) & ~(size_t)255; return p;
  };
  int*   cnt      = (int*)  alloc(NEXP*sizeof(int));
  int*   offA     = (int*)  alloc((NEXP+1)*sizeof(int));
  int*   fill     = (int*)  alloc(NEXP*sizeof(int));
  int*   topk_idx = (int*)  alloc((size_t)T_TOK*4*sizeof(int));
  float* topk_w   = (float*)alloc((size_t)T_TOK*4*sizeof(float));
  int*   list_tok = (int*)  alloc((size_t)NPAIR*sizeof(int));
  int*   slot_of  = (int*)  alloc((size_t)T_TOK*4*sizeof(int));
  ushort_t* xb   = (ushort_t*)alloc((size_t)T_TOK*HD*2);   // later reused as rdRp (fp32, 2 parts)
  ushort_t* Rgb  = (ushort_t*)alloc((size_t)128*HD*2);
  ushort_t* Rub  = (ushort_t*)alloc((size_t)128*HD*2);
  ushort_t* Rdb  = (ushort_t*)alloc((size_t)128*IR*2);
  ushort_t* Ugb  = (ushort_t*)alloc((size_t)NEXP*128*128*2);
  ushort_t* Cgb  = (ushort_t*)alloc((size_t)NEXP*IR*128*2);
  ushort_t* Uub  = (ushort_t*)alloc((size_t)NEXP*128*128*2);
  ushort_t* Cub  = (ushort_t*)alloc((size_t)NEXP*IR*128*2);
  ushort_t* Udb  = (ushort_t*)alloc((size_t)NEXP*128*128*2);
  ushort_t* Cdb  = (ushort_t*)alloc((size_t)NEXP*HD*128*2);
  ushort_t* sRgb = (ushort_t*)alloc((size_t)128*HD*2);
  ushort_t* sUgb = (ushort_t*)alloc((size_t)128*128*2);
  ushort_t* sCgb = (ushort_t*)alloc((size_t)ISH*128*2);
  ushort_t* sRub = (ushort_t*)alloc((size_t)128*HD*2);
  ushort_t* sUub = (ushort_t*)alloc((size_t)128*128*2);
  ushort_t* sCub = (ushort_t*)alloc((size_t)ISH*128*2);
  ushort_t* sRdb = (ushort_t*)alloc((size_t)128*ISH*2);
  ushort_t* sUdb = (ushort_t*)alloc((size_t)128*128*2);
  ushort_t* sCdb = (ushort_t*)alloc((size_t)HD*128*2);
  ushort_t* rg   = (ushort_t*)alloc((size_t)T_TOK*128*2);
  ushort_t* ru   = (ushort_t*)alloc((size_t)T_TOK*128*2);
  ushort_t* sa   = (ushort_t*)alloc((size_t)T_TOK*128*2);
  ushort_t* su   = (ushort_t*)alloc((size_t)T_TOK*128*2);
  ushort_t* t1R  = (ushort_t*)alloc((size_t)NPAIR*128*2);
  ushort_t* t2R  = (ushort_t*)alloc((size_t)NPAIR*128*2);
  ushort_t* t1S  = (ushort_t*)alloc((size_t)T_TOK*128*2);
  ushort_t* t2S  = (ushort_t*)alloc((size_t)T_TOK*128*2);
  float*    rdSp = (float*)   alloc((size_t)4*T_TOK*128*sizeof(float));  // 4 shared partials
  ushort_t* ybufR= (ushort_t*)alloc((size_t)NPAIR*HD*2);                 // per-slot routed y (bf16)
  (void)ws_size; (void)in_sizes; (void)n_in;

  // routed rd partials (fp32, 2 parts) alias xb exactly:
  // 2*NPAIR*128*4 = 16.78 MB == T_TOK*HD*2. xb is dead after rproj; mid writes it after.
  float* rdRp = (float*)xb;

  hipMemsetAsync(cnt,  0, NEXP*sizeof(int), stream);
  hipMemsetAsync(fill, 0, NEXP*sizeof(int), stream);
  // no out memset: out_kernel's shared path fully writes out; combine RMWs it.

  // fused cvt
  CvtSegs cs;
  const float* ss[NSEG] = {x,Rg,Ru,Rd,Ug,Cg,Uu,Cu,Ud,Cd,sRg,sUg,sCg,sRu,sUu,sCu,sRd,sUd,sCd};
  ushort_t* dd[NSEG] = {xb,Rgb,Rub,Rdb,Ugb,Cgb,Uub,Cub,Udb,Cdb,sRgb,sUgb,sCgb,sRub,sUub,sCub,sRdb,sUdb,sCdb};
  size_t nn[NSEG] = {(size_t)T_TOK*HD,(size_t)128*HD,(size_t)128*HD,(size_t)128*IR,
                     (size_t)NEXP*128*128,(size_t)NEXP*IR*128,(size_t)NEXP*128*128,(size_t)NEXP*IR*128,
                     (size_t)NEXP*128*128,(size_t)NEXP*HD*128,(size_t)128*HD,(size_t)128*128,
                     (size_t)ISH*128,(size_t)128*HD,(size_t)128*128,(size_t)ISH*128,
                     (size_t)128*ISH,(size_t)128*128,(size_t)HD*128};
  int tot_blk = 0;
  for (int k = 0; k < NSEG; ++k) {
    cs.s[k] = ss[k]; cs.d[k] = dd[k];
    cs.n4[k] = (int)(nn[k] >> 2);
    cs.blk0[k] = tot_blk;
    tot_blk += (cs.n4[k] + 255) / 256;
  }
  cs.blk0[NSEG] = tot_blk;
  cvt_all_kernel<<<tot_blk, 256, 0, stream>>>(cs);

  gate_kernel<<<T_TOK/4, 256, 0, stream>>>(x, gw, topk_idx, topk_w, cnt);
  scan_kernel<<<1, 64, 0, stream>>>(cnt, offA);
  scatter_kernel<<<T_TOK/256, 256, 0, stream>>>(topk_idx, topk_w, offA, fill, list_tok, slot_of);
  rproj_kernel<<<dim3(T_TOK/64, 4), 256, 0, stream>>>(xb, Rgb, Rub, sRgb, sRub, rg, ru, sa, su);
  pair_proj_kernel<<<dim3(64, NEXP+1), 256, 0, stream>>>(
      rg, ru, sa, su, Ugb, Uub, sUgb, sUub, offA, cnt, list_tok, t1R, t2R, t1S, t2S);
  mid_kernel<<<dim3(64, NEXP+1, 4), 256, 0, stream>>>(
      t1R, t2R, t1S, t2S, Cgb, Cub, Rdb, sCgb, sCub, sRdb, offA, cnt, rdRp, rdSp);
  out_kernel<<<dim3(64, NEXP+1, 2), 256, 0, stream>>>(
      rdRp, rdSp, Udb, Cdb, sUdb, sCdb, offA, cnt, ybufR, out);
  combine_kernel<<<T_TOK, 256, 0, stream>>>(ybufR, slot_of, topk_w, out);
}

// Round 10
// 576.517 us; speedup vs baseline: 1.3908x; 1.0185x over previous
//
#include <hip/hip_runtime.h>
#include <math.h>

#define T_TOK 4096
#define HD    2048
#define NEXP  32
#define IR    1408
#define ISH   2816
#define NPAIR (T_TOK*4)
#define SRK   136      // padded bf16 row stride (cold paths only)
#define MTILES 11      // I-tiles (of 64) per chunk: routed 2 chunks, shared 4
#define WLCAP 2048     // per-XCD work-list capacity

typedef unsigned short ushort_t;
typedef __attribute__((ext_vector_type(8))) short    short8;
typedef __attribute__((ext_vector_type(8))) __bf16   bf16x8;
typedef __attribute__((ext_vector_type(4))) float    f32x4;

__device__ __forceinline__ f32x4 MF(short8 a, short8 b, f32x4 c) {
  return __builtin_amdgcn_mfma_f32_16x16x32_bf16(
      __builtin_bit_cast(bf16x8, a), __builtin_bit_cast(bf16x8, b), c, 0, 0, 0);
}
__device__ __forceinline__ ushort_t f2b(float f) {
  unsigned u = __float_as_uint(f);
  unsigned r = (u + 0x7fffu + ((u >> 16) & 1u)) >> 16;   // RNE
  return (ushort_t)r;
}
__device__ __forceinline__ float b2f(ushort_t b) {
  return __uint_as_float(((unsigned)b) << 16);
}
__device__ __forceinline__ float fast_rcp(float x) {     // v_rcp_f32: 1 inst, ~1ulp
  float r; asm("v_rcp_f32 %0, %1" : "=v"(r) : "v"(x)); return r;
}
__device__ __forceinline__ unsigned cvt_pk_bf16(float lo, float hi) {  // RNE pack
  unsigned r; asm("v_cvt_pk_bf16_f32 %0, %1, %2" : "=v"(r) : "v"(lo), "v"(hi)); return r;
}

// async global->LDS 16B; LDS dst must be wave-uniform base (+lane*16 implicit)
__device__ __forceinline__ void gll16(const ushort_t* g, ushort_t* l) {
  __builtin_amdgcn_global_load_lds(
      (const __attribute__((address_space(1))) unsigned int*)(const void*)g,
      (__attribute__((address_space(3))) unsigned int*)(void*)l, 16, 0, 0);
}

// ---- swizzled tile loader (XOR swizzle: phys chunk = logical ^ (row&mask)) ----
// 64 rows x 128 cols bf16 (16 chunks/row). One instr = 4 rows.
__device__ __forceinline__ void load_64x128_swz(
    const ushort_t* __restrict__ g, size_t gstride, ushort_t* lds, int tid)
{
  const int lane = tid & 63, w = tid >> 6;
  #pragma unroll
  for (int s = 0; s < 4; ++s) {
    int rbase = s*16 + w*4;
    int r = rbase + (lane >> 4);
    int p = lane & 15;
    gll16(g + (size_t)r*gstride + ((p ^ (r & 15)) << 3), lds + rbase*128);
  }
}
// read elem(row r, chunk c of 8hw): lds[r*128 + ((c^(r&15))<<3)]

// ---------------------------------------------------------------- fused cvt
#define NSEG 19
struct CvtSegs {
  const float* s[NSEG];
  ushort_t* d[NSEG];
  int n4[NSEG];
  int blk0[NSEG+1];
};
__global__ __launch_bounds__(256) void cvt_all_kernel(CvtSegs cs)
{
  int b = blockIdx.x;
  int k = 0;
  #pragma unroll 1
  while (k+1 < NSEG && b >= cs.blk0[k+1]) ++k;
  int i = (b - cs.blk0[k])*256 + threadIdx.x;
  if (i < cs.n4[k]) {
    float4 v = ((const float4*)cs.s[k])[i];
    ushort4 o; o.x=f2b(v.x); o.y=f2b(v.y); o.z=f2b(v.z); o.w=f2b(v.w);
    ((ushort4*)cs.d[k])[i] = o;
  }
}

// ---------------------------------------------------------------- gate
// 4 tokens/block (4 waves); gw staged through LDS per 128-k chunk.
__global__ __launch_bounds__(256) void gate_kernel(
    const float* __restrict__ x, const float* __restrict__ gw,
    int* __restrict__ topk_idx, float* __restrict__ topk_w, int* __restrict__ cnt)
{
  __shared__ float gws[32*132];
  __shared__ float xs[4*132];
  const int tid = threadIdx.x;
  const int w = tid >> 6, lane = tid & 63;
  const int t0 = blockIdx.x * 4;
  const int e = lane & 31, half = lane >> 5;

  float acc = 0.f;
  for (int ck = 0; ck < HD/128; ++ck) {
    for (int li = tid; li < 1024; li += 256) {        // gw chunk 32x128
      int r = li >> 5, c4 = li & 31;
      *(float4*)(gws + r*132 + c4*4) = *(const float4*)(gw + (size_t)r*HD + ck*128 + c4*4);
    }
    for (int li = tid; li < 128; li += 256) {          // x chunk 4x128
      int r = li >> 5, c4 = li & 31;
      *(float4*)(xs + r*132 + c4*4) = *(const float4*)(x + (size_t)(t0+r)*HD + ck*128 + c4*4);
    }
    __syncthreads();
    #pragma unroll
    for (int k4 = 0; k4 < 16; ++k4) {
      float4 xv = *(const float4*)(xs + w*132 + half*64 + k4*4);
      float4 wv = *(const float4*)(gws + e*132 + half*64 + k4*4);
      acc += xv.x*wv.x + xv.y*wv.y + xv.z*wv.z + xv.w*wv.w;
    }
    __syncthreads();
  }
  float p = acc;
  p += __shfl_down(p, 32);
  float logit = (lane < 32) ? p : -INFINITY;
  float m = logit;
  #pragma unroll
  for (int o = 32; o >= 1; o >>= 1) m = fmaxf(m, __shfl_xor(m, o));
  float ex = (lane < 32) ? expf(logit - m) : 0.f;
  float se = ex;
  #pragma unroll
  for (int o = 32; o >= 1; o >>= 1) se += __shfl_xor(se, o);
  float score = ex / se;

  bool taken = false;
  float selw[4]; int seli[4];
  for (int k = 0; k < 4; ++k) {
    float cur = (lane < 32 && !taken) ? score : -1.f;
    float mm = cur;
    #pragma unroll
    for (int o = 32; o >= 1; o >>= 1) mm = fmaxf(mm, __shfl_xor(mm, o));
    unsigned long long b = __ballot(cur == mm);
    int il = __ffsll(b) - 1;
    if (lane == il) taken = true;
    selw[k] = mm; seli[k] = il;
  }
  float wsum = selw[0]+selw[1]+selw[2]+selw[3] + 1e-20f;
  int t = t0 + w;
  if (lane < 4) {
    topk_idx[t*4+lane] = seli[lane];
    topk_w[t*4+lane]  = selw[lane] / wsum;
    atomicAdd(&cnt[seli[lane]], 1);
  }
}

__global__ void scan_kernel(const int* __restrict__ cnt, int* __restrict__ offA)
{
  if (threadIdx.x == 0) {
    int a = 0;
    for (int e = 0; e < NEXP; ++e) { offA[e] = a; a += cnt[e]; }
    offA[NEXP] = a;
  }
}

// ---------------------------------------------------------------- plan
// Build per-XCD work lists for the persistent mid kernel.
// XCD x gets: 32 shared items (static) + routed items of experts e%8==x.
// item encoding: (by<<16) | (bz<<12) | bx
__global__ __launch_bounds__(256) void plan_kernel(
    const int* __restrict__ cnt, int* __restrict__ wn, int* __restrict__ wl)
{
  const int t = threadIdx.x;
  if (t < 8) wn[t] = 32;
  __syncthreads();
  {
    int x = t >> 5, i = t & 31;                 // 256 threads -> 8 XCDs x 32 shared items
    int bz = i >> 3, bx = ((i & 7) << 3) + x;   // bz in [0,4), bx covers 0..63 once
    wl[x*WLCAP + i] = (NEXP << 16) | (bz << 12) | bx;
  }
  __syncthreads();
  if (t < NEXP) {
    int nb = (cnt[t] + 63) >> 6;
    int x = t & 7;
    int pos = atomicAdd(&wn[x], nb*2);
    for (int bz = 0; bz < 2; ++bz)
      for (int bx = 0; bx < nb; ++bx)
        wl[x*WLCAP + pos++] = (t << 16) | (bz << 12) | bx;
  }
}

__global__ __launch_bounds__(256) void scatter_kernel(
    const int* __restrict__ topk_idx, const float* __restrict__ topk_w,
    const int* __restrict__ offA, int* __restrict__ fill,
    int* __restrict__ list_tok, int* __restrict__ slot_of)
{
  int t = blockIdx.x*256 + threadIdx.x;
  if (t >= T_TOK) return;
  #pragma unroll
  for (int k = 0; k < 4; ++k) {
    int e = topk_idx[t*4+k];
    int pos = atomicAdd(&fill[e], 1);
    int s = offA[e] + pos;
    list_tok[s] = t;
    slot_of[t*4+k] = s;     // inverse map for non-atomic combine
  }
}

// ------------------------------------------------- R projections (pipelined)
// Y[T,128] = Xb[T,2048] @ W[128,2048]^T. A via gll dbuf; B-frags from global (L2-hot).
__global__ __launch_bounds__(256) void rproj_kernel(
    const ushort_t* __restrict__ xb,
    const ushort_t* __restrict__ Rg, const ushort_t* __restrict__ Ru,
    const ushort_t* __restrict__ sRg, const ushort_t* __restrict__ sRu,
    ushort_t* __restrict__ rg, ushort_t* __restrict__ ru,
    ushort_t* __restrict__ sa, ushort_t* __restrict__ su)
{
  __shared__ ushort_t abuf[2][64*128];
  const ushort_t* W; ushort_t* Y;
  switch (blockIdx.y) {
    case 0:  W = Rg;  Y = rg; break;
    case 1:  W = Ru;  Y = ru; break;
    case 2:  W = sRg; Y = sa; break;
    default: W = sRu; Y = su; break;
  }
  const int tid = threadIdx.x;
  const int lane = tid & 63, ln = lane & 15, q = lane >> 4;
  const int wv = tid >> 6, mh = wv >> 1, nh = wv & 1;
  const int r0 = blockIdx.x * 64;

  f32x4 acc[2][4];
  #pragma unroll
  for (int i = 0; i < 2; ++i)
    #pragma unroll
    for (int j = 0; j < 4; ++j) acc[i][j] = (f32x4){0.f,0.f,0.f,0.f};

  load_64x128_swz(xb + (size_t)r0*HD, HD, abuf[0], tid);
  for (int kt = 0; kt < 16; ++kt) {
    __syncthreads();                       // abuf[kt&1] ready
    if (kt+1 < 16)
      load_64x128_swz(xb + (size_t)r0*HD + (kt+1)*128, HD, abuf[(kt+1)&1], tid);
    const ushort_t* A = abuf[kt&1];
    #pragma unroll
    for (int c = 0; c < 4; ++c) {
      short8 a[2], b[4];
      #pragma unroll
      for (int i = 0; i < 2; ++i) {
        int rr = mh*32 + i*16 + ln;
        a[i] = *(const short8*)(A + rr*128 + (((c*4+q) ^ (rr&15)) << 3));
      }
      #pragma unroll
      for (int j = 0; j < 4; ++j)
        b[j] = *(const short8*)(W + (size_t)(nh*64 + j*16 + ln)*HD + kt*128 + c*32 + q*8);
      #pragma unroll
      for (int i = 0; i < 2; ++i)
        #pragma unroll
        for (int j = 0; j < 4; ++j) acc[i][j] = MF(a[i], b[j], acc[i][j]);
    }
  }
  #pragma unroll
  for (int i = 0; i < 2; ++i)
    #pragma unroll
    for (int j = 0; j < 4; ++j)
      #pragma unroll
      for (int r = 0; r < 4; ++r)
        Y[(size_t)(r0 + mh*32 + i*16 + q*4 + r)*128 + nh*64 + j*16 + ln] = f2b(acc[i][j][r]);
}

// -------- helper (cold path): acc = A_lds[64][SRK] @ Wg[128][128]^T, C in regs
__device__ __forceinline__ void gemm64x128_regs(
    int tid, const ushort_t* __restrict__ A, const ushort_t* __restrict__ Wg,
    ushort_t* __restrict__ stage, f32x4 acc[2][2][2])
{
  const int lane = tid & 63, ln = lane & 15, q = lane >> 4;
  const int wv = tid >> 6, mh = wv >> 1, nh = wv & 1;
  #pragma unroll
  for (int h = 0; h < 2; ++h)
    #pragma unroll
    for (int i = 0; i < 2; ++i)
      #pragma unroll
      for (int j = 0; j < 2; ++j) acc[h][i][j] = (f32x4){0.f,0.f,0.f,0.f};
  for (int h = 0; h < 2; ++h) {
    for (int li = tid; li < 64*16; li += 256) {
      int r = li >> 4, c = (li & 15) << 3;
      *(short8*)(stage + r*SRK + c) = *(const short8*)(Wg + (size_t)(h*64 + r)*128 + c);
    }
    __syncthreads();
    #pragma unroll
    for (int c = 0; c < 4; ++c) {
      short8 a[2], b[2];
      #pragma unroll
      for (int i = 0; i < 2; ++i)
        a[i] = *(const short8*)(A + (mh*32 + i*16 + ln)*SRK + c*32 + q*8);
      #pragma unroll
      for (int j = 0; j < 2; ++j)
        b[j] = *(const short8*)(stage + (nh*32 + j*16 + ln)*SRK + c*32 + q*8);
      #pragma unroll
      for (int i = 0; i < 2; ++i)
        #pragma unroll
        for (int j = 0; j < 2; ++j) acc[h][i][j] = MF(a[i], b[j], acc[h][i][j]);
    }
    __syncthreads();
  }
}

// ---------------------------------------------------------------- pair_proj
// t1[slot] = rg[tok(slot)] @ Ug_e^T ; t2 = ru @ Uu_e^T ; shared rows direct.
__global__ __launch_bounds__(256) void pair_proj_kernel(
    const ushort_t* __restrict__ rgb, const ushort_t* __restrict__ rub,
    const ushort_t* __restrict__ sab, const ushort_t* __restrict__ sub,
    const ushort_t* __restrict__ Ug, const ushort_t* __restrict__ Uu,
    const ushort_t* __restrict__ sUg, const ushort_t* __restrict__ sUu,
    const int* __restrict__ offA, const int* __restrict__ cntA,
    const int* __restrict__ list_tok,
    ushort_t* __restrict__ t1R, ushort_t* __restrict__ t2R,
    ushort_t* __restrict__ t1S, ushort_t* __restrict__ t2S)
{
  __shared__ ushort_t ldsX[64*SRK];
  __shared__ ushort_t stage[64*SRK];
  __shared__ int toks[64];
  const int tid = threadIdx.x;
  const int by = blockIdx.y;
  const bool shm = (by == NEXP);
  const int nrows = shm ? T_TOK : cntA[by];
  const int s0 = blockIdx.x * 64;
  if (s0 >= nrows) return;
  const int base = shm ? 0 : offA[by];
  const ushort_t* pUg = shm ? sUg : Ug + (size_t)by*128*128;
  const ushort_t* pUu = shm ? sUu : Uu + (size_t)by*128*128;
  const int lane = tid & 63, ln = lane & 15, q = lane >> 4;
  const int wv = tid >> 6, mh = wv >> 1, nh = wv & 1;

  if (tid < 64) {
    int sc = s0 + tid; if (sc > nrows-1) sc = nrows-1;
    toks[tid] = shm ? sc : list_tok[base + sc];
  }
  __syncthreads();

  f32x4 acc[2][2][2];
  // t1
  for (int li = tid; li < 64*16; li += 256) {
    int r = li >> 4, c = (li & 15) << 3;
    const ushort_t* src = shm ? sab : rgb;
    *(short8*)(ldsX + r*SRK + c) = *(const short8*)(src + (size_t)toks[r]*128 + c);
  }
  __syncthreads();
  gemm64x128_regs(tid, ldsX, pUg, stage, acc);
  {
    ushort_t* dst = shm ? t1S : (t1R + (size_t)base*128);
    #pragma unroll
    for (int h = 0; h < 2; ++h)
      #pragma unroll
      for (int i = 0; i < 2; ++i)
        #pragma unroll
        for (int r = 0; r < 4; ++r) {
          int gs = s0 + mh*32 + i*16 + q*4 + r;
          if (gs < nrows) {
            #pragma unroll
            for (int j = 0; j < 2; ++j)
              dst[(size_t)gs*128 + h*64 + nh*32 + j*16 + ln] = f2b(acc[h][i][j][r]);
          }
        }
  }
  // t2
  for (int li = tid; li < 64*16; li += 256) {
    int r = li >> 4, c = (li & 15) << 3;
    const ushort_t* src = shm ? sub : rub;
    *(short8*)(ldsX + r*SRK + c) = *(const short8*)(src + (size_t)toks[r]*128 + c);
  }
  __syncthreads();
  gemm64x128_regs(tid, ldsX, pUu, stage, acc);
  {
    ushort_t* dst = shm ? t2S : (t2R + (size_t)base*128);
    #pragma unroll
    for (int h = 0; h < 2; ++h)
      #pragma unroll
      for (int i = 0; i < 2; ++i)
        #pragma unroll
        for (int r = 0; r < 4; ++r) {
          int gs = s0 + mh*32 + i*16 + q*4 + r;
          if (gs < nrows) {
            #pragma unroll
            for (int j = 0; j < 2; ++j)
              dst[(size_t)gs*128 + h*64 + nh*32 + j*16 + ln] = f2b(acc[h][i][j][r]);
          }
        }
  }
}

// ---------------------------------------------------------------- mid (v6: persistent work-list + VALU diet)
// 512 persistent blocks (2/CU, 80KB LDS). Each pulls items from its XCD's work
// list via atomic counter (stealing from other XCDs when exhausted) -> no empty
// -block parade, no tail. Per-iter VALU cut: v_rcp_f32 silu (vs ~10-inst div),
// v_cvt_pk_bf16_f32 packs (vs 2x f2b), Rd reg-loads issued BEFORE gll prefetch
// so rb's vmcnt-wait doesn't force prefetch retirement.
__global__ __launch_bounds__(256, 1) void mid_kernel(
    const ushort_t* __restrict__ t1R, const ushort_t* __restrict__ t2R,
    const ushort_t* __restrict__ t1S, const ushort_t* __restrict__ t2S,
    const ushort_t* __restrict__ Cg, const ushort_t* __restrict__ Cu,
    const ushort_t* __restrict__ Rd,
    const ushort_t* __restrict__ sCg, const ushort_t* __restrict__ sCu,
    const ushort_t* __restrict__ sRd,
    const int* __restrict__ offA, const int* __restrict__ cntA,
    float* __restrict__ rdRp, float* __restrict__ rdSp,
    const int* __restrict__ wn, int* __restrict__ wcnt, const int* __restrict__ wl)
{
  __shared__ ushort_t ldsCg[2][64*128];   // 32 KB
  __shared__ ushort_t ldsCu[2][64*128];   // 32 KB
  __shared__ ushort_t ldsH [2][64*64];    // 16 KB  -> 80 KB total
  __shared__ int s_item;

  const int tid = threadIdx.x;
  const int lane = tid & 63, ln = lane & 15, q = lane >> 4;
  const int wv = tid >> 6, mh = wv >> 1, nh = wv & 1;
  const int xc0 = blockIdx.x & 7;

  for (int lx = 0; lx < 8; ++lx) {
    const int xc = (xc0 + lx) & 7;
    const int nww = wn[xc];
    for (;;) {
      __syncthreads();                       // prior item's LDS reads done; s_item consumed
      if (tid == 0) s_item = atomicAdd(&wcnt[xc], 1);
      __syncthreads();
      const int wi = s_item;
      if (wi >= nww) break;
      const int item = wl[xc*WLCAP + wi];
      const int by = item >> 16, bz = (item >> 12) & 15, bx = item & 4095;

      const bool shm = (by == NEXP);
      const int nrows = shm ? T_TOK : cntA[by];
      const int s0 = bx * 64;
      const int base = shm ? 0 : offA[by];
      const int Ifull = shm ? ISH : IR;
      const ushort_t* pCg = shm ? sCg : Cg + (size_t)by*IR*128;
      const ushort_t* pCu = shm ? sCu : Cu + (size_t)by*IR*128;
      const ushort_t* pRd = shm ? sRd : Rd;
      const int it0 = bz * MTILES;

      // t1/t2 A-fragments -> registers (held across the K loop)
      short8 t1f[2][4], t2f[2][4];
      const ushort_t* srcT1 = shm ? t1S : (t1R + (size_t)base*128);
      const ushort_t* srcT2 = shm ? t2S : (t2R + (size_t)base*128);
      #pragma unroll
      for (int i = 0; i < 2; ++i) {
        int r = s0 + mh*32 + i*16 + ln; if (r > nrows-1) r = nrows-1;
        #pragma unroll
        for (int c = 0; c < 4; ++c) {
          t1f[i][c] = *(const short8*)(srcT1 + (size_t)r*128 + c*32 + q*8);
          t2f[i][c] = *(const short8*)(srcT2 + (size_t)r*128 + c*32 + q*8);
        }
      }

      load_64x128_swz(pCg + (size_t)it0*64*128, 128, ldsCg[0], tid);
      load_64x128_swz(pCu + (size_t)it0*64*128, 128, ldsCu[0], tid);

      f32x4 rdacc[2][4];
      #pragma unroll
      for (int i = 0; i < 2; ++i)
        #pragma unroll
        for (int j = 0; j < 4; ++j) rdacc[i][j] = (f32x4){0.f,0.f,0.f,0.f};

      const size_t rdRow = (size_t)(nh*64 + ln)*Ifull + q*8;  // + j*16*Ifull + i0 + c2*32

      __syncthreads();   // tile 0 staged

      for (int it = 0; it < MTILES; ++it) {
        const int i0 = (it0 + it) * 64;
        const int cb = it & 1;
        // 1. preload Rd B-frags for phaseB(it-1) FIRST (vmcnt in-order: waiting
        //    for these must not force the gll prefetch issued after them)
        short8 rb[2][4];
        if (it > 0) {
          const int ip = i0 - 64;
          #pragma unroll
          for (int c2 = 0; c2 < 2; ++c2)
            #pragma unroll
            for (int j = 0; j < 4; ++j)
              rb[c2][j] = *(const short8*)(pRd + rdRow + (size_t)(j*16)*Ifull + ip + c2*32);
        }
        // 2. prefetch Cg/Cu(it+1) into the idle buffers (drains at THIS barrier)
        if (it+1 < MTILES) {
          load_64x128_swz(pCg + (size_t)(i0+64)*128, 128, ldsCg[cb^1], tid);
          load_64x128_swz(pCu + (size_t)(i0+64)*128, 128, ldsCu[cb^1], tid);
        }
        // 3. phaseA(it): g,u from regs x ldsCg/Cu[cb]; silu; h -> ldsH[cb]
        f32x4 g[2][2], u[2][2];
        #pragma unroll
        for (int i = 0; i < 2; ++i)
          #pragma unroll
          for (int j = 0; j < 2; ++j) { g[i][j] = (f32x4){0.f,0.f,0.f,0.f}; u[i][j] = (f32x4){0.f,0.f,0.f,0.f}; }
        #pragma unroll
        for (int c = 0; c < 4; ++c) {
          #pragma unroll
          for (int j = 0; j < 2; ++j) {
            int rr = nh*32 + j*16 + ln;
            int off = rr*128 + (((c*4+q) ^ (rr&15)) << 3);
            short8 bg = *(const short8*)(ldsCg[cb] + off);
            short8 bu = *(const short8*)(ldsCu[cb] + off);
            #pragma unroll
            for (int i = 0; i < 2; ++i) {
              g[i][j] = MF(t1f[i][c], bg, g[i][j]);
              u[i][j] = MF(t2f[i][c], bu, u[i][j]);
            }
          }
        }
        #pragma unroll
        for (int i = 0; i < 2; ++i)
          #pragma unroll
          for (int j = 0; j < 2; ++j) {
            float hv[4];
            #pragma unroll
            for (int r = 0; r < 4; ++r) {
              float gv = g[i][j][r];
              hv[r] = gv * fast_rcp(1.f + __expf(-gv)) * u[i][j][r];
            }
            unsigned p01 = cvt_pk_bf16(hv[0], hv[1]);
            unsigned p23 = cvt_pk_bf16(hv[2], hv[3]);
            const int hc = nh*32 + j*16 + ln;
            const int hb = mh*32 + i*16 + q*4;
            #pragma unroll
            for (int r = 0; r < 4; ++r) {
              int hr = hb + r;
              ushort_t v = (r==0) ? (ushort_t)p01 : (r==1) ? (ushort_t)(p01>>16)
                         : (r==2) ? (ushort_t)p23 : (ushort_t)(p23>>16);
              ldsH[cb][hr*64 + (((hc>>3) ^ (hr&7)) << 3) + (hc&7)] = v;
            }
          }
        // 4. phaseB(it-1): rd += h[cb^1] @ Rd (h written last iter, barrier'd)
        if (it > 0) {
          #pragma unroll
          for (int c2 = 0; c2 < 2; ++c2) {
            short8 a[2];
            #pragma unroll
            for (int i = 0; i < 2; ++i) {
              int rr = mh*32 + i*16 + ln;
              a[i] = *(const short8*)(ldsH[cb^1] + rr*64 + (((c2*4+q) ^ (rr&7)) << 3));
            }
            #pragma unroll
            for (int j = 0; j < 4; ++j)
              #pragma unroll
              for (int i = 0; i < 2; ++i) rdacc[i][j] = MF(a[i], rb[c2][j], rdacc[i][j]);
          }
        }
        __syncthreads();   // ONE barrier/iter: h[cb] visible next iter; gll(it+1) landed
      }
      // epilogue: phaseB(MTILES-1)
      {
        const int ip = (it0 + MTILES - 1) * 64;
        const int cb = (MTILES - 1) & 1;
        #pragma unroll
        for (int c2 = 0; c2 < 2; ++c2) {
          short8 a[2];
          #pragma unroll
          for (int i = 0; i < 2; ++i) {
            int rr = mh*32 + i*16 + ln;
            a[i] = *(const short8*)(ldsH[cb] + rr*64 + (((c2*4+q) ^ (rr&7)) << 3));
          }
          #pragma unroll
          for (int j = 0; j < 4; ++j) {
            short8 b = *(const short8*)(pRd + rdRow + (size_t)(j*16)*Ifull + ip + c2*32);
            #pragma unroll
            for (int i = 0; i < 2; ++i) rdacc[i][j] = MF(a[i], b, rdacc[i][j]);
          }
        }
      }

      // plain disjoint stores (no atomics): part bz of 2 (routed) or 4 (shared)
      float* dst = shm ? (rdSp + (size_t)bz*T_TOK*128)
                       : (rdRp + (size_t)bz*NPAIR*128 + (size_t)base*128);
      #pragma unroll
      for (int i = 0; i < 2; ++i) {
        #pragma unroll
        for (int r = 0; r < 4; ++r) {
          int gs = s0 + mh*32 + i*16 + q*4 + r;
          if (gs < nrows) {
            #pragma unroll
            for (int j = 0; j < 4; ++j)
              dst[(size_t)gs*128 + nh*64 + j*16 + ln] = rdacc[i][j][r];
          }
        }
      }
    }
  }
}

// ---------------------------------------------------------------- out
// grid (64, 33, 2). t3 frags in regs; Cd double-buffered via gll; 1 barrier/tile.
// Balanced expert-clustered XCD map. NO atomics: routed y -> ybufR (bf16,
// per-slot, unweighted); shared y -> out directly (fp32 plain stores).
__global__ __launch_bounds__(256) void out_kernel(
    const float* __restrict__ rdRp, const float* __restrict__ rdSp,
    const ushort_t* __restrict__ Ud, const ushort_t* __restrict__ Cd,
    const ushort_t* __restrict__ sUd, const ushort_t* __restrict__ sCd,
    const int* __restrict__ offA, const int* __restrict__ cntA,
    ushort_t* __restrict__ ybufR, float* __restrict__ out)
{
  __shared__ ushort_t smem[3*64*SRK];   // prologue: ldsA | stage | ldsT ; loop: cd0,cd1
  ushort_t* ldsA  = smem;
  ushort_t* stage = smem + 64*SRK;
  ushort_t* ldsT  = smem + 2*64*SRK;
  ushort_t* cd0   = smem;
  ushort_t* cd1   = smem + 64*128;

  // balanced XCD map (4224 blocks, 528 per XCD):
  //   routed m<512: by=(m>>7)*8+x, bzz=(m>>6)&1, bx=m&63
  //   shared m>=512: by=32, bzz=(m-512)>>3, bx=((m-512)&7)*8+x
  const int hh = blockIdx.x + 64*(blockIdx.y + 33*blockIdx.z);
  const int xc = hh & 7, m = hh >> 3;
  int bx, by, bzz;
  if (m < 512) { by = (m >> 7)*8 + xc; bzz = (m >> 6) & 1; bx = m & 63; }
  else         { int mm = m - 512; by = NEXP; bzz = mm >> 3; bx = ((mm & 7) << 3) + xc; }

  const int tid = threadIdx.x;
  const bool shm = (by == NEXP);
  const int nrows = shm ? T_TOK : cntA[by];
  const int s0 = bx * 64;
  if (s0 >= nrows) return;
  const int base = shm ? 0 : offA[by];
  const int ct0 = bzz * 16;
  const ushort_t* pUd = shm ? sUd : Ud + (size_t)by*128*128;
  const ushort_t* pCd = shm ? sCd : Cd + (size_t)by*HD*128;

  const int lane = tid & 63, ln = lane & 15, q = lane >> 4;
  const int wv = tid >> 6, mh = wv >> 1, nh = wv & 1;

  // gather rd rows: sum the per-bz partials (fp32) -> bf16 ldsA
  for (int li = tid; li < 64*32; li += 256) {
    int r = li >> 5, c4 = li & 31;
    int row = s0 + r; if (row > nrows-1) row = nrows-1;
    float4 v;
    if (shm) {
      const float* p = rdSp + (size_t)row*128 + c4*4;
      v = *(const float4*)p;
      #pragma unroll
      for (int pp = 1; pp < 4; ++pp) {
        float4 w2 = *(const float4*)(p + (size_t)pp*T_TOK*128);
        v.x += w2.x; v.y += w2.y; v.z += w2.z; v.w += w2.w;
      }
    } else {
      const float* p = rdRp + (size_t)(base+row)*128 + c4*4;
      v = *(const float4*)p;
      float4 w2 = *(const float4*)(p + (size_t)NPAIR*128);
      v.x += w2.x; v.y += w2.y; v.z += w2.z; v.w += w2.w;
    }
    ushort4 o; o.x=f2b(v.x); o.y=f2b(v.y); o.z=f2b(v.z); o.w=f2b(v.w);
    *(ushort4*)(ldsA + r*SRK + c4*4) = o;
  }
  __syncthreads();

  f32x4 acc[2][2][2];
  gemm64x128_regs(tid, ldsA, pUd, stage, acc);
  // C -> ldsT (padded), then extract A-frags
  #pragma unroll
  for (int h = 0; h < 2; ++h)
    #pragma unroll
    for (int i = 0; i < 2; ++i)
      #pragma unroll
      for (int j = 0; j < 2; ++j)
        #pragma unroll
        for (int r = 0; r < 4; ++r)
          ldsT[(mh*32 + i*16 + q*4 + r)*SRK + h*64 + nh*32 + j*16 + ln] = f2b(acc[h][i][j][r]);
  __syncthreads();
  short8 t3f[2][4];
  #pragma unroll
  for (int i = 0; i < 2; ++i)
    #pragma unroll
    for (int c = 0; c < 4; ++c)
      t3f[i][c] = *(const short8*)(ldsT + (mh*32 + i*16 + ln)*SRK + c*32 + q*8);
  __syncthreads();   // smem free for cd buffers

  load_64x128_swz(pCd + (size_t)ct0*64*128, 128, cd0, tid);
  for (int tt = 0; tt < 16; ++tt) {
    __syncthreads();                      // cd[tt&1] ready; prior reads drained
    ushort_t* cur = (tt & 1) ? cd1 : cd0;
    ushort_t* nxt = (tt & 1) ? cd0 : cd1;
    if (tt+1 < 16)
      load_64x128_swz(pCd + (size_t)(ct0+tt+1)*64*128, 128, nxt, tid);
    f32x4 y[2][2];
    #pragma unroll
    for (int i = 0; i < 2; ++i)
      #pragma unroll
      for (int j = 0; j < 2; ++j) y[i][j] = (f32x4){0.f,0.f,0.f,0.f};
    #pragma unroll
    for (int c = 0; c < 4; ++c) {
      #pragma unroll
      for (int j = 0; j < 2; ++j) {
        int rr = nh*32 + j*16 + ln;
        short8 b = *(const short8*)(cur + rr*128 + (((c*4+q) ^ (rr&15)) << 3));
        #pragma unroll
        for (int i = 0; i < 2; ++i) y[i][j] = MF(t3f[i][c], b, y[i][j]);
      }
    }
    #pragma unroll
    for (int i = 0; i < 2; ++i) {
      #pragma unroll
      for (int r = 0; r < 4; ++r) {
        int lr = mh*32 + i*16 + q*4 + r;
        int gs = s0 + lr;
        if (gs < nrows) {
          if (shm) {
            size_t ob = (size_t)gs*HD + (ct0 + tt)*64;
            #pragma unroll
            for (int j = 0; j < 2; ++j)
              out[ob + nh*32 + j*16 + ln] = y[i][j][r];
          } else {
            size_t ob = (size_t)(base + gs)*HD + (ct0 + tt)*64;
            #pragma unroll
            for (int j = 0; j < 2; ++j)
              ybufR[ob + nh*32 + j*16 + ln] = f2b(y[i][j][r]);
          }
        }
      }
    }
  }
}

// ---------------------------------------------------------------- combine
// out[t] = out[t] (shared, already stored) + sum_k w_k * ybufR[slot_of[t,k]]
// One block per token row; fully coalesced, no atomics.
__global__ __launch_bounds__(256) void combine_kernel(
    const ushort_t* __restrict__ ybufR,
    const int* __restrict__ slot_of, const float* __restrict__ topk_w,
    float* __restrict__ out)
{
  __shared__ int   ss[4];
  __shared__ float ww[4];
  const int t = blockIdx.x;
  if (threadIdx.x < 4) {
    ss[threadIdx.x] = slot_of[t*4 + threadIdx.x];
    ww[threadIdx.x] = topk_w[t*4 + threadIdx.x];
  }
  __syncthreads();
  const int c = threadIdx.x * 8;
  const size_t tb = (size_t)t*HD + c;
  float o[8];
  float4 a0 = *(const float4*)(out + tb);
  float4 a1 = *(const float4*)(out + tb + 4);
  o[0]=a0.x; o[1]=a0.y; o[2]=a0.z; o[3]=a0.w;
  o[4]=a1.x; o[5]=a1.y; o[6]=a1.z; o[7]=a1.w;
  #pragma unroll
  for (int k = 0; k < 4; ++k) {
    short8 rv = *(const short8*)(ybufR + (size_t)ss[k]*HD + c);
    float wk = ww[k];
    #pragma unroll
    for (int u = 0; u < 8; ++u)
      o[u] += wk * b2f((ushort_t)rv[u]);
  }
  float4 b0 = {o[0],o[1],o[2],o[3]};
  float4 b1 = {o[4],o[5],o[6],o[7]};
  *(float4*)(out + tb)     = b0;
  *(float4*)(out + tb + 4) = b1;
}

// ---------------------------------------------------------------- launch
extern "C" void kernel_launch(void* const* d_in, const int* in_sizes, int n_in,
                              void* d_out, int out_size, void* d_ws, size_t ws_size,
                              hipStream_t stream) {
  const float* x    = (const float*)d_in[0];
  const float* gw   = (const float*)d_in[1];
  const float* Rg   = (const float*)d_in[2];
  const float* Ru   = (const float*)d_in[3];
  const float* Rd   = (const float*)d_in[4];
  const float* Ug   = (const float*)d_in[5];
  const float* Cg   = (const float*)d_in[6];
  const float* Uu   = (const float*)d_in[7];
  const float* Cu   = (const float*)d_in[8];
  const float* Ud   = (const float*)d_in[9];
  const float* Cd   = (const float*)d_in[10];
  const float* sRg  = (const float*)d_in[11];
  const float* sUg  = (const float*)d_in[12];
  const float* sCg  = (const float*)d_in[13];
  const float* sRu  = (const float*)d_in[14];
  const float* sUu  = (const float*)d_in[15];
  const float* sCu  = (const float*)d_in[16];
  const float* sRd  = (const float*)d_in[17];
  const float* sUd  = (const float*)d_in[18];
  const float* sCd  = (const float*)d_in[19];
  float* out = (float*)d_out;

  char* w = (char*)d_ws;
  auto alloc = [&](size_t bytes) -> void* {
    void* p = (void*)w; w += (bytes + 255) & ~(size_t)255; return p;
  };
  int*   cnt      = (int*)  alloc(NEXP*sizeof(int));
  int*   offA     = (int*)  alloc((NEXP+1)*sizeof(int));
  int*   fill     = (int*)  alloc(NEXP*sizeof(int));
  int*   topk_idx = (int*)  alloc((size_t)T_TOK*4*sizeof(int));
  float* topk_w   = (float*)alloc((size_t)T_TOK*4*sizeof(float));
  int*   list_tok = (int*)  alloc((size_t)NPAIR*sizeof(int));
  int*   slot_of  = (int*)  alloc((size_t)T_TOK*4*sizeof(int));
  int*   wn       = (int*)  alloc(8*sizeof(int));
  int*   wcnt     = (int*)  alloc(8*sizeof(int));
  int*   wl       = (int*)  alloc((size_t)8*WLCAP*sizeof(int));
  ushort_t* xb   = (ushort_t*)alloc((size_t)T_TOK*HD*2);   // later reused as rdRp (fp32, 2 parts)
  ushort_t* Rgb  = (ushort_t*)alloc((size_t)128*HD*2);
  ushort_t* Rub  = (ushort_t*)alloc((size_t)128*HD*2);
  ushort_t* Rdb  = (ushort_t*)alloc((size_t)128*IR*2);
  ushort_t* Ugb  = (ushort_t*)alloc((size_t)NEXP*128*128*2);
  ushort_t* Cgb  = (ushort_t*)alloc((size_t)NEXP*IR*128*2);
  ushort_t* Uub  = (ushort_t*)alloc((size_t)NEXP*128*128*2);
  ushort_t* Cub  = (ushort_t*)alloc((size_t)NEXP*IR*128*2);
  ushort_t* Udb  = (ushort_t*)alloc((size_t)NEXP*128*128*2);
  ushort_t* Cdb  = (ushort_t*)alloc((size_t)NEXP*HD*128*2);
  ushort_t* sRgb = (ushort_t*)alloc((size_t)128*HD*2);
  ushort_t* sUgb = (ushort_t*)alloc((size_t)128*128*2);
  ushort_t* sCgb = (ushort_t*)alloc((size_t)ISH*128*2);
  ushort_t* sRub = (ushort_t*)alloc((size_t)128*HD*2);
  ushort_t* sUub = (ushort_t*)alloc((size_t)128*128*2);
  ushort_t* sCub = (ushort_t*)alloc((size_t)ISH*128*2);
  ushort_t* sRdb = (ushort_t*)alloc((size_t)128*ISH*2);
  ushort_t* sUdb = (ushort_t*)alloc((size_t)128*128*2);
  ushort_t* sCdb = (ushort_t*)alloc((size_t)HD*128*2);
  ushort_t* rg   = (ushort_t*)alloc((size_t)T_TOK*128*2);
  ushort_t* ru   = (ushort_t*)alloc((size_t)T_TOK*128*2);
  ushort_t* sa   = (ushort_t*)alloc((size_t)T_TOK*128*2);
  ushort_t* su   = (ushort_t*)alloc((size_t)T_TOK*128*2);
  ushort_t* t1R  = (ushort_t*)alloc((size_t)NPAIR*128*2);
  ushort_t* t2R  = (ushort_t*)alloc((size_t)NPAIR*128*2);
  ushort_t* t1S  = (ushort_t*)alloc((size_t)T_TOK*128*2);
  ushort_t* t2S  = (ushort_t*)alloc((size_t)T_TOK*128*2);
  float*    rdSp = (float*)   alloc((size_t)4*T_TOK*128*sizeof(float));  // 4 shared partials
  ushort_t* ybufR= (ushort_t*)alloc((size_t)NPAIR*HD*2);                 // per-slot routed y (bf16)
  (void)ws_size; (void)in_sizes; (void)n_in;

  // routed rd partials (fp32, 2 parts) alias xb exactly:
  // 2*NPAIR*128*4 = 16.78 MB == T_TOK*HD*2. xb is dead after rproj; mid writes it after.
  float* rdRp = (float*)xb;

  hipMemsetAsync(cnt,  0, NEXP*sizeof(int), stream);
  hipMemsetAsync(fill, 0, NEXP*sizeof(int), stream);
  hipMemsetAsync(wcnt, 0, 8*sizeof(int), stream);
  // no out memset: out_kernel's shared path fully writes out; combine RMWs it.

  // fused cvt
  CvtSegs cs;
  const float* ss[NSEG] = {x,Rg,Ru,Rd,Ug,Cg,Uu,Cu,Ud,Cd,sRg,sUg,sCg,sRu,sUu,sCu,sRd,sUd,sCd};
  ushort_t* dd[NSEG] = {xb,Rgb,Rub,Rdb,Ugb,Cgb,Uub,Cub,Udb,Cdb,sRgb,sUgb,sCgb,sRub,sUub,sCub,sRdb,sUdb,sCdb};
  size_t nn[NSEG] = {(size_t)T_TOK*HD,(size_t)128*HD,(size_t)128*HD,(size_t)128*IR,
                     (size_t)NEXP*128*128,(size_t)NEXP*IR*128,(size_t)NEXP*128*128,(size_t)NEXP*IR*128,
                     (size_t)NEXP*128*128,(size_t)NEXP*HD*128,(size_t)128*HD,(size_t)128*128,
                     (size_t)ISH*128,(size_t)128*HD,(size_t)128*128,(size_t)ISH*128,
                     (size_t)128*ISH,(size_t)128*128,(size_t)HD*128};
  int tot_blk = 0;
  for (int k = 0; k < NSEG; ++k) {
    cs.s[k] = ss[k]; cs.d[k] = dd[k];
    cs.n4[k] = (int)(nn[k] >> 2);
    cs.blk0[k] = tot_blk;
    tot_blk += (cs.n4[k] + 255) / 256;
  }
  cs.blk0[NSEG] = tot_blk;
  cvt_all_kernel<<<tot_blk, 256, 0, stream>>>(cs);

  gate_kernel<<<T_TOK/4, 256, 0, stream>>>(x, gw, topk_idx, topk_w, cnt);
  scan_kernel<<<1, 64, 0, stream>>>(cnt, offA);
  plan_kernel<<<1, 256, 0, stream>>>(cnt, wn, wl);
  scatter_kernel<<<T_TOK/256, 256, 0, stream>>>(topk_idx, topk_w, offA, fill, list_tok, slot_of);
  rproj_kernel<<<dim3(T_TOK/64, 4), 256, 0, stream>>>(xb, Rgb, Rub, sRgb, sRub, rg, ru, sa, su);
  pair_proj_kernel<<<dim3(64, NEXP+1), 256, 0, stream>>>(
      rg, ru, sa, su, Ugb, Uub, sUgb, sUub, offA, cnt, list_tok, t1R, t2R, t1S, t2S);
  mid_kernel<<<512, 256, 0, stream>>>(
      t1R, t2R, t1S, t2S, Cgb, Cub, Rdb, sCgb, sCub, sRdb, offA, cnt, rdRp, rdSp,
      wn, wcnt, wl);
  out_kernel<<<dim3(64, 33, 2), 256, 0, stream>>>(
      rdRp, rdSp, Udb, Cdb, sUdb, sCdb, offA, cnt, ybufR, out);
  combine_kernel<<<T_TOK, 256, 0, stream>>>(ybufR, slot_of, topk_w, out);
}

// Round 12
// 576.188 us; speedup vs baseline: 1.3915x; 1.0006x over previous
//
#include <hip/hip_runtime.h>
#include <math.h>

#define T_TOK 4096
#define HD    2048
#define NEXP  32
#define IR    1408
#define ISH   2816
#define NPAIR (T_TOK*4)
#define SRK   136      // padded bf16 row stride (cold paths only)
#define WLCAP 2048     // per-XCD work-list capacity

typedef unsigned short ushort_t;
typedef __attribute__((ext_vector_type(8))) short    short8;
typedef __attribute__((ext_vector_type(8))) __bf16   bf16x8;
typedef __attribute__((ext_vector_type(4))) float    f32x4;

__device__ __forceinline__ f32x4 MF(short8 a, short8 b, f32x4 c) {
  return __builtin_amdgcn_mfma_f32_16x16x32_bf16(
      __builtin_bit_cast(bf16x8, a), __builtin_bit_cast(bf16x8, b), c, 0, 0, 0);
}
__device__ __forceinline__ ushort_t f2b(float f) {
  unsigned u = __float_as_uint(f);
  unsigned r = (u + 0x7fffu + ((u >> 16) & 1u)) >> 16;   // RNE
  return (ushort_t)r;
}
__device__ __forceinline__ float b2f(ushort_t b) {
  return __uint_as_float(((unsigned)b) << 16);
}
__device__ __forceinline__ float fast_rcp(float x) {     // v_rcp_f32: 1 inst, ~1ulp
  float r; asm("v_rcp_f32 %0, %1" : "=v"(r) : "v"(x)); return r;
}
__device__ __forceinline__ unsigned cvt_pk_bf16(float lo, float hi) {  // RNE pack
  unsigned r; asm("v_cvt_pk_bf16_f32 %0, %1, %2" : "=v"(r) : "v"(lo), "v"(hi)); return r;
}

// async global->LDS 16B; LDS dst must be wave-uniform base (+lane*16 implicit)
__device__ __forceinline__ void gll16(const ushort_t* g, ushort_t* l) {
  __builtin_amdgcn_global_load_lds(
      (const __attribute__((address_space(1))) unsigned int*)(const void*)g,
      (__attribute__((address_space(3))) unsigned int*)(void*)l, 16, 0, 0);
}

// ---- swizzled tile loader (XOR swizzle: phys chunk = logical ^ (row&mask)) ----
// 64 rows x 128 cols bf16 (16 chunks/row). One instr = 4 rows.
__device__ __forceinline__ void load_64x128_swz(
    const ushort_t* __restrict__ g, size_t gstride, ushort_t* lds, int tid)
{
  const int lane = tid & 63, w = tid >> 6;
  #pragma unroll
  for (int s = 0; s < 4; ++s) {
    int rbase = s*16 + w*4;
    int r = rbase + (lane >> 4);
    int p = lane & 15;
    gll16(g + (size_t)r*gstride + ((p ^ (r & 15)) << 3), lds + rbase*128);
  }
}
// read elem(row r, chunk c of 8hw): lds[r*128 + ((c^(r&15))<<3)]

// ---------------------------------------------------------------- fused cvt
#define NSEG 19
struct CvtSegs {
  const float* s[NSEG];
  ushort_t* d[NSEG];
  int n4[NSEG];
  int blk0[NSEG+1];
};
__global__ __launch_bounds__(256) void cvt_all_kernel(CvtSegs cs)
{
  int b = blockIdx.x;
  int k = 0;
  #pragma unroll 1
  while (k+1 < NSEG && b >= cs.blk0[k+1]) ++k;
  int i = (b - cs.blk0[k])*256 + threadIdx.x;
  if (i < cs.n4[k]) {
    float4 v = ((const float4*)cs.s[k])[i];
    ushort4 o; o.x=f2b(v.x); o.y=f2b(v.y); o.z=f2b(v.z); o.w=f2b(v.w);
    ((ushort4*)cs.d[k])[i] = o;
  }
}

// ---------------------------------------------------------------- gate
// 4 tokens/block (4 waves); gw staged through LDS per 128-k chunk.
__global__ __launch_bounds__(256) void gate_kernel(
    const float* __restrict__ x, const float* __restrict__ gw,
    int* __restrict__ topk_idx, float* __restrict__ topk_w, int* __restrict__ cnt)
{
  __shared__ float gws[32*132];
  __shared__ float xs[4*132];
  const int tid = threadIdx.x;
  const int w = tid >> 6, lane = tid & 63;
  const int t0 = blockIdx.x * 4;
  const int e = lane & 31, half = lane >> 5;

  float acc = 0.f;
  for (int ck = 0; ck < HD/128; ++ck) {
    for (int li = tid; li < 1024; li += 256) {        // gw chunk 32x128
      int r = li >> 5, c4 = li & 31;
      *(float4*)(gws + r*132 + c4*4) = *(const float4*)(gw + (size_t)r*HD + ck*128 + c4*4);
    }
    for (int li = tid; li < 128; li += 256) {          // x chunk 4x128
      int r = li >> 5, c4 = li & 31;
      *(float4*)(xs + r*132 + c4*4) = *(const float4*)(x + (size_t)(t0+r)*HD + ck*128 + c4*4);
    }
    __syncthreads();
    #pragma unroll
    for (int k4 = 0; k4 < 16; ++k4) {
      float4 xv = *(const float4*)(xs + w*132 + half*64 + k4*4);
      float4 wv = *(const float4*)(gws + e*132 + half*64 + k4*4);
      acc += xv.x*wv.x + xv.y*wv.y + xv.z*wv.z + xv.w*wv.w;
    }
    __syncthreads();
  }
  float p = acc;
  p += __shfl_down(p, 32);
  float logit = (lane < 32) ? p : -INFINITY;
  float m = logit;
  #pragma unroll
  for (int o = 32; o >= 1; o >>= 1) m = fmaxf(m, __shfl_xor(m, o));
  float ex = (lane < 32) ? expf(logit - m) : 0.f;
  float se = ex;
  #pragma unroll
  for (int o = 32; o >= 1; o >>= 1) se += __shfl_xor(se, o);
  float score = ex / se;

  bool taken = false;
  float selw[4]; int seli[4];
  for (int k = 0; k < 4; ++k) {
    float cur = (lane < 32 && !taken) ? score : -1.f;
    float mm = cur;
    #pragma unroll
    for (int o = 32; o >= 1; o >>= 1) mm = fmaxf(mm, __shfl_xor(mm, o));
    unsigned long long b = __ballot(cur == mm);
    int il = __ffsll(b) - 1;
    if (lane == il) taken = true;
    selw[k] = mm; seli[k] = il;
  }
  float wsum = selw[0]+selw[1]+selw[2]+selw[3] + 1e-20f;
  int t = t0 + w;
  if (lane < 4) {
    topk_idx[t*4+lane] = seli[lane];
    topk_w[t*4+lane]  = selw[lane] / wsum;
    atomicAdd(&cnt[seli[lane]], 1);
  }
}

__global__ void scan_kernel(const int* __restrict__ cnt, int* __restrict__ offA)
{
  if (threadIdx.x == 0) {
    int a = 0;
    for (int e = 0; e < NEXP; ++e) { offA[e] = a; a += cnt[e]; }
    offA[NEXP] = a;
  }
}

// ---------------------------------------------------------------- plan
// Build per-XCD work lists for the persistent mid kernel.
// XCD x gets: 64 shared items (8 I-chunks x 8 bx) + routed items of experts e%8==x.
// Shared items FIRST so each block pulls ~1 shared (~5.5 tiles) + 1 routed (11
// tiles) -> duration-balanced 2.0 items/block (was 1.5 -> 25% tail idle).
// item encoding: (by<<16) | (bz<<12) | bx
__global__ __launch_bounds__(256) void plan_kernel(
    const int* __restrict__ cnt, int* __restrict__ wn, int* __restrict__ wl)
{
  const int t = threadIdx.x;
  if (t < 8) wn[t] = 64;
  __syncthreads();
  for (int s = t; s < 512; s += 256) {          // 8 XCDs x 64 shared items
    int x = s >> 6, i = s & 63;
    int bz = i >> 3, bx = ((i & 7) << 3) + x;   // bz in [0,8), bx covers 0..63 once
    wl[x*WLCAP + i] = (NEXP << 16) | (bz << 12) | bx;
  }
  __syncthreads();
  if (t < NEXP) {
    int nb = (cnt[t] + 63) >> 6;
    int x = t & 7;
    int pos = atomicAdd(&wn[x], nb*2);
    for (int bz = 0; bz < 2; ++bz)
      for (int bx = 0; bx < nb; ++bx)
        wl[x*WLCAP + pos++] = (t << 16) | (bz << 12) | bx;
  }
}

__global__ __launch_bounds__(256) void scatter_kernel(
    const int* __restrict__ topk_idx, const float* __restrict__ topk_w,
    const int* __restrict__ offA, int* __restrict__ fill,
    int* __restrict__ list_tok, int* __restrict__ slot_of)
{
  int t = blockIdx.x*256 + threadIdx.x;
  if (t >= T_TOK) return;
  #pragma unroll
  for (int k = 0; k < 4; ++k) {
    int e = topk_idx[t*4+k];
    int pos = atomicAdd(&fill[e], 1);
    int s = offA[e] + pos;
    list_tok[s] = t;
    slot_of[t*4+k] = s;     // inverse map for non-atomic combine
  }
}

// ------------------------------------------------- R projections (pipelined)
// Y[T,128] = Xb[T,2048] @ W[128,2048]^T. A via gll dbuf; B-frags from global (L2-hot).
__global__ __launch_bounds__(256) void rproj_kernel(
    const ushort_t* __restrict__ xb,
    const ushort_t* __restrict__ Rg, const ushort_t* __restrict__ Ru,
    const ushort_t* __restrict__ sRg, const ushort_t* __restrict__ sRu,
    ushort_t* __restrict__ rg, ushort_t* __restrict__ ru,
    ushort_t* __restrict__ sa, ushort_t* __restrict__ su)
{
  __shared__ ushort_t abuf[2][64*128];
  const ushort_t* W; ushort_t* Y;
  switch (blockIdx.y) {
    case 0:  W = Rg;  Y = rg; break;
    case 1:  W = Ru;  Y = ru; break;
    case 2:  W = sRg; Y = sa; break;
    default: W = sRu; Y = su; break;
  }
  const int tid = threadIdx.x;
  const int lane = tid & 63, ln = lane & 15, q = lane >> 4;
  const int wv = tid >> 6, mh = wv >> 1, nh = wv & 1;
  const int r0 = blockIdx.x * 64;

  f32x4 acc[2][4];
  #pragma unroll
  for (int i = 0; i < 2; ++i)
    #pragma unroll
    for (int j = 0; j < 4; ++j) acc[i][j] = (f32x4){0.f,0.f,0.f,0.f};

  load_64x128_swz(xb + (size_t)r0*HD, HD, abuf[0], tid);
  for (int kt = 0; kt < 16; ++kt) {
    __syncthreads();                       // abuf[kt&1] ready
    if (kt+1 < 16)
      load_64x128_swz(xb + (size_t)r0*HD + (kt+1)*128, HD, abuf[(kt+1)&1], tid);
    const ushort_t* A = abuf[kt&1];
    #pragma unroll
    for (int c = 0; c < 4; ++c) {
      short8 a[2], b[4];
      #pragma unroll
      for (int i = 0; i < 2; ++i) {
        int rr = mh*32 + i*16 + ln;
        a[i] = *(const short8*)(A + rr*128 + (((c*4+q) ^ (rr&15)) << 3));
      }
      #pragma unroll
      for (int j = 0; j < 4; ++j)
        b[j] = *(const short8*)(W + (size_t)(nh*64 + j*16 + ln)*HD + kt*128 + c*32 + q*8);
      #pragma unroll
      for (int i = 0; i < 2; ++i)
        #pragma unroll
        for (int j = 0; j < 4; ++j) acc[i][j] = MF(a[i], b[j], acc[i][j]);
    }
  }
  #pragma unroll
  for (int i = 0; i < 2; ++i)
    #pragma unroll
    for (int j = 0; j < 4; ++j)
      #pragma unroll
      for (int r = 0; r < 4; ++r)
        Y[(size_t)(r0 + mh*32 + i*16 + q*4 + r)*128 + nh*64 + j*16 + ln] = f2b(acc[i][j][r]);
}

// -------- helper (cold path): acc = A_lds[64][SRK] @ Wg[128][128]^T, C in regs
__device__ __forceinline__ void gemm64x128_regs(
    int tid, const ushort_t* __restrict__ A, const ushort_t* __restrict__ Wg,
    ushort_t* __restrict__ stage, f32x4 acc[2][2][2])
{
  const int lane = tid & 63, ln = lane & 15, q = lane >> 4;
  const int wv = tid >> 6, mh = wv >> 1, nh = wv & 1;
  #pragma unroll
  for (int h = 0; h < 2; ++h)
    #pragma unroll
    for (int i = 0; i < 2; ++i)
      #pragma unroll
      for (int j = 0; j < 2; ++j) acc[h][i][j] = (f32x4){0.f,0.f,0.f,0.f};
  for (int h = 0; h < 2; ++h) {
    for (int li = tid; li < 64*16; li += 256) {
      int r = li >> 4, c = (li & 15) << 3;
      *(short8*)(stage + r*SRK + c) = *(const short8*)(Wg + (size_t)(h*64 + r)*128 + c);
    }
    __syncthreads();
    #pragma unroll
    for (int c = 0; c < 4; ++c) {
      short8 a[2], b[2];
      #pragma unroll
      for (int i = 0; i < 2; ++i)
        a[i] = *(const short8*)(A + (mh*32 + i*16 + ln)*SRK + c*32 + q*8);
      #pragma unroll
      for (int j = 0; j < 2; ++j)
        b[j] = *(const short8*)(stage + (nh*32 + j*16 + ln)*SRK + c*32 + q*8);
      #pragma unroll
      for (int i = 0; i < 2; ++i)
        #pragma unroll
        for (int j = 0; j < 2; ++j) acc[h][i][j] = MF(a[i], b[j], acc[h][i][j]);
    }
    __syncthreads();
  }
}

// ---------------------------------------------------------------- pair_proj
// t1[slot] = rg[tok(slot)] @ Ug_e^T ; t2 = ru @ Uu_e^T ; shared rows direct.
__global__ __launch_bounds__(256) void pair_proj_kernel(
    const ushort_t* __restrict__ rgb, const ushort_t* __restrict__ rub,
    const ushort_t* __restrict__ sab, const ushort_t* __restrict__ sub,
    const ushort_t* __restrict__ Ug, const ushort_t* __restrict__ Uu,
    const ushort_t* __restrict__ sUg, const ushort_t* __restrict__ sUu,
    const int* __restrict__ offA, const int* __restrict__ cntA,
    const int* __restrict__ list_tok,
    ushort_t* __restrict__ t1R, ushort_t* __restrict__ t2R,
    ushort_t* __restrict__ t1S, ushort_t* __restrict__ t2S)
{
  __shared__ ushort_t ldsX[64*SRK];
  __shared__ ushort_t stage[64*SRK];
  __shared__ int toks[64];
  const int tid = threadIdx.x;
  const int by = blockIdx.y;
  const bool shm = (by == NEXP);
  const int nrows = shm ? T_TOK : cntA[by];
  const int s0 = blockIdx.x * 64;
  if (s0 >= nrows) return;
  const int base = shm ? 0 : offA[by];
  const ushort_t* pUg = shm ? sUg : Ug + (size_t)by*128*128;
  const ushort_t* pUu = shm ? sUu : Uu + (size_t)by*128*128;
  const int lane = tid & 63, ln = lane & 15, q = lane >> 4;
  const int wv = tid >> 6, mh = wv >> 1, nh = wv & 1;

  if (tid < 64) {
    int sc = s0 + tid; if (sc > nrows-1) sc = nrows-1;
    toks[tid] = shm ? sc : list_tok[base + sc];
  }
  __syncthreads();

  f32x4 acc[2][2][2];
  // t1
  for (int li = tid; li < 64*16; li += 256) {
    int r = li >> 4, c = (li & 15) << 3;
    const ushort_t* src = shm ? sab : rgb;
    *(short8*)(ldsX + r*SRK + c) = *(const short8*)(src + (size_t)toks[r]*128 + c);
  }
  __syncthreads();
  gemm64x128_regs(tid, ldsX, pUg, stage, acc);
  {
    ushort_t* dst = shm ? t1S : (t1R + (size_t)base*128);
    #pragma unroll
    for (int h = 0; h < 2; ++h)
      #pragma unroll
      for (int i = 0; i < 2; ++i)
        #pragma unroll
        for (int r = 0; r < 4; ++r) {
          int gs = s0 + mh*32 + i*16 + q*4 + r;
          if (gs < nrows) {
            #pragma unroll
            for (int j = 0; j < 2; ++j)
              dst[(size_t)gs*128 + h*64 + nh*32 + j*16 + ln] = f2b(acc[h][i][j][r]);
          }
        }
  }
  // t2
  for (int li = tid; li < 64*16; li += 256) {
    int r = li >> 4, c = (li & 15) << 3;
    const ushort_t* src = shm ? sub : rub;
    *(short8*)(ldsX + r*SRK + c) = *(const short8*)(src + (size_t)toks[r]*128 + c);
  }
  __syncthreads();
  gemm64x128_regs(tid, ldsX, pUu, stage, acc);
  {
    ushort_t* dst = shm ? t2S : (t2R + (size_t)base*128);
    #pragma unroll
    for (int h = 0; h < 2; ++h)
      #pragma unroll
      for (int i = 0; i < 2; ++i)
        #pragma unroll
        for (int r = 0; r < 4; ++r) {
          int gs = s0 + mh*32 + i*16 + q*4 + r;
          if (gs < nrows) {
            #pragma unroll
            for (int j = 0; j < 2; ++j)
              dst[(size_t)gs*128 + h*64 + nh*32 + j*16 + ln] = f2b(acc[h][i][j][r]);
          }
        }
  }
}

// ---------------------------------------------------------------- mid (v7: balanced 2.0 items/block)
// 512 persistent blocks (2/CU, 80KB LDS). Work items: 512 routed (11 tiles) +
// 512 shared (8 chunks of 6/6/6/6/5/5/5/5 tiles) = 1024 = exactly 2.0/block;
// shared items first in each XCD list -> each block does ~1 shared + 1 routed
// (duration-balanced). v6's 768/512=1.5 left 25% of block-time idle.
__global__ __launch_bounds__(256, 1) void mid_kernel(
    const ushort_t* __restrict__ t1R, const ushort_t* __restrict__ t2R,
    const ushort_t* __restrict__ t1S, const ushort_t* __restrict__ t2S,
    const ushort_t* __restrict__ Cg, const ushort_t* __restrict__ Cu,
    const ushort_t* __restrict__ Rd,
    const ushort_t* __restrict__ sCg, const ushort_t* __restrict__ sCu,
    const ushort_t* __restrict__ sRd,
    const int* __restrict__ offA, const int* __restrict__ cntA,
    float* __restrict__ rdRp, float* __restrict__ rdSp,
    const int* __restrict__ wn, int* __restrict__ wcnt, const int* __restrict__ wl)
{
  __shared__ ushort_t ldsCg[2][64*128];   // 32 KB
  __shared__ ushort_t ldsCu[2][64*128];   // 32 KB
  __shared__ ushort_t ldsH [2][64*64];    // 16 KB  -> 80 KB total
  __shared__ int s_item;

  const int tid = threadIdx.x;
  const int lane = tid & 63, ln = lane & 15, q = lane >> 4;
  const int wv = tid >> 6, mh = wv >> 1, nh = wv & 1;
  const int xc0 = blockIdx.x & 7;

  for (int lx = 0; lx < 8; ++lx) {
    const int xc = (xc0 + lx) & 7;
    const int nww = wn[xc];
    for (;;) {
      __syncthreads();                       // prior item's LDS reads done; s_item consumed
      if (tid == 0) s_item = atomicAdd(&wcnt[xc], 1);
      __syncthreads();
      const int wi = s_item;
      if (wi >= nww) break;
      const int item = wl[xc*WLCAP + wi];
      const int by = item >> 16, bz = (item >> 12) & 15, bx = item & 4095;

      const bool shm = (by == NEXP);
      const int nrows = shm ? T_TOK : cntA[by];
      const int s0 = bx * 64;
      const int base = shm ? 0 : offA[by];
      const int Ifull = shm ? ISH : IR;
      const ushort_t* pCg = shm ? sCg : Cg + (size_t)by*IR*128;
      const ushort_t* pCu = shm ? sCu : Cu + (size_t)by*IR*128;
      const ushort_t* pRd = shm ? sRd : Rd;
      // chunk -> tile range: routed 2x11; shared 8 chunks 6/6/6/6/5/5/5/5 of 44
      int it0, nt;
      if (shm) { it0 = (bz < 4) ? 6*bz : 24 + 5*(bz-4); nt = (bz < 4) ? 6 : 5; }
      else     { it0 = bz*11; nt = 11; }

      // t1/t2 A-fragments -> registers (held across the K loop)
      short8 t1f[2][4], t2f[2][4];
      const ushort_t* srcT1 = shm ? t1S : (t1R + (size_t)base*128);
      const ushort_t* srcT2 = shm ? t2S : (t2R + (size_t)base*128);
      #pragma unroll
      for (int i = 0; i < 2; ++i) {
        int r = s0 + mh*32 + i*16 + ln; if (r > nrows-1) r = nrows-1;
        #pragma unroll
        for (int c = 0; c < 4; ++c) {
          t1f[i][c] = *(const short8*)(srcT1 + (size_t)r*128 + c*32 + q*8);
          t2f[i][c] = *(const short8*)(srcT2 + (size_t)r*128 + c*32 + q*8);
        }
      }

      load_64x128_swz(pCg + (size_t)it0*64*128, 128, ldsCg[0], tid);
      load_64x128_swz(pCu + (size_t)it0*64*128, 128, ldsCu[0], tid);

      f32x4 rdacc[2][4];
      #pragma unroll
      for (int i = 0; i < 2; ++i)
        #pragma unroll
        for (int j = 0; j < 4; ++j) rdacc[i][j] = (f32x4){0.f,0.f,0.f,0.f};

      const size_t rdRow = (size_t)(nh*64 + ln)*Ifull + q*8;  // + j*16*Ifull + i0 + c2*32

      __syncthreads();   // tile 0 staged

      for (int it = 0; it < nt; ++it) {
        const int i0 = (it0 + it) * 64;
        const int cb = it & 1;
        // 1. preload Rd B-frags for phaseB(it-1) FIRST (vmcnt in-order: waiting
        //    for these must not force the gll prefetch issued after them)
        short8 rb[2][4];
        if (it > 0) {
          const int ip = i0 - 64;
          #pragma unroll
          for (int c2 = 0; c2 < 2; ++c2)
            #pragma unroll
            for (int j = 0; j < 4; ++j)
              rb[c2][j] = *(const short8*)(pRd + rdRow + (size_t)(j*16)*Ifull + ip + c2*32);
        }
        // 2. prefetch Cg/Cu(it+1) into the idle buffers (drains at THIS barrier)
        if (it+1 < nt) {
          load_64x128_swz(pCg + (size_t)(i0+64)*128, 128, ldsCg[cb^1], tid);
          load_64x128_swz(pCu + (size_t)(i0+64)*128, 128, ldsCu[cb^1], tid);
        }
        // 3. phaseA(it): g,u from regs x ldsCg/Cu[cb]; silu; h -> ldsH[cb]
        f32x4 g[2][2], u[2][2];
        #pragma unroll
        for (int i = 0; i < 2; ++i)
          #pragma unroll
          for (int j = 0; j < 2; ++j) { g[i][j] = (f32x4){0.f,0.f,0.f,0.f}; u[i][j] = (f32x4){0.f,0.f,0.f,0.f}; }
        #pragma unroll
        for (int c = 0; c < 4; ++c) {
          #pragma unroll
          for (int j = 0; j < 2; ++j) {
            int rr = nh*32 + j*16 + ln;
            int off = rr*128 + (((c*4+q) ^ (rr&15)) << 3);
            short8 bg = *(const short8*)(ldsCg[cb] + off);
            short8 bu = *(const short8*)(ldsCu[cb] + off);
            #pragma unroll
            for (int i = 0; i < 2; ++i) {
              g[i][j] = MF(t1f[i][c], bg, g[i][j]);
              u[i][j] = MF(t2f[i][c], bu, u[i][j]);
            }
          }
        }
        #pragma unroll
        for (int i = 0; i < 2; ++i)
          #pragma unroll
          for (int j = 0; j < 2; ++j) {
            float hv[4];
            #pragma unroll
            for (int r = 0; r < 4; ++r) {
              float gv = g[i][j][r];
              hv[r] = gv * fast_rcp(1.f + __expf(-gv)) * u[i][j][r];
            }
            unsigned p01 = cvt_pk_bf16(hv[0], hv[1]);
            unsigned p23 = cvt_pk_bf16(hv[2], hv[3]);
            const int hc = nh*32 + j*16 + ln;
            const int hb = mh*32 + i*16 + q*4;
            #pragma unroll
            for (int r = 0; r < 4; ++r) {
              int hr = hb + r;
              ushort_t v = (r==0) ? (ushort_t)p01 : (r==1) ? (ushort_t)(p01>>16)
                         : (r==2) ? (ushort_t)p23 : (ushort_t)(p23>>16);
              ldsH[cb][hr*64 + (((hc>>3) ^ (hr&7)) << 3) + (hc&7)] = v;
            }
          }
        // 4. phaseB(it-1): rd += h[cb^1] @ Rd (h written last iter, barrier'd)
        if (it > 0) {
          #pragma unroll
          for (int c2 = 0; c2 < 2; ++c2) {
            short8 a[2];
            #pragma unroll
            for (int i = 0; i < 2; ++i) {
              int rr = mh*32 + i*16 + ln;
              a[i] = *(const short8*)(ldsH[cb^1] + rr*64 + (((c2*4+q) ^ (rr&7)) << 3));
            }
            #pragma unroll
            for (int j = 0; j < 4; ++j)
              #pragma unroll
              for (int i = 0; i < 2; ++i) rdacc[i][j] = MF(a[i], rb[c2][j], rdacc[i][j]);
          }
        }
        __syncthreads();   // ONE barrier/iter: h[cb] visible next iter; gll(it+1) landed
      }
      // epilogue: phaseB(nt-1)
      {
        const int ip = (it0 + nt - 1) * 64;
        const int cb = (nt - 1) & 1;
        #pragma unroll
        for (int c2 = 0; c2 < 2; ++c2) {
          short8 a[2];
          #pragma unroll
          for (int i = 0; i < 2; ++i) {
            int rr = mh*32 + i*16 + ln;
            a[i] = *(const short8*)(ldsH[cb] + rr*64 + (((c2*4+q) ^ (rr&7)) << 3));
          }
          #pragma unroll
          for (int j = 0; j < 4; ++j) {
            short8 b = *(const short8*)(pRd + rdRow + (size_t)(j*16)*Ifull + ip + c2*32);
            #pragma unroll
            for (int i = 0; i < 2; ++i) rdacc[i][j] = MF(a[i], b, rdacc[i][j]);
          }
        }
      }

      // plain disjoint stores (no atomics): part bz of 2 (routed) or 8 (shared)
      float* dst = shm ? (rdSp + (size_t)bz*T_TOK*128)
                       : (rdRp + (size_t)bz*NPAIR*128 + (size_t)base*128);
      #pragma unroll
      for (int i = 0; i < 2; ++i) {
        #pragma unroll
        for (int r = 0; r < 4; ++r) {
          int gs = s0 + mh*32 + i*16 + q*4 + r;
          if (gs < nrows) {
            #pragma unroll
            for (int j = 0; j < 4; ++j)
              dst[(size_t)gs*128 + nh*64 + j*16 + ln] = rdacc[i][j][r];
          }
        }
      }
    }
  }
}

// ---------------------------------------------------------------- out
// grid (64, 33, 2). t3 frags in regs; Cd double-buffered via gll; 1 barrier/tile.
// LDS diet: ldsT ALIASES ldsA (all A-reads complete at gemm's final barrier
// before ldsT written) -> smem 52.7->34.8 KB -> 4 blocks/CU (was 3).
// Balanced expert-clustered XCD map. NO atomics: routed y -> ybufR (bf16,
// per-slot, unweighted); shared y -> out directly (fp32 plain stores).
__global__ __launch_bounds__(256) void out_kernel(
    const float* __restrict__ rdRp, const float* __restrict__ rdSp,
    const ushort_t* __restrict__ Ud, const ushort_t* __restrict__ Cd,
    const ushort_t* __restrict__ sUd, const ushort_t* __restrict__ sCd,
    const int* __restrict__ offA, const int* __restrict__ cntA,
    ushort_t* __restrict__ ybufR, float* __restrict__ out)
{
  __shared__ ushort_t smem[2*64*SRK];   // prologue: ldsA(=ldsT) | stage ; loop: cd0,cd1
  ushort_t* ldsA  = smem;
  ushort_t* stage = smem + 64*SRK;
  ushort_t* ldsT  = smem;               // aliases ldsA (safe: see header comment)
  ushort_t* cd0   = smem;
  ushort_t* cd1   = smem + 64*128;

  // balanced XCD map (4224 blocks, 528 per XCD):
  //   routed m<512: by=(m>>7)*8+x, bzz=(m>>6)&1, bx=m&63
  //   shared m>=512: by=32, bzz=(m-512)>>3, bx=((m-512)&7)*8+x
  const int hh = blockIdx.x + 64*(blockIdx.y + 33*blockIdx.z);
  const int xc = hh & 7, m = hh >> 3;
  int bx, by, bzz;
  if (m < 512) { by = (m >> 7)*8 + xc; bzz = (m >> 6) & 1; bx = m & 63; }
  else         { int mm = m - 512; by = NEXP; bzz = mm >> 3; bx = ((mm & 7) << 3) + xc; }

  const int tid = threadIdx.x;
  const bool shm = (by == NEXP);
  const int nrows = shm ? T_TOK : cntA[by];
  const int s0 = bx * 64;
  if (s0 >= nrows) return;
  const int base = shm ? 0 : offA[by];
  const int ct0 = bzz * 16;
  const ushort_t* pUd = shm ? sUd : Ud + (size_t)by*128*128;
  const ushort_t* pCd = shm ? sCd : Cd + (size_t)by*HD*128;

  const int lane = tid & 63, ln = lane & 15, q = lane >> 4;
  const int wv = tid >> 6, mh = wv >> 1, nh = wv & 1;

  // gather rd rows: sum the per-bz partials (fp32) -> bf16 ldsA
  for (int li = tid; li < 64*32; li += 256) {
    int r = li >> 5, c4 = li & 31;
    int row = s0 + r; if (row > nrows-1) row = nrows-1;
    float4 v;
    if (shm) {
      const float* p = rdSp + (size_t)row*128 + c4*4;
      v = *(const float4*)p;
      #pragma unroll
      for (int pp = 1; pp < 8; ++pp) {
        float4 w2 = *(const float4*)(p + (size_t)pp*T_TOK*128);
        v.x += w2.x; v.y += w2.y; v.z += w2.z; v.w += w2.w;
      }
    } else {
      const float* p = rdRp + (size_t)(base+row)*128 + c4*4;
      v = *(const float4*)p;
      float4 w2 = *(const float4*)(p + (size_t)NPAIR*128);
      v.x += w2.x; v.y += w2.y; v.z += w2.z; v.w += w2.w;
    }
    ushort4 o; o.x=f2b(v.x); o.y=f2b(v.y); o.z=f2b(v.z); o.w=f2b(v.w);
    *(ushort4*)(ldsA + r*SRK + c4*4) = o;
  }
  __syncthreads();

  f32x4 acc[2][2][2];
  gemm64x128_regs(tid, ldsA, pUd, stage, acc);
  // C -> ldsT (= ldsA; all A-reads done at gemm's last barrier), then extract A-frags
  #pragma unroll
  for (int h = 0; h < 2; ++h)
    #pragma unroll
    for (int i = 0; i < 2; ++i)
      #pragma unroll
      for (int j = 0; j < 2; ++j)
        #pragma unroll
        for (int r = 0; r < 4; ++r)
          ldsT[(mh*32 + i*16 + q*4 + r)*SRK + h*64 + nh*32 + j*16 + ln] = f2b(acc[h][i][j][r]);
  __syncthreads();
  short8 t3f[2][4];
  #pragma unroll
  for (int i = 0; i < 2; ++i)
    #pragma unroll
    for (int c = 0; c < 4; ++c)
      t3f[i][c] = *(const short8*)(ldsT + (mh*32 + i*16 + ln)*SRK + c*32 + q*8);
  __syncthreads();   // smem free for cd buffers

  load_64x128_swz(pCd + (size_t)ct0*64*128, 128, cd0, tid);
  for (int tt = 0; tt < 16; ++tt) {
    __syncthreads();                      // cd[tt&1] ready; prior reads drained
    ushort_t* cur = (tt & 1) ? cd1 : cd0;
    ushort_t* nxt = (tt & 1) ? cd0 : cd1;
    if (tt+1 < 16)
      load_64x128_swz(pCd + (size_t)(ct0+tt+1)*64*128, 128, nxt, tid);
    f32x4 y[2][2];
    #pragma unroll
    for (int i = 0; i < 2; ++i)
      #pragma unroll
      for (int j = 0; j < 2; ++j) y[i][j] = (f32x4){0.f,0.f,0.f,0.f};
    #pragma unroll
    for (int c = 0; c < 4; ++c) {
      #pragma unroll
      for (int j = 0; j < 2; ++j) {
        int rr = nh*32 + j*16 + ln;
        short8 b = *(const short8*)(cur + rr*128 + (((c*4+q) ^ (rr&15)) << 3));
        #pragma unroll
        for (int i = 0; i < 2; ++i) y[i][j] = MF(t3f[i][c], b, y[i][j]);
      }
    }
    #pragma unroll
    for (int i = 0; i < 2; ++i) {
      #pragma unroll
      for (int r = 0; r < 4; ++r) {
        int lr = mh*32 + i*16 + q*4 + r;
        int gs = s0 + lr;
        if (gs < nrows) {
          if (shm) {
            size_t ob = (size_t)gs*HD + (ct0 + tt)*64;
            #pragma unroll
            for (int j = 0; j < 2; ++j)
              out[ob + nh*32 + j*16 + ln] = y[i][j][r];
          } else {
            size_t ob = (size_t)(base + gs)*HD + (ct0 + tt)*64;
            #pragma unroll
            for (int j = 0; j < 2; ++j)
              ybufR[ob + nh*32 + j*16 + ln] = f2b(y[i][j][r]);
          }
        }
      }
    }
  }
}

// ---------------------------------------------------------------- combine
// out[t] = out[t] (shared, already stored) + sum_k w_k * ybufR[slot_of[t,k]]
// One block per token row; fully coalesced, no atomics.
__global__ __launch_bounds__(256) void combine_kernel(
    const ushort_t* __restrict__ ybufR,
    const int* __restrict__ slot_of, const float* __restrict__ topk_w,
    float* __restrict__ out)
{
  __shared__ int   ss[4];
  __shared__ float ww[4];
  const int t = blockIdx.x;
  if (threadIdx.x < 4) {
    ss[threadIdx.x] = slot_of[t*4 + threadIdx.x];
    ww[threadIdx.x] = topk_w[t*4 + threadIdx.x];
  }
  __syncthreads();
  const int c = threadIdx.x * 8;
  const size_t tb = (size_t)t*HD + c;
  float o[8];
  float4 a0 = *(const float4*)(out + tb);
  float4 a1 = *(const float4*)(out + tb + 4);
  o[0]=a0.x; o[1]=a0.y; o[2]=a0.z; o[3]=a0.w;
  o[4]=a1.x; o[5]=a1.y; o[6]=a1.z; o[7]=a1.w;
  #pragma unroll
  for (int k = 0; k < 4; ++k) {
    short8 rv = *(const short8*)(ybufR + (size_t)ss[k]*HD + c);
    float wk = ww[k];
    #pragma unroll
    for (int u = 0; u < 8; ++u)
      o[u] += wk * b2f((ushort_t)rv[u]);
  }
  float4 b0 = {o[0],o[1],o[2],o[3]};
  float4 b1 = {o[4],o[5],o[6],o[7]};
  *(float4*)(out + tb)     = b0;
  *(float4*)(out + tb + 4) = b1;
}

// ---------------------------------------------------------------- launch
extern "C" void kernel_launch(void* const* d_in, const int* in_sizes, int n_in,
                              void* d_out, int out_size, void* d_ws, size_t ws_size,
                              hipStream_t stream) {
  const float* x    = (const float*)d_in[0];
  const float* gw   = (const float*)d_in[1];
  const float* Rg   = (const float*)d_in[2];
  const float* Ru   = (const float*)d_in[3];
  const float* Rd   = (const float*)d_in[4];
  const float* Ug   = (const float*)d_in[5];
  const float* Cg   = (const float*)d_in[6];
  const float* Uu   = (const float*)d_in[7];
  const float* Cu   = (const float*)d_in[8];
  const float* Ud   = (const float*)d_in[9];
  const float* Cd   = (const float*)d_in[10];
  const float* sRg  = (const float*)d_in[11];
  const float* sUg  = (const float*)d_in[12];
  const float* sCg  = (const float*)d_in[13];
  const float* sRu  = (const float*)d_in[14];
  const float* sUu  = (const float*)d_in[15];
  const float* sCu  = (const float*)d_in[16];
  const float* sRd  = (const float*)d_in[17];
  const float* sUd  = (const float*)d_in[18];
  const float* sCd  = (const float*)d_in[19];
  float* out = (float*)d_out;

  char* w = (char*)d_ws;
  auto alloc = [&](size_t bytes) -> void* {
    void* p = (void*)w; w += (bytes + 255) & ~(size_t)255; return p;
  };
  int*   cnt      = (int*)  alloc(NEXP*sizeof(int));
  int*   offA     = (int*)  alloc((NEXP+1)*sizeof(int));
  int*   fill     = (int*)  alloc(NEXP*sizeof(int));
  int*   topk_idx = (int*)  alloc((size_t)T_TOK*4*sizeof(int));
  float* topk_w   = (float*)alloc((size_t)T_TOK*4*sizeof(float));
  int*   list_tok = (int*)  alloc((size_t)NPAIR*sizeof(int));
  int*   slot_of  = (int*)  alloc((size_t)T_TOK*4*sizeof(int));
  int*   wn       = (int*)  alloc(8*sizeof(int));
  int*   wcnt     = (int*)  alloc(8*sizeof(int));
  int*   wl       = (int*)  alloc((size_t)8*WLCAP*sizeof(int));
  ushort_t* xb   = (ushort_t*)alloc((size_t)T_TOK*HD*2);   // later reused as rdRp (fp32, 2 parts)
  ushort_t* Rgb  = (ushort_t*)alloc((size_t)128*HD*2);
  ushort_t* Rub  = (ushort_t*)alloc((size_t)128*HD*2);
  ushort_t* Rdb  = (ushort_t*)alloc((size_t)128*IR*2);
  ushort_t* Ugb  = (ushort_t*)alloc((size_t)NEXP*128*128*2);
  ushort_t* Cgb  = (ushort_t*)alloc((size_t)NEXP*IR*128*2);
  ushort_t* Uub  = (ushort_t*)alloc((size_t)NEXP*128*128*2);
  ushort_t* Cub  = (ushort_t*)alloc((size_t)NEXP*IR*128*2);
  ushort_t* Udb  = (ushort_t*)alloc((size_t)NEXP*128*128*2);
  ushort_t* Cdb  = (ushort_t*)alloc((size_t)NEXP*HD*128*2);
  ushort_t* sRgb = (ushort_t*)alloc((size_t)128*HD*2);
  ushort_t* sUgb = (ushort_t*)alloc((size_t)128*128*2);
  ushort_t* sCgb = (ushort_t*)alloc((size_t)ISH*128*2);
  ushort_t* sRub = (ushort_t*)alloc((size_t)128*HD*2);
  ushort_t* sUub = (ushort_t*)alloc((size_t)128*128*2);
  ushort_t* sCub = (ushort_t*)alloc((size_t)ISH*128*2);
  ushort_t* sRdb = (ushort_t*)alloc((size_t)128*ISH*2);
  ushort_t* sUdb = (ushort_t*)alloc((size_t)128*128*2);
  ushort_t* sCdb = (ushort_t*)alloc((size_t)HD*128*2);
  ushort_t* rg   = (ushort_t*)alloc((size_t)T_TOK*128*2);
  ushort_t* ru   = (ushort_t*)alloc((size_t)T_TOK*128*2);
  ushort_t* sa   = (ushort_t*)alloc((size_t)T_TOK*128*2);
  ushort_t* su   = (ushort_t*)alloc((size_t)T_TOK*128*2);
  ushort_t* t1R  = (ushort_t*)alloc((size_t)NPAIR*128*2);
  ushort_t* t2R  = (ushort_t*)alloc((size_t)NPAIR*128*2);
  ushort_t* t1S  = (ushort_t*)alloc((size_t)T_TOK*128*2);
  ushort_t* t2S  = (ushort_t*)alloc((size_t)T_TOK*128*2);
  float*    rdSp = (float*)   alloc((size_t)8*T_TOK*128*sizeof(float));  // 8 shared partials
  ushort_t* ybufR= (ushort_t*)alloc((size_t)NPAIR*HD*2);                 // per-slot routed y (bf16)
  (void)ws_size; (void)in_sizes; (void)n_in;

  // routed rd partials (fp32, 2 parts) alias xb exactly:
  // 2*NPAIR*128*4 = 16.78 MB == T_TOK*HD*2. xb is dead after rproj; mid writes it after.
  float* rdRp = (float*)xb;

  hipMemsetAsync(cnt,  0, NEXP*sizeof(int), stream);
  hipMemsetAsync(fill, 0, NEXP*sizeof(int), stream);
  hipMemsetAsync(wcnt, 0, 8*sizeof(int), stream);
  // no out memset: out_kernel's shared path fully writes out; combine RMWs it.

  // fused cvt
  CvtSegs cs;
  const float* ss[NSEG] = {x,Rg,Ru,Rd,Ug,Cg,Uu,Cu,Ud,Cd,sRg,sUg,sCg,sRu,sUu,sCu,sRd,sUd,sCd};
  ushort_t* dd[NSEG] = {xb,Rgb,Rub,Rdb,Ugb,Cgb,Uub,Cub,Udb,Cdb,sRgb,sUgb,sCgb,sRub,sUub,sCub,sRdb,sUdb,sCdb};
  size_t nn[NSEG] = {(size_t)T_TOK*HD,(size_t)128*HD,(size_t)128*HD,(size_t)128*IR,
                     (size_t)NEXP*128*128,(size_t)NEXP*IR*128,(size_t)NEXP*128*128,(size_t)NEXP*IR*128,
                     (size_t)NEXP*128*128,(size_t)NEXP*HD*128,(size_t)128*HD,(size_t)128*128,
                     (size_t)ISH*128,(size_t)128*HD,(size_t)128*128,(size_t)ISH*128,
                     (size_t)128*ISH,(size_t)128*128,(size_t)HD*128};
  int tot_blk = 0;
  for (int k = 0; k < NSEG; ++k) {
    cs.s[k] = ss[k]; cs.d[k] = dd[k];
    cs.n4[k] = (int)(nn[k] >> 2);
    cs.blk0[k] = tot_blk;
    tot_blk += (cs.n4[k] + 255) / 256;
  }
  cs.blk0[NSEG] = tot_blk;
  cvt_all_kernel<<<tot_blk, 256, 0, stream>>>(cs);

  gate_kernel<<<T_TOK/4, 256, 0, stream>>>(x, gw, topk_idx, topk_w, cnt);
  scan_kernel<<<1, 64, 0, stream>>>(cnt, offA);
  plan_kernel<<<1, 256, 0, stream>>>(cnt, wn, wl);
  scatter_kernel<<<T_TOK/256, 256, 0, stream>>>(topk_idx, topk_w, offA, fill, list_tok, slot_of);
  rproj_kernel<<<dim3(T_TOK/64, 4), 256, 0, stream>>>(xb, Rgb, Rub, sRgb, sRub, rg, ru, sa, su);
  pair_proj_kernel<<<dim3(64, NEXP+1), 256, 0, stream>>>(
      rg, ru, sa, su, Ugb, Uub, sUgb, sUub, offA, cnt, list_tok, t1R, t2R, t1S, t2S);
  mid_kernel<<<512, 256, 0, stream>>>(
      t1R, t2R, t1S, t2S, Cgb, Cub, Rdb, sCgb, sCub, sRdb, offA, cnt, rdRp, rdSp,
      wn, wcnt, wl);
  out_kernel<<<dim3(64, 33, 2), 256, 0, stream>>>(
      rdRp, rdSp, Udb, Cdb, sUdb, sCdb, offA, cnt, ybufR, out);
  combine_kernel<<<T_TOK, 256, 0, stream>>>(ybufR, slot_of, topk_w, out);
}

// Round 13
// 576.068 us; speedup vs baseline: 1.3918x; 1.0002x over previous
//
#include <hip/hip_runtime.h>
#include <math.h>

#define T_TOK 4096
#define HD    2048
#define NEXP  32
#define IR    1408
#define ISH   2816
#define NPAIR (T_TOK*4)
#define SRK   136      // padded bf16 row stride (cold paths only)
#define MTILES 11      // I-tiles (of 64) per chunk: routed 2 chunks, shared 4
#define WLCAP 2048     // per-XCD work-list capacity

typedef unsigned short ushort_t;
typedef __attribute__((ext_vector_type(8))) short    short8;
typedef __attribute__((ext_vector_type(8))) __bf16   bf16x8;
typedef __attribute__((ext_vector_type(4))) float    f32x4;

__device__ __forceinline__ f32x4 MF(short8 a, short8 b, f32x4 c) {
  return __builtin_amdgcn_mfma_f32_16x16x32_bf16(
      __builtin_bit_cast(bf16x8, a), __builtin_bit_cast(bf16x8, b), c, 0, 0, 0);
}
__device__ __forceinline__ ushort_t f2b(float f) {
  unsigned u = __float_as_uint(f);
  unsigned r = (u + 0x7fffu + ((u >> 16) & 1u)) >> 16;   // RNE
  return (ushort_t)r;
}
__device__ __forceinline__ float b2f(ushort_t b) {
  return __uint_as_float(((unsigned)b) << 16);
}
__device__ __forceinline__ float fast_rcp(float x) {     // v_rcp_f32: 1 inst, ~1ulp
  float r; asm("v_rcp_f32 %0, %1" : "=v"(r) : "v"(x)); return r;
}
__device__ __forceinline__ unsigned cvt_pk_bf16(float lo, float hi) {  // RNE pack
  unsigned r; asm("v_cvt_pk_bf16_f32 %0, %1, %2" : "=v"(r) : "v"(lo), "v"(hi)); return r;
}

// async global->LDS 16B; LDS dst must be wave-uniform base (+lane*16 implicit)
__device__ __forceinline__ void gll16(const ushort_t* g, ushort_t* l) {
  __builtin_amdgcn_global_load_lds(
      (const __attribute__((address_space(1))) unsigned int*)(const void*)g,
      (__attribute__((address_space(3))) unsigned int*)(void*)l, 16, 0, 0);
}

// ---- swizzled tile loader (XOR swizzle: phys chunk = logical ^ (row&mask)) ----
// 64 rows x 128 cols bf16 (16 chunks/row). One instr = 4 rows.
__device__ __forceinline__ void load_64x128_swz(
    const ushort_t* __restrict__ g, size_t gstride, ushort_t* lds, int tid)
{
  const int lane = tid & 63, w = tid >> 6;
  #pragma unroll
  for (int s = 0; s < 4; ++s) {
    int rbase = s*16 + w*4;
    int r = rbase + (lane >> 4);
    int p = lane & 15;
    gll16(g + (size_t)r*gstride + ((p ^ (r & 15)) << 3), lds + rbase*128);
  }
}
// read elem(row r, chunk c of 8hw): lds[r*128 + ((c^(r&15))<<3)]

// ---------------------------------------------------------------- fused cvt
#define NSEG 19
struct CvtSegs {
  const float* s[NSEG];
  ushort_t* d[NSEG];
  int n4[NSEG];
  int blk0[NSEG+1];
};
__global__ __launch_bounds__(256) void cvt_all_kernel(CvtSegs cs)
{
  int b = blockIdx.x;
  int k = 0;
  #pragma unroll 1
  while (k+1 < NSEG && b >= cs.blk0[k+1]) ++k;
  int i = (b - cs.blk0[k])*256 + threadIdx.x;
  if (i < cs.n4[k]) {
    float4 v = ((const float4*)cs.s[k])[i];
    ushort4 o; o.x=f2b(v.x); o.y=f2b(v.y); o.z=f2b(v.z); o.w=f2b(v.w);
    ((ushort4*)cs.d[k])[i] = o;
  }
}

// ---------------------------------------------------------------- gate
// 4 tokens/block (4 waves); gw staged through LDS per 128-k chunk.
__global__ __launch_bounds__(256) void gate_kernel(
    const float* __restrict__ x, const float* __restrict__ gw,
    int* __restrict__ topk_idx, float* __restrict__ topk_w, int* __restrict__ cnt)
{
  __shared__ float gws[32*132];
  __shared__ float xs[4*132];
  const int tid = threadIdx.x;
  const int w = tid >> 6, lane = tid & 63;
  const int t0 = blockIdx.x * 4;
  const int e = lane & 31, half = lane >> 5;

  float acc = 0.f;
  for (int ck = 0; ck < HD/128; ++ck) {
    for (int li = tid; li < 1024; li += 256) {        // gw chunk 32x128
      int r = li >> 5, c4 = li & 31;
      *(float4*)(gws + r*132 + c4*4) = *(const float4*)(gw + (size_t)r*HD + ck*128 + c4*4);
    }
    for (int li = tid; li < 128; li += 256) {          // x chunk 4x128
      int r = li >> 5, c4 = li & 31;
      *(float4*)(xs + r*132 + c4*4) = *(const float4*)(x + (size_t)(t0+r)*HD + ck*128 + c4*4);
    }
    __syncthreads();
    #pragma unroll
    for (int k4 = 0; k4 < 16; ++k4) {
      float4 xv = *(const float4*)(xs + w*132 + half*64 + k4*4);
      float4 wv = *(const float4*)(gws + e*132 + half*64 + k4*4);
      acc += xv.x*wv.x + xv.y*wv.y + xv.z*wv.z + xv.w*wv.w;
    }
    __syncthreads();
  }
  float p = acc;
  p += __shfl_down(p, 32);
  float logit = (lane < 32) ? p : -INFINITY;
  float m = logit;
  #pragma unroll
  for (int o = 32; o >= 1; o >>= 1) m = fmaxf(m, __shfl_xor(m, o));
  float ex = (lane < 32) ? expf(logit - m) : 0.f;
  float se = ex;
  #pragma unroll
  for (int o = 32; o >= 1; o >>= 1) se += __shfl_xor(se, o);
  float score = ex / se;

  bool taken = false;
  float selw[4]; int seli[4];
  for (int k = 0; k < 4; ++k) {
    float cur = (lane < 32 && !taken) ? score : -1.f;
    float mm = cur;
    #pragma unroll
    for (int o = 32; o >= 1; o >>= 1) mm = fmaxf(mm, __shfl_xor(mm, o));
    unsigned long long b = __ballot(cur == mm);
    int il = __ffsll(b) - 1;
    if (lane == il) taken = true;
    selw[k] = mm; seli[k] = il;
  }
  float wsum = selw[0]+selw[1]+selw[2]+selw[3] + 1e-20f;
  int t = t0 + w;
  if (lane < 4) {
    topk_idx[t*4+lane] = seli[lane];
    topk_w[t*4+lane]  = selw[lane] / wsum;
    atomicAdd(&cnt[seli[lane]], 1);
  }
}

__global__ void scan_kernel(const int* __restrict__ cnt, int* __restrict__ offA)
{
  if (threadIdx.x == 0) {
    int a = 0;
    for (int e = 0; e < NEXP; ++e) { offA[e] = a; a += cnt[e]; }
    offA[NEXP] = a;
  }
}

// ---------------------------------------------------------------- plan
// Build per-XCD work lists for the persistent mid kernel (v6 split: 768 items).
// XCD x gets: 32 shared items (4 I-chunks x 8 bx) + routed items of experts e%8==x.
// item encoding: (by<<16) | (bz<<12) | bx
__global__ __launch_bounds__(256) void plan_kernel(
    const int* __restrict__ cnt, int* __restrict__ wn, int* __restrict__ wl)
{
  const int t = threadIdx.x;
  if (t < 8) wn[t] = 32;
  __syncthreads();
  {
    int x = t >> 5, i = t & 31;                 // 256 threads -> 8 XCDs x 32 shared items
    int bz = i >> 3, bx = ((i & 7) << 3) + x;   // bz in [0,4), bx covers 0..63 once
    wl[x*WLCAP + i] = (NEXP << 16) | (bz << 12) | bx;
  }
  __syncthreads();
  if (t < NEXP) {
    int nb = (cnt[t] + 63) >> 6;
    int x = t & 7;
    int pos = atomicAdd(&wn[x], nb*2);
    for (int bz = 0; bz < 2; ++bz)
      for (int bx = 0; bx < nb; ++bx)
        wl[x*WLCAP + pos++] = (t << 16) | (bz << 12) | bx;
  }
}

__global__ __launch_bounds__(256) void scatter_kernel(
    const int* __restrict__ topk_idx, const float* __restrict__ topk_w,
    const int* __restrict__ offA, int* __restrict__ fill,
    int* __restrict__ list_tok, int* __restrict__ slot_of)
{
  int t = blockIdx.x*256 + threadIdx.x;
  if (t >= T_TOK) return;
  #pragma unroll
  for (int k = 0; k < 4; ++k) {
    int e = topk_idx[t*4+k];
    int pos = atomicAdd(&fill[e], 1);
    int s = offA[e] + pos;
    list_tok[s] = t;
    slot_of[t*4+k] = s;     // inverse map for non-atomic combine
  }
}

// ------------------------------------------------- R projections (pipelined)
// Y[T,128] = Xb[T,2048] @ W[128,2048]^T. A via gll dbuf; B-frags from global (L2-hot).
__global__ __launch_bounds__(256) void rproj_kernel(
    const ushort_t* __restrict__ xb,
    const ushort_t* __restrict__ Rg, const ushort_t* __restrict__ Ru,
    const ushort_t* __restrict__ sRg, const ushort_t* __restrict__ sRu,
    ushort_t* __restrict__ rg, ushort_t* __restrict__ ru,
    ushort_t* __restrict__ sa, ushort_t* __restrict__ su)
{
  __shared__ ushort_t abuf[2][64*128];
  const ushort_t* W; ushort_t* Y;
  switch (blockIdx.y) {
    case 0:  W = Rg;  Y = rg; break;
    case 1:  W = Ru;  Y = ru; break;
    case 2:  W = sRg; Y = sa; break;
    default: W = sRu; Y = su; break;
  }
  const int tid = threadIdx.x;
  const int lane = tid & 63, ln = lane & 15, q = lane >> 4;
  const int wv = tid >> 6, mh = wv >> 1, nh = wv & 1;
  const int r0 = blockIdx.x * 64;

  f32x4 acc[2][4];
  #pragma unroll
  for (int i = 0; i < 2; ++i)
    #pragma unroll
    for (int j = 0; j < 4; ++j) acc[i][j] = (f32x4){0.f,0.f,0.f,0.f};

  load_64x128_swz(xb + (size_t)r0*HD, HD, abuf[0], tid);
  for (int kt = 0; kt < 16; ++kt) {
    __syncthreads();                       // abuf[kt&1] ready
    if (kt+1 < 16)
      load_64x128_swz(xb + (size_t)r0*HD + (kt+1)*128, HD, abuf[(kt+1)&1], tid);
    const ushort_t* A = abuf[kt&1];
    #pragma unroll
    for (int c = 0; c < 4; ++c) {
      short8 a[2], b[4];
      #pragma unroll
      for (int i = 0; i < 2; ++i) {
        int rr = mh*32 + i*16 + ln;
        a[i] = *(const short8*)(A + rr*128 + (((c*4+q) ^ (rr&15)) << 3));
      }
      #pragma unroll
      for (int j = 0; j < 4; ++j)
        b[j] = *(const short8*)(W + (size_t)(nh*64 + j*16 + ln)*HD + kt*128 + c*32 + q*8);
      #pragma unroll
      for (int i = 0; i < 2; ++i)
        #pragma unroll
        for (int j = 0; j < 4; ++j) acc[i][j] = MF(a[i], b[j], acc[i][j]);
    }
  }
  #pragma unroll
  for (int i = 0; i < 2; ++i)
    #pragma unroll
    for (int j = 0; j < 4; ++j)
      #pragma unroll
      for (int r = 0; r < 4; ++r)
        Y[(size_t)(r0 + mh*32 + i*16 + q*4 + r)*128 + nh*64 + j*16 + ln] = f2b(acc[i][j][r]);
}

// -------- helper (cold path): acc = A_lds[64][SRK] @ Wg[128][128]^T, C in regs
__device__ __forceinline__ void gemm64x128_regs(
    int tid, const ushort_t* __restrict__ A, const ushort_t* __restrict__ Wg,
    ushort_t* __restrict__ stage, f32x4 acc[2][2][2])
{
  const int lane = tid & 63, ln = lane & 15, q = lane >> 4;
  const int wv = tid >> 6, mh = wv >> 1, nh = wv & 1;
  #pragma unroll
  for (int h = 0; h < 2; ++h)
    #pragma unroll
    for (int i = 0; i < 2; ++i)
      #pragma unroll
      for (int j = 0; j < 2; ++j) acc[h][i][j] = (f32x4){0.f,0.f,0.f,0.f};
  for (int h = 0; h < 2; ++h) {
    for (int li = tid; li < 64*16; li += 256) {
      int r = li >> 4, c = (li & 15) << 3;
      *(short8*)(stage + r*SRK + c) = *(const short8*)(Wg + (size_t)(h*64 + r)*128 + c);
    }
    __syncthreads();
    #pragma unroll
    for (int c = 0; c < 4; ++c) {
      short8 a[2], b[2];
      #pragma unroll
      for (int i = 0; i < 2; ++i)
        a[i] = *(const short8*)(A + (mh*32 + i*16 + ln)*SRK + c*32 + q*8);
      #pragma unroll
      for (int j = 0; j < 2; ++j)
        b[j] = *(const short8*)(stage + (nh*32 + j*16 + ln)*SRK + c*32 + q*8);
      #pragma unroll
      for (int i = 0; i < 2; ++i)
        #pragma unroll
        for (int j = 0; j < 2; ++j) acc[h][i][j] = MF(a[i], b[j], acc[h][i][j]);
    }
    __syncthreads();
  }
}

// ---------------------------------------------------------------- pair_proj
// t1[slot] = rg[tok(slot)] @ Ug_e^T ; t2 = ru @ Uu_e^T ; shared rows direct.
__global__ __launch_bounds__(256) void pair_proj_kernel(
    const ushort_t* __restrict__ rgb, const ushort_t* __restrict__ rub,
    const ushort_t* __restrict__ sab, const ushort_t* __restrict__ sub,
    const ushort_t* __restrict__ Ug, const ushort_t* __restrict__ Uu,
    const ushort_t* __restrict__ sUg, const ushort_t* __restrict__ sUu,
    const int* __restrict__ offA, const int* __restrict__ cntA,
    const int* __restrict__ list_tok,
    ushort_t* __restrict__ t1R, ushort_t* __restrict__ t2R,
    ushort_t* __restrict__ t1S, ushort_t* __restrict__ t2S)
{
  __shared__ ushort_t ldsX[64*SRK];
  __shared__ ushort_t stage[64*SRK];
  __shared__ int toks[64];
  const int tid = threadIdx.x;
  const int by = blockIdx.y;
  const bool shm = (by == NEXP);
  const int nrows = shm ? T_TOK : cntA[by];
  const int s0 = blockIdx.x * 64;
  if (s0 >= nrows) return;
  const int base = shm ? 0 : offA[by];
  const ushort_t* pUg = shm ? sUg : Ug + (size_t)by*128*128;
  const ushort_t* pUu = shm ? sUu : Uu + (size_t)by*128*128;
  const int lane = tid & 63, ln = lane & 15, q = lane >> 4;
  const int wv = tid >> 6, mh = wv >> 1, nh = wv & 1;

  if (tid < 64) {
    int sc = s0 + tid; if (sc > nrows-1) sc = nrows-1;
    toks[tid] = shm ? sc : list_tok[base + sc];
  }
  __syncthreads();

  f32x4 acc[2][2][2];
  // t1
  for (int li = tid; li < 64*16; li += 256) {
    int r = li >> 4, c = (li & 15) << 3;
    const ushort_t* src = shm ? sab : rgb;
    *(short8*)(ldsX + r*SRK + c) = *(const short8*)(src + (size_t)toks[r]*128 + c);
  }
  __syncthreads();
  gemm64x128_regs(tid, ldsX, pUg, stage, acc);
  {
    ushort_t* dst = shm ? t1S : (t1R + (size_t)base*128);
    #pragma unroll
    for (int h = 0; h < 2; ++h)
      #pragma unroll
      for (int i = 0; i < 2; ++i)
        #pragma unroll
        for (int r = 0; r < 4; ++r) {
          int gs = s0 + mh*32 + i*16 + q*4 + r;
          if (gs < nrows) {
            #pragma unroll
            for (int j = 0; j < 2; ++j)
              dst[(size_t)gs*128 + h*64 + nh*32 + j*16 + ln] = f2b(acc[h][i][j][r]);
          }
        }
  }
  // t2
  for (int li = tid; li < 64*16; li += 256) {
    int r = li >> 4, c = (li & 15) << 3;
    const ushort_t* src = shm ? sub : rub;
    *(short8*)(ldsX + r*SRK + c) = *(const short8*)(src + (size_t)toks[r]*128 + c);
  }
  __syncthreads();
  gemm64x128_regs(tid, ldsX, pUu, stage, acc);
  {
    ushort_t* dst = shm ? t2S : (t2R + (size_t)base*128);
    #pragma unroll
    for (int h = 0; h < 2; ++h)
      #pragma unroll
      for (int i = 0; i < 2; ++i)
        #pragma unroll
        for (int r = 0; r < 4; ++r) {
          int gs = s0 + mh*32 + i*16 + q*4 + r;
          if (gs < nrows) {
            #pragma unroll
            for (int j = 0; j < 2; ++j)
              dst[(size_t)gs*128 + h*64 + nh*32 + j*16 + ln] = f2b(acc[h][i][j][r]);
          }
        }
  }
}

// ---------------------------------------------------------------- mid (v8: LDS = exactly 80KB -> 2 blocks/CU)
// THE v6/v7 BUG: s_item (4B in LDS) pushed LDS to 82432 > 81920 -> only
// 1 block/CU = 1 wave/SIMD = zero latency hiding. Fix: broadcast the work-item
// index through a per-block GLOBAL slot (tid0 writes after atomicAdd;
// __syncthreads has block-scope global fence semantics). LDS = 81920 exactly
// -> 2 blocks/CU, 2 waves/SIMD. Work split reverted to v6 (768 items, 4
// shared partials) -- v7's 8-way split was measured-negative.
__global__ __launch_bounds__(256, 1) void mid_kernel(
    const ushort_t* __restrict__ t1R, const ushort_t* __restrict__ t2R,
    const ushort_t* __restrict__ t1S, const ushort_t* __restrict__ t2S,
    const ushort_t* __restrict__ Cg, const ushort_t* __restrict__ Cu,
    const ushort_t* __restrict__ Rd,
    const ushort_t* __restrict__ sCg, const ushort_t* __restrict__ sCu,
    const ushort_t* __restrict__ sRd,
    const int* __restrict__ offA, const int* __restrict__ cntA,
    float* __restrict__ rdRp, float* __restrict__ rdSp,
    const int* __restrict__ wn, int* __restrict__ wcnt, const int* __restrict__ wl,
    int* __restrict__ bcast)
{
  __shared__ ushort_t ldsCg[2][64*128];   // 32 KB
  __shared__ ushort_t ldsCu[2][64*128];   // 32 KB
  __shared__ ushort_t ldsH [2][64*64];    // 16 KB  -> 80 KB EXACTLY (no s_item!)

  const int tid = threadIdx.x;
  const int lane = tid & 63, ln = lane & 15, q = lane >> 4;
  const int wv = tid >> 6, mh = wv >> 1, nh = wv & 1;
  const int xc0 = blockIdx.x & 7;
  volatile int* myslot = bcast + blockIdx.x;   // global bcast slot (replaces LDS s_item)

  for (int lx = 0; lx < 8; ++lx) {
    const int xc = (xc0 + lx) & 7;
    const int nww = wn[xc];
    for (;;) {
      __syncthreads();                       // prior item's LDS reads done; slot consumed
      if (tid == 0) *myslot = atomicAdd(&wcnt[xc], 1);
      __syncthreads();                       // block-scope fence: write visible
      const int wi = *myslot;
      if (wi >= nww) break;
      const int item = wl[xc*WLCAP + wi];
      const int by = item >> 16, bz = (item >> 12) & 15, bx = item & 4095;

      const bool shm = (by == NEXP);
      const int nrows = shm ? T_TOK : cntA[by];
      const int s0 = bx * 64;
      const int base = shm ? 0 : offA[by];
      const int Ifull = shm ? ISH : IR;
      const ushort_t* pCg = shm ? sCg : Cg + (size_t)by*IR*128;
      const ushort_t* pCu = shm ? sCu : Cu + (size_t)by*IR*128;
      const ushort_t* pRd = shm ? sRd : Rd;
      const int it0 = bz * MTILES;

      // t1/t2 A-fragments -> registers (held across the K loop)
      short8 t1f[2][4], t2f[2][4];
      const ushort_t* srcT1 = shm ? t1S : (t1R + (size_t)base*128);
      const ushort_t* srcT2 = shm ? t2S : (t2R + (size_t)base*128);
      #pragma unroll
      for (int i = 0; i < 2; ++i) {
        int r = s0 + mh*32 + i*16 + ln; if (r > nrows-1) r = nrows-1;
        #pragma unroll
        for (int c = 0; c < 4; ++c) {
          t1f[i][c] = *(const short8*)(srcT1 + (size_t)r*128 + c*32 + q*8);
          t2f[i][c] = *(const short8*)(srcT2 + (size_t)r*128 + c*32 + q*8);
        }
      }

      load_64x128_swz(pCg + (size_t)it0*64*128, 128, ldsCg[0], tid);
      load_64x128_swz(pCu + (size_t)it0*64*128, 128, ldsCu[0], tid);

      f32x4 rdacc[2][4];
      #pragma unroll
      for (int i = 0; i < 2; ++i)
        #pragma unroll
        for (int j = 0; j < 4; ++j) rdacc[i][j] = (f32x4){0.f,0.f,0.f,0.f};

      const size_t rdRow = (size_t)(nh*64 + ln)*Ifull + q*8;  // + j*16*Ifull + i0 + c2*32

      __syncthreads();   // tile 0 staged

      for (int it = 0; it < MTILES; ++it) {
        const int i0 = (it0 + it) * 64;
        const int cb = it & 1;
        // 1. preload Rd B-frags for phaseB(it-1) FIRST (vmcnt in-order: waiting
        //    for these must not force the gll prefetch issued after them)
        short8 rb[2][4];
        if (it > 0) {
          const int ip = i0 - 64;
          #pragma unroll
          for (int c2 = 0; c2 < 2; ++c2)
            #pragma unroll
            for (int j = 0; j < 4; ++j)
              rb[c2][j] = *(const short8*)(pRd + rdRow + (size_t)(j*16)*Ifull + ip + c2*32);
        }
        // 2. prefetch Cg/Cu(it+1) into the idle buffers (drains at THIS barrier)
        if (it+1 < MTILES) {
          load_64x128_swz(pCg + (size_t)(i0+64)*128, 128, ldsCg[cb^1], tid);
          load_64x128_swz(pCu + (size_t)(i0+64)*128, 128, ldsCu[cb^1], tid);
        }
        // 3. phaseA(it): g,u from regs x ldsCg/Cu[cb]; silu; h -> ldsH[cb]
        f32x4 g[2][2], u[2][2];
        #pragma unroll
        for (int i = 0; i < 2; ++i)
          #pragma unroll
          for (int j = 0; j < 2; ++j) { g[i][j] = (f32x4){0.f,0.f,0.f,0.f}; u[i][j] = (f32x4){0.f,0.f,0.f,0.f}; }
        #pragma unroll
        for (int c = 0; c < 4; ++c) {
          #pragma unroll
          for (int j = 0; j < 2; ++j) {
            int rr = nh*32 + j*16 + ln;
            int off = rr*128 + (((c*4+q) ^ (rr&15)) << 3);
            short8 bg = *(const short8*)(ldsCg[cb] + off);
            short8 bu = *(const short8*)(ldsCu[cb] + off);
            #pragma unroll
            for (int i = 0; i < 2; ++i) {
              g[i][j] = MF(t1f[i][c], bg, g[i][j]);
              u[i][j] = MF(t2f[i][c], bu, u[i][j]);
            }
          }
        }
        #pragma unroll
        for (int i = 0; i < 2; ++i)
          #pragma unroll
          for (int j = 0; j < 2; ++j) {
            float hv[4];
            #pragma unroll
            for (int r = 0; r < 4; ++r) {
              float gv = g[i][j][r];
              hv[r] = gv * fast_rcp(1.f + __expf(-gv)) * u[i][j][r];
            }
            unsigned p01 = cvt_pk_bf16(hv[0], hv[1]);
            unsigned p23 = cvt_pk_bf16(hv[2], hv[3]);
            const int hc = nh*32 + j*16 + ln;
            const int hb = mh*32 + i*16 + q*4;
            #pragma unroll
            for (int r = 0; r < 4; ++r) {
              int hr = hb + r;
              ushort_t v = (r==0) ? (ushort_t)p01 : (r==1) ? (ushort_t)(p01>>16)
                         : (r==2) ? (ushort_t)p23 : (ushort_t)(p23>>16);
              ldsH[cb][hr*64 + (((hc>>3) ^ (hr&7)) << 3) + (hc&7)] = v;
            }
          }
        // 4. phaseB(it-1): rd += h[cb^1] @ Rd (h written last iter, barrier'd)
        if (it > 0) {
          #pragma unroll
          for (int c2 = 0; c2 < 2; ++c2) {
            short8 a[2];
            #pragma unroll
            for (int i = 0; i < 2; ++i) {
              int rr = mh*32 + i*16 + ln;
              a[i] = *(const short8*)(ldsH[cb^1] + rr*64 + (((c2*4+q) ^ (rr&7)) << 3));
            }
            #pragma unroll
            for (int j = 0; j < 4; ++j)
              #pragma unroll
              for (int i = 0; i < 2; ++i) rdacc[i][j] = MF(a[i], rb[c2][j], rdacc[i][j]);
          }
        }
        __syncthreads();   // ONE barrier/iter: h[cb] visible next iter; gll(it+1) landed
      }
      // epilogue: phaseB(MTILES-1)
      {
        const int ip = (it0 + MTILES - 1) * 64;
        const int cb = (MTILES - 1) & 1;
        #pragma unroll
        for (int c2 = 0; c2 < 2; ++c2) {
          short8 a[2];
          #pragma unroll
          for (int i = 0; i < 2; ++i) {
            int rr = mh*32 + i*16 + ln;
            a[i] = *(const short8*)(ldsH[cb] + rr*64 + (((c2*4+q) ^ (rr&7)) << 3));
          }
          #pragma unroll
          for (int j = 0; j < 4; ++j) {
            short8 b = *(const short8*)(pRd + rdRow + (size_t)(j*16)*Ifull + ip + c2*32);
            #pragma unroll
            for (int i = 0; i < 2; ++i) rdacc[i][j] = MF(a[i], b, rdacc[i][j]);
          }
        }
      }

      // plain disjoint stores (no atomics): part bz of 2 (routed) or 4 (shared)
      float* dst = shm ? (rdSp + (size_t)bz*T_TOK*128)
                       : (rdRp + (size_t)bz*NPAIR*128 + (size_t)base*128);
      #pragma unroll
      for (int i = 0; i < 2; ++i) {
        #pragma unroll
        for (int r = 0; r < 4; ++r) {
          int gs = s0 + mh*32 + i*16 + q*4 + r;
          if (gs < nrows) {
            #pragma unroll
            for (int j = 0; j < 4; ++j)
              dst[(size_t)gs*128 + nh*64 + j*16 + ln] = rdacc[i][j][r];
          }
        }
      }
    }
  }
}

// ---------------------------------------------------------------- out
// grid (64, 33, 2). t3 frags in regs; Cd double-buffered via gll; 1 barrier/tile.
// LDS diet (v7, kept): ldsT ALIASES ldsA -> smem 34.8 KB -> 4 blocks/CU.
// Balanced expert-clustered XCD map. NO atomics: routed y -> ybufR (bf16,
// per-slot, unweighted); shared y -> out directly (fp32 plain stores).
__global__ __launch_bounds__(256) void out_kernel(
    const float* __restrict__ rdRp, const float* __restrict__ rdSp,
    const ushort_t* __restrict__ Ud, const ushort_t* __restrict__ Cd,
    const ushort_t* __restrict__ sUd, const ushort_t* __restrict__ sCd,
    const int* __restrict__ offA, const int* __restrict__ cntA,
    ushort_t* __restrict__ ybufR, float* __restrict__ out)
{
  __shared__ ushort_t smem[2*64*SRK];   // prologue: ldsA(=ldsT) | stage ; loop: cd0,cd1
  ushort_t* ldsA  = smem;
  ushort_t* stage = smem + 64*SRK;
  ushort_t* ldsT  = smem;               // aliases ldsA (safe: see header comment)
  ushort_t* cd0   = smem;
  ushort_t* cd1   = smem + 64*128;

  // balanced XCD map (4224 blocks, 528 per XCD):
  //   routed m<512: by=(m>>7)*8+x, bzz=(m>>6)&1, bx=m&63
  //   shared m>=512: by=32, bzz=(m-512)>>3, bx=((m-512)&7)*8+x
  const int hh = blockIdx.x + 64*(blockIdx.y + 33*blockIdx.z);
  const int xc = hh & 7, m = hh >> 3;
  int bx, by, bzz;
  if (m < 512) { by = (m >> 7)*8 + xc; bzz = (m >> 6) & 1; bx = m & 63; }
  else         { int mm = m - 512; by = NEXP; bzz = mm >> 3; bx = ((mm & 7) << 3) + xc; }

  const int tid = threadIdx.x;
  const bool shm = (by == NEXP);
  const int nrows = shm ? T_TOK : cntA[by];
  const int s0 = bx * 64;
  if (s0 >= nrows) return;
  const int base = shm ? 0 : offA[by];
  const int ct0 = bzz * 16;
  const ushort_t* pUd = shm ? sUd : Ud + (size_t)by*128*128;
  const ushort_t* pCd = shm ? sCd : Cd + (size_t)by*HD*128;

  const int lane = tid & 63, ln = lane & 15, q = lane >> 4;
  const int wv = tid >> 6, mh = wv >> 1, nh = wv & 1;

  // gather rd rows: sum the per-bz partials (fp32) -> bf16 ldsA
  for (int li = tid; li < 64*32; li += 256) {
    int r = li >> 5, c4 = li & 31;
    int row = s0 + r; if (row > nrows-1) row = nrows-1;
    float4 v;
    if (shm) {
      const float* p = rdSp + (size_t)row*128 + c4*4;
      v = *(const float4*)p;
      #pragma unroll
      for (int pp = 1; pp < 4; ++pp) {
        float4 w2 = *(const float4*)(p + (size_t)pp*T_TOK*128);
        v.x += w2.x; v.y += w2.y; v.z += w2.z; v.w += w2.w;
      }
    } else {
      const float* p = rdRp + (size_t)(base+row)*128 + c4*4;
      v = *(const float4*)p;
      float4 w2 = *(const float4*)(p + (size_t)NPAIR*128);
      v.x += w2.x; v.y += w2.y; v.z += w2.z; v.w += w2.w;
    }
    ushort4 o; o.x=f2b(v.x); o.y=f2b(v.y); o.z=f2b(v.z); o.w=f2b(v.w);
    *(ushort4*)(ldsA + r*SRK + c4*4) = o;
  }
  __syncthreads();

  f32x4 acc[2][2][2];
  gemm64x128_regs(tid, ldsA, pUd, stage, acc);
  // C -> ldsT (= ldsA; all A-reads done at gemm's last barrier), then extract A-frags
  #pragma unroll
  for (int h = 0; h < 2; ++h)
    #pragma unroll
    for (int i = 0; i < 2; ++i)
      #pragma unroll
      for (int j = 0; j < 2; ++j)
        #pragma unroll
        for (int r = 0; r < 4; ++r)
          ldsT[(mh*32 + i*16 + q*4 + r)*SRK + h*64 + nh*32 + j*16 + ln] = f2b(acc[h][i][j][r]);
  __syncthreads();
  short8 t3f[2][4];
  #pragma unroll
  for (int i = 0; i < 2; ++i)
    #pragma unroll
    for (int c = 0; c < 4; ++c)
      t3f[i][c] = *(const short8*)(ldsT + (mh*32 + i*16 + ln)*SRK + c*32 + q*8);
  __syncthreads();   // smem free for cd buffers

  load_64x128_swz(pCd + (size_t)ct0*64*128, 128, cd0, tid);
  for (int tt = 0; tt < 16; ++tt) {
    __syncthreads();                      // cd[tt&1] ready; prior reads drained
    ushort_t* cur = (tt & 1) ? cd1 : cd0;
    ushort_t* nxt = (tt & 1) ? cd0 : cd1;
    if (tt+1 < 16)
      load_64x128_swz(pCd + (size_t)(ct0+tt+1)*64*128, 128, nxt, tid);
    f32x4 y[2][2];
    #pragma unroll
    for (int i = 0; i < 2; ++i)
      #pragma unroll
      for (int j = 0; j < 2; ++j) y[i][j] = (f32x4){0.f,0.f,0.f,0.f};
    #pragma unroll
    for (int c = 0; c < 4; ++c) {
      #pragma unroll
      for (int j = 0; j < 2; ++j) {
        int rr = nh*32 + j*16 + ln;
        short8 b = *(const short8*)(cur + rr*128 + (((c*4+q) ^ (rr&15)) << 3));
        #pragma unroll
        for (int i = 0; i < 2; ++i) y[i][j] = MF(t3f[i][c], b, y[i][j]);
      }
    }
    #pragma unroll
    for (int i = 0; i < 2; ++i) {
      #pragma unroll
      for (int r = 0; r < 4; ++r) {
        int lr = mh*32 + i*16 + q*4 + r;
        int gs = s0 + lr;
        if (gs < nrows) {
          if (shm) {
            size_t ob = (size_t)gs*HD + (ct0 + tt)*64;
            #pragma unroll
            for (int j = 0; j < 2; ++j)
              out[ob + nh*32 + j*16 + ln] = y[i][j][r];
          } else {
            size_t ob = (size_t)(base + gs)*HD + (ct0 + tt)*64;
            #pragma unroll
            for (int j = 0; j < 2; ++j)
              ybufR[ob + nh*32 + j*16 + ln] = f2b(y[i][j][r]);
          }
        }
      }
    }
  }
}

// ---------------------------------------------------------------- combine
// out[t] = out[t] (shared, already stored) + sum_k w_k * ybufR[slot_of[t,k]]
// One block per token row; fully coalesced, no atomics.
__global__ __launch_bounds__(256) void combine_kernel(
    const ushort_t* __restrict__ ybufR,
    const int* __restrict__ slot_of, const float* __restrict__ topk_w,
    float* __restrict__ out)
{
  __shared__ int   ss[4];
  __shared__ float ww[4];
  const int t = blockIdx.x;
  if (threadIdx.x < 4) {
    ss[threadIdx.x] = slot_of[t*4 + threadIdx.x];
    ww[threadIdx.x] = topk_w[t*4 + threadIdx.x];
  }
  __syncthreads();
  const int c = threadIdx.x * 8;
  const size_t tb = (size_t)t*HD + c;
  float o[8];
  float4 a0 = *(const float4*)(out + tb);
  float4 a1 = *(const float4*)(out + tb + 4);
  o[0]=a0.x; o[1]=a0.y; o[2]=a0.z; o[3]=a0.w;
  o[4]=a1.x; o[5]=a1.y; o[6]=a1.z; o[7]=a1.w;
  #pragma unroll
  for (int k = 0; k < 4; ++k) {
    short8 rv = *(const short8*)(ybufR + (size_t)ss[k]*HD + c);
    float wk = ww[k];
    #pragma unroll
    for (int u = 0; u < 8; ++u)
      o[u] += wk * b2f((ushort_t)rv[u]);
  }
  float4 b0 = {o[0],o[1],o[2],o[3]};
  float4 b1 = {o[4],o[5],o[6],o[7]};
  *(float4*)(out + tb)     = b0;
  *(float4*)(out + tb + 4) = b1;
}

// ---------------------------------------------------------------- launch
extern "C" void kernel_launch(void* const* d_in, const int* in_sizes, int n_in,
                              void* d_out, int out_size, void* d_ws, size_t ws_size,
                              hipStream_t stream) {
  const float* x    = (const float*)d_in[0];
  const float* gw   = (const float*)d_in[1];
  const float* Rg   = (const float*)d_in[2];
  const float* Ru   = (const float*)d_in[3];
  const float* Rd   = (const float*)d_in[4];
  const float* Ug   = (const float*)d_in[5];
  const float* Cg   = (const float*)d_in[6];
  const float* Uu   = (const float*)d_in[7];
  const float* Cu   = (const float*)d_in[8];
  const float* Ud   = (const float*)d_in[9];
  const float* Cd   = (const float*)d_in[10];
  const float* sRg  = (const float*)d_in[11];
  const float* sUg  = (const float*)d_in[12];
  const float* sCg  = (const float*)d_in[13];
  const float* sRu  = (const float*)d_in[14];
  const float* sUu  = (const float*)d_in[15];
  const float* sCu  = (const float*)d_in[16];
  const float* sRd  = (const float*)d_in[17];
  const float* sUd  = (const float*)d_in[18];
  const float* sCd  = (const float*)d_in[19];
  float* out = (float*)d_out;

  char* w = (char*)d_ws;
  auto alloc = [&](size_t bytes) -> void* {
    void* p = (void*)w; w += (bytes + 255) & ~(size_t)255; return p;
  };
  int*   cnt      = (int*)  alloc(NEXP*sizeof(int));
  int*   offA     = (int*)  alloc((NEXP+1)*sizeof(int));
  int*   fill     = (int*)  alloc(NEXP*sizeof(int));
  int*   topk_idx = (int*)  alloc((size_t)T_TOK*4*sizeof(int));
  float* topk_w   = (float*)alloc((size_t)T_TOK*4*sizeof(float));
  int*   list_tok = (int*)  alloc((size_t)NPAIR*sizeof(int));
  int*   slot_of  = (int*)  alloc((size_t)T_TOK*4*sizeof(int));
  int*   wn       = (int*)  alloc(8*sizeof(int));
  int*   wcnt     = (int*)  alloc(8*sizeof(int));
  int*   wl       = (int*)  alloc((size_t)8*WLCAP*sizeof(int));
  int*   bcast    = (int*)  alloc(512*sizeof(int));
  ushort_t* xb   = (ushort_t*)alloc((size_t)T_TOK*HD*2);   // later reused as rdRp (fp32, 2 parts)
  ushort_t* Rgb  = (ushort_t*)alloc((size_t)128*HD*2);
  ushort_t* Rub  = (ushort_t*)alloc((size_t)128*HD*2);
  ushort_t* Rdb  = (ushort_t*)alloc((size_t)128*IR*2);
  ushort_t* Ugb  = (ushort_t*)alloc((size_t)NEXP*128*128*2);
  ushort_t* Cgb  = (ushort_t*)alloc((size_t)NEXP*IR*128*2);
  ushort_t* Uub  = (ushort_t*)alloc((size_t)NEXP*128*128*2);
  ushort_t* Cub  = (ushort_t*)alloc((size_t)NEXP*IR*128*2);
  ushort_t* Udb  = (ushort_t*)alloc((size_t)NEXP*128*128*2);
  ushort_t* Cdb  = (ushort_t*)alloc((size_t)NEXP*HD*128*2);
  ushort_t* sRgb = (ushort_t*)alloc((size_t)128*HD*2);
  ushort_t* sUgb = (ushort_t*)alloc((size_t)128*128*2);
  ushort_t* sCgb = (ushort_t*)alloc((size_t)ISH*128*2);
  ushort_t* sRub = (ushort_t*)alloc((size_t)128*HD*2);
  ushort_t* sUub = (ushort_t*)alloc((size_t)128*128*2);
  ushort_t* sCub = (ushort_t*)alloc((size_t)ISH*128*2);
  ushort_t* sRdb = (ushort_t*)alloc((size_t)128*ISH*2);
  ushort_t* sUdb = (ushort_t*)alloc((size_t)128*128*2);
  ushort_t* sCdb = (ushort_t*)alloc((size_t)HD*128*2);
  ushort_t* rg   = (ushort_t*)alloc((size_t)T_TOK*128*2);
  ushort_t* ru   = (ushort_t*)alloc((size_t)T_TOK*128*2);
  ushort_t* sa   = (ushort_t*)alloc((size_t)T_TOK*128*2);
  ushort_t* su   = (ushort_t*)alloc((size_t)T_TOK*128*2);
  ushort_t* t1R  = (ushort_t*)alloc((size_t)NPAIR*128*2);
  ushort_t* t2R  = (ushort_t*)alloc((size_t)NPAIR*128*2);
  ushort_t* t1S  = (ushort_t*)alloc((size_t)T_TOK*128*2);
  ushort_t* t2S  = (ushort_t*)alloc((size_t)T_TOK*128*2);
  float*    rdSp = (float*)   alloc((size_t)4*T_TOK*128*sizeof(float));  // 4 shared partials
  ushort_t* ybufR= (ushort_t*)alloc((size_t)NPAIR*HD*2);                 // per-slot routed y (bf16)
  (void)ws_size; (void)in_sizes; (void)n_in;

  // routed rd partials (fp32, 2 parts) alias xb exactly:
  // 2*NPAIR*128*4 = 16.78 MB == T_TOK*HD*2. xb is dead after rproj; mid writes it after.
  float* rdRp = (float*)xb;

  hipMemsetAsync(cnt,  0, NEXP*sizeof(int), stream);
  hipMemsetAsync(fill, 0, NEXP*sizeof(int), stream);
  hipMemsetAsync(wcnt, 0, 8*sizeof(int), stream);
  // no out memset: out_kernel's shared path fully writes out; combine RMWs it.

  // fused cvt
  CvtSegs cs;
  const float* ss[NSEG] = {x,Rg,Ru,Rd,Ug,Cg,Uu,Cu,Ud,Cd,sRg,sUg,sCg,sRu,sUu,sCu,sRd,sUd,sCd};
  ushort_t* dd[NSEG] = {xb,Rgb,Rub,Rdb,Ugb,Cgb,Uub,Cub,Udb,Cdb,sRgb,sUgb,sCgb,sRub,sUub,sCub,sRdb,sUdb,sCdb};
  size_t nn[NSEG] = {(size_t)T_TOK*HD,(size_t)128*HD,(size_t)128*HD,(size_t)128*IR,
                     (size_t)NEXP*128*128,(size_t)NEXP*IR*128,(size_t)NEXP*128*128,(size_t)NEXP*IR*128,
                     (size_t)NEXP*128*128,(size_t)NEXP*HD*128,(size_t)128*HD,(size_t)128*128,
                     (size_t)ISH*128,(size_t)128*HD,(size_t)128*128,(size_t)ISH*128,
                     (size_t)128*ISH,(size_t)128*128,(size_t)HD*128};
  int tot_blk = 0;
  for (int k = 0; k < NSEG; ++k) {
    cs.s[k] = ss[k]; cs.d[k] = dd[k];
    cs.n4[k] = (int)(nn[k] >> 2);
    cs.blk0[k] = tot_blk;
    tot_blk += (cs.n4[k] + 255) / 256;
  }
  cs.blk0[NSEG] = tot_blk;
  cvt_all_kernel<<<tot_blk, 256, 0, stream>>>(cs);

  gate_kernel<<<T_TOK/4, 256, 0, stream>>>(x, gw, topk_idx, topk_w, cnt);
  scan_kernel<<<1, 64, 0, stream>>>(cnt, offA);
  plan_kernel<<<1, 256, 0, stream>>>(cnt, wn, wl);
  scatter_kernel<<<T_TOK/256, 256, 0, stream>>>(topk_idx, topk_w, offA, fill, list_tok, slot_of);
  rproj_kernel<<<dim3(T_TOK/64, 4), 256, 0, stream>>>(xb, Rgb, Rub, sRgb, sRub, rg, ru, sa, su);
  pair_proj_kernel<<<dim3(64, NEXP+1), 256, 0, stream>>>(
      rg, ru, sa, su, Ugb, Uub, sUgb, sUub, offA, cnt, list_tok, t1R, t2R, t1S, t2S);
  mid_kernel<<<512, 256, 0, stream>>>(
      t1R, t2R, t1S, t2S, Cgb, Cub, Rdb, sCgb, sCub, sRdb, offA, cnt, rdRp, rdSp,
      wn, wcnt, wl, bcast);
  out_kernel<<<dim3(64, 33, 2), 256, 0, stream>>>(
      rdRp, rdSp, Udb, Cdb, sUdb, sCdb, offA, cnt, ybufR, out);
  combine_kernel<<<T_TOK, 256, 0, stream>>>(ybufR, slot_of, topk_w, out);
}

// Round 14
// 542.609 us; speedup vs baseline: 1.4777x; 1.0617x over previous
//
#include <hip/hip_runtime.h>
#include <math.h>

#define T_TOK 4096
#define HD    2048
#define NEXP  32
#define IR    1408
#define ISH   2816
#define NPAIR (T_TOK*4)
#define SRK   136      // padded bf16 row stride (cold paths only)
#define MTILES 11      // I-tiles (of 64) per chunk: routed 2 chunks, shared 4
#define WLCAP 2048     // per-XCD work-list capacity

typedef unsigned short ushort_t;
typedef __attribute__((ext_vector_type(8))) short    short8;
typedef __attribute__((ext_vector_type(8))) __bf16   bf16x8;
typedef __attribute__((ext_vector_type(4))) float    f32x4;

__device__ __forceinline__ f32x4 MF(short8 a, short8 b, f32x4 c) {
  return __builtin_amdgcn_mfma_f32_16x16x32_bf16(
      __builtin_bit_cast(bf16x8, a), __builtin_bit_cast(bf16x8, b), c, 0, 0, 0);
}
__device__ __forceinline__ ushort_t f2b(float f) {
  unsigned u = __float_as_uint(f);
  unsigned r = (u + 0x7fffu + ((u >> 16) & 1u)) >> 16;   // RNE
  return (ushort_t)r;
}
__device__ __forceinline__ float b2f(ushort_t b) {
  return __uint_as_float(((unsigned)b) << 16);
}
__device__ __forceinline__ float fast_rcp(float x) {     // v_rcp_f32: 1 inst, ~1ulp
  float r; asm("v_rcp_f32 %0, %1" : "=v"(r) : "v"(x)); return r;
}
__device__ __forceinline__ unsigned cvt_pk_bf16(float lo, float hi) {  // RNE pack
  unsigned r; asm("v_cvt_pk_bf16_f32 %0, %1, %2" : "=v"(r) : "v"(lo), "v"(hi)); return r;
}

// async global->LDS 16B; LDS dst must be wave-uniform base (+lane*16 implicit)
__device__ __forceinline__ void gll16(const ushort_t* g, ushort_t* l) {
  __builtin_amdgcn_global_load_lds(
      (const __attribute__((address_space(1))) unsigned int*)(const void*)g,
      (__attribute__((address_space(3))) unsigned int*)(void*)l, 16, 0, 0);
}

// ---- swizzled tile loader (XOR swizzle: phys chunk = logical ^ (row&mask)) ----
// 64 rows x 128 cols bf16 (16 chunks/row). One instr = 4 rows.
__device__ __forceinline__ void load_64x128_swz(
    const ushort_t* __restrict__ g, size_t gstride, ushort_t* lds, int tid)
{
  const int lane = tid & 63, w = tid >> 6;
  #pragma unroll
  for (int s = 0; s < 4; ++s) {
    int rbase = s*16 + w*4;
    int r = rbase + (lane >> 4);
    int p = lane & 15;
    gll16(g + (size_t)r*gstride + ((p ^ (r & 15)) << 3), lds + rbase*128);
  }
}
// read elem(row r, chunk c of 8hw): lds[r*128 + ((c^(r&15))<<3)]

// ---------------------------------------------------------------- fused cvt
#define NSEG 19
struct CvtSegs {
  const float* s[NSEG];
  ushort_t* d[NSEG];
  int n4[NSEG];
  int blk0[NSEG+1];
};
__global__ __launch_bounds__(256) void cvt_all_kernel(CvtSegs cs)
{
  int b = blockIdx.x;
  int k = 0;
  #pragma unroll 1
  while (k+1 < NSEG && b >= cs.blk0[k+1]) ++k;
  int i = (b - cs.blk0[k])*256 + threadIdx.x;
  if (i < cs.n4[k]) {
    float4 v = ((const float4*)cs.s[k])[i];
    ushort4 o; o.x=f2b(v.x); o.y=f2b(v.y); o.z=f2b(v.z); o.w=f2b(v.w);
    ((ushort4*)cs.d[k])[i] = o;
  }
}

// ---------------------------------------------------------------- gate
// 4 tokens/block (4 waves); gw staged through LDS per 128-k chunk.
__global__ __launch_bounds__(256) void gate_kernel(
    const float* __restrict__ x, const float* __restrict__ gw,
    int* __restrict__ topk_idx, float* __restrict__ topk_w, int* __restrict__ cnt)
{
  __shared__ float gws[32*132];
  __shared__ float xs[4*132];
  const int tid = threadIdx.x;
  const int w = tid >> 6, lane = tid & 63;
  const int t0 = blockIdx.x * 4;
  const int e = lane & 31, half = lane >> 5;

  float acc = 0.f;
  for (int ck = 0; ck < HD/128; ++ck) {
    for (int li = tid; li < 1024; li += 256) {        // gw chunk 32x128
      int r = li >> 5, c4 = li & 31;
      *(float4*)(gws + r*132 + c4*4) = *(const float4*)(gw + (size_t)r*HD + ck*128 + c4*4);
    }
    for (int li = tid; li < 128; li += 256) {          // x chunk 4x128
      int r = li >> 5, c4 = li & 31;
      *(float4*)(xs + r*132 + c4*4) = *(const float4*)(x + (size_t)(t0+r)*HD + ck*128 + c4*4);
    }
    __syncthreads();
    #pragma unroll
    for (int k4 = 0; k4 < 16; ++k4) {
      float4 xv = *(const float4*)(xs + w*132 + half*64 + k4*4);
      float4 wv = *(const float4*)(gws + e*132 + half*64 + k4*4);
      acc += xv.x*wv.x + xv.y*wv.y + xv.z*wv.z + xv.w*wv.w;
    }
    __syncthreads();
  }
  float p = acc;
  p += __shfl_down(p, 32);
  float logit = (lane < 32) ? p : -INFINITY;
  float m = logit;
  #pragma unroll
  for (int o = 32; o >= 1; o >>= 1) m = fmaxf(m, __shfl_xor(m, o));
  float ex = (lane < 32) ? expf(logit - m) : 0.f;
  float se = ex;
  #pragma unroll
  for (int o = 32; o >= 1; o >>= 1) se += __shfl_xor(se, o);
  float score = ex / se;

  bool taken = false;
  float selw[4]; int seli[4];
  for (int k = 0; k < 4; ++k) {
    float cur = (lane < 32 && !taken) ? score : -1.f;
    float mm = cur;
    #pragma unroll
    for (int o = 32; o >= 1; o >>= 1) mm = fmaxf(mm, __shfl_xor(mm, o));
    unsigned long long b = __ballot(cur == mm);
    int il = __ffsll(b) - 1;
    if (lane == il) taken = true;
    selw[k] = mm; seli[k] = il;
  }
  float wsum = selw[0]+selw[1]+selw[2]+selw[3] + 1e-20f;
  int t = t0 + w;
  if (lane < 4) {
    topk_idx[t*4+lane] = seli[lane];
    topk_w[t*4+lane]  = selw[lane] / wsum;
    atomicAdd(&cnt[seli[lane]], 1);
  }
}

__global__ void scan_kernel(const int* __restrict__ cnt, int* __restrict__ offA)
{
  if (threadIdx.x == 0) {
    int a = 0;
    for (int e = 0; e < NEXP; ++e) { offA[e] = a; a += cnt[e]; }
    offA[NEXP] = a;
  }
}

// ---------------------------------------------------------------- plan
// Build per-XCD work lists for the static-stride mid kernel (768 items).
// XCD x gets: 32 shared items (4 I-chunks x 8 bx) + routed items of experts e%8==x.
// item encoding: (by<<16) | (bz<<12) | bx
__global__ __launch_bounds__(256) void plan_kernel(
    const int* __restrict__ cnt, int* __restrict__ wn, int* __restrict__ wl)
{
  const int t = threadIdx.x;
  if (t < 8) wn[t] = 32;
  __syncthreads();
  {
    int x = t >> 5, i = t & 31;                 // 256 threads -> 8 XCDs x 32 shared items
    int bz = i >> 3, bx = ((i & 7) << 3) + x;   // bz in [0,4), bx covers 0..63 once
    wl[x*WLCAP + i] = (NEXP << 16) | (bz << 12) | bx;
  }
  __syncthreads();
  if (t < NEXP) {
    int nb = (cnt[t] + 63) >> 6;
    int x = t & 7;
    int pos = atomicAdd(&wn[x], nb*2);
    for (int bz = 0; bz < 2; ++bz)
      for (int bx = 0; bx < nb; ++bx)
        wl[x*WLCAP + pos++] = (t << 16) | (bz << 12) | bx;
  }
}

__global__ __launch_bounds__(256) void scatter_kernel(
    const int* __restrict__ topk_idx, const float* __restrict__ topk_w,
    const int* __restrict__ offA, int* __restrict__ fill,
    int* __restrict__ list_tok, int* __restrict__ slot_of)
{
  int t = blockIdx.x*256 + threadIdx.x;
  if (t >= T_TOK) return;
  #pragma unroll
  for (int k = 0; k < 4; ++k) {
    int e = topk_idx[t*4+k];
    int pos = atomicAdd(&fill[e], 1);
    int s = offA[e] + pos;
    list_tok[s] = t;
    slot_of[t*4+k] = s;     // inverse map for non-atomic combine
  }
}

// ------------------------------------------------- R projections (pipelined)
// Y[T,128] = Xb[T,2048] @ W[128,2048]^T. A via gll dbuf; B-frags from global (L2-hot).
__global__ __launch_bounds__(256) void rproj_kernel(
    const ushort_t* __restrict__ xb,
    const ushort_t* __restrict__ Rg, const ushort_t* __restrict__ Ru,
    const ushort_t* __restrict__ sRg, const ushort_t* __restrict__ sRu,
    ushort_t* __restrict__ rg, ushort_t* __restrict__ ru,
    ushort_t* __restrict__ sa, ushort_t* __restrict__ su)
{
  __shared__ ushort_t abuf[2][64*128];
  const ushort_t* W; ushort_t* Y;
  switch (blockIdx.y) {
    case 0:  W = Rg;  Y = rg; break;
    case 1:  W = Ru;  Y = ru; break;
    case 2:  W = sRg; Y = sa; break;
    default: W = sRu; Y = su; break;
  }
  const int tid = threadIdx.x;
  const int lane = tid & 63, ln = lane & 15, q = lane >> 4;
  const int wv = tid >> 6, mh = wv >> 1, nh = wv & 1;
  const int r0 = blockIdx.x * 64;

  f32x4 acc[2][4];
  #pragma unroll
  for (int i = 0; i < 2; ++i)
    #pragma unroll
    for (int j = 0; j < 4; ++j) acc[i][j] = (f32x4){0.f,0.f,0.f,0.f};

  load_64x128_swz(xb + (size_t)r0*HD, HD, abuf[0], tid);
  for (int kt = 0; kt < 16; ++kt) {
    __syncthreads();                       // abuf[kt&1] ready
    if (kt+1 < 16)
      load_64x128_swz(xb + (size_t)r0*HD + (kt+1)*128, HD, abuf[(kt+1)&1], tid);
    const ushort_t* A = abuf[kt&1];
    #pragma unroll
    for (int c = 0; c < 4; ++c) {
      short8 a[2], b[4];
      #pragma unroll
      for (int i = 0; i < 2; ++i) {
        int rr = mh*32 + i*16 + ln;
        a[i] = *(const short8*)(A + rr*128 + (((c*4+q) ^ (rr&15)) << 3));
      }
      #pragma unroll
      for (int j = 0; j < 4; ++j)
        b[j] = *(const short8*)(W + (size_t)(nh*64 + j*16 + ln)*HD + kt*128 + c*32 + q*8);
      #pragma unroll
      for (int i = 0; i < 2; ++i)
        #pragma unroll
        for (int j = 0; j < 4; ++j) acc[i][j] = MF(a[i], b[j], acc[i][j]);
    }
  }
  #pragma unroll
  for (int i = 0; i < 2; ++i)
    #pragma unroll
    for (int j = 0; j < 4; ++j)
      #pragma unroll
      for (int r = 0; r < 4; ++r)
        Y[(size_t)(r0 + mh*32 + i*16 + q*4 + r)*128 + nh*64 + j*16 + ln] = f2b(acc[i][j][r]);
}

// -------- helper (cold path): acc = A_lds[64][SRK] @ Wg[128][128]^T, C in regs
__device__ __forceinline__ void gemm64x128_regs(
    int tid, const ushort_t* __restrict__ A, const ushort_t* __restrict__ Wg,
    ushort_t* __restrict__ stage, f32x4 acc[2][2][2])
{
  const int lane = tid & 63, ln = lane & 15, q = lane >> 4;
  const int wv = tid >> 6, mh = wv >> 1, nh = wv & 1;
  #pragma unroll
  for (int h = 0; h < 2; ++h)
    #pragma unroll
    for (int i = 0; i < 2; ++i)
      #pragma unroll
      for (int j = 0; j < 2; ++j) acc[h][i][j] = (f32x4){0.f,0.f,0.f,0.f};
  for (int h = 0; h < 2; ++h) {
    for (int li = tid; li < 64*16; li += 256) {
      int r = li >> 4, c = (li & 15) << 3;
      *(short8*)(stage + r*SRK + c) = *(const short8*)(Wg + (size_t)(h*64 + r)*128 + c);
    }
    __syncthreads();
    #pragma unroll
    for (int c = 0; c < 4; ++c) {
      short8 a[2], b[2];
      #pragma unroll
      for (int i = 0; i < 2; ++i)
        a[i] = *(const short8*)(A + (mh*32 + i*16 + ln)*SRK + c*32 + q*8);
      #pragma unroll
      for (int j = 0; j < 2; ++j)
        b[j] = *(const short8*)(stage + (nh*32 + j*16 + ln)*SRK + c*32 + q*8);
      #pragma unroll
      for (int i = 0; i < 2; ++i)
        #pragma unroll
        for (int j = 0; j < 2; ++j) acc[h][i][j] = MF(a[i], b[j], acc[h][i][j]);
    }
    __syncthreads();
  }
}

// ---------------------------------------------------------------- pair_proj
// t1[slot] = rg[tok(slot)] @ Ug_e^T ; t2 = ru @ Uu_e^T ; shared rows direct.
__global__ __launch_bounds__(256) void pair_proj_kernel(
    const ushort_t* __restrict__ rgb, const ushort_t* __restrict__ rub,
    const ushort_t* __restrict__ sab, const ushort_t* __restrict__ sub,
    const ushort_t* __restrict__ Ug, const ushort_t* __restrict__ Uu,
    const ushort_t* __restrict__ sUg, const ushort_t* __restrict__ sUu,
    const int* __restrict__ offA, const int* __restrict__ cntA,
    const int* __restrict__ list_tok,
    ushort_t* __restrict__ t1R, ushort_t* __restrict__ t2R,
    ushort_t* __restrict__ t1S, ushort_t* __restrict__ t2S)
{
  __shared__ ushort_t ldsX[64*SRK];
  __shared__ ushort_t stage[64*SRK];
  __shared__ int toks[64];
  const int tid = threadIdx.x;
  const int by = blockIdx.y;
  const bool shm = (by == NEXP);
  const int nrows = shm ? T_TOK : cntA[by];
  const int s0 = blockIdx.x * 64;
  if (s0 >= nrows) return;
  const int base = shm ? 0 : offA[by];
  const ushort_t* pUg = shm ? sUg : Ug + (size_t)by*128*128;
  const ushort_t* pUu = shm ? sUu : Uu + (size_t)by*128*128;
  const int lane = tid & 63, ln = lane & 15, q = lane >> 4;
  const int wv = tid >> 6, mh = wv >> 1, nh = wv & 1;

  if (tid < 64) {
    int sc = s0 + tid; if (sc > nrows-1) sc = nrows-1;
    toks[tid] = shm ? sc : list_tok[base + sc];
  }
  __syncthreads();

  f32x4 acc[2][2][2];
  // t1
  for (int li = tid; li < 64*16; li += 256) {
    int r = li >> 4, c = (li & 15) << 3;
    const ushort_t* src = shm ? sab : rgb;
    *(short8*)(ldsX + r*SRK + c) = *(const short8*)(src + (size_t)toks[r]*128 + c);
  }
  __syncthreads();
  gemm64x128_regs(tid, ldsX, pUg, stage, acc);
  {
    ushort_t* dst = shm ? t1S : (t1R + (size_t)base*128);
    #pragma unroll
    for (int h = 0; h < 2; ++h)
      #pragma unroll
      for (int i = 0; i < 2; ++i)
        #pragma unroll
        for (int r = 0; r < 4; ++r) {
          int gs = s0 + mh*32 + i*16 + q*4 + r;
          if (gs < nrows) {
            #pragma unroll
            for (int j = 0; j < 2; ++j)
              dst[(size_t)gs*128 + h*64 + nh*32 + j*16 + ln] = f2b(acc[h][i][j][r]);
          }
        }
  }
  // t2
  for (int li = tid; li < 64*16; li += 256) {
    int r = li >> 4, c = (li & 15) << 3;
    const ushort_t* src = shm ? sub : rub;
    *(short8*)(ldsX + r*SRK + c) = *(const short8*)(src + (size_t)toks[r]*128 + c);
  }
  __syncthreads();
  gemm64x128_regs(tid, ldsX, pUu, stage, acc);
  {
    ushort_t* dst = shm ? t2S : (t2R + (size_t)base*128);
    #pragma unroll
    for (int h = 0; h < 2; ++h)
      #pragma unroll
      for (int i = 0; i < 2; ++i)
        #pragma unroll
        for (int r = 0; r < 4; ++r) {
          int gs = s0 + mh*32 + i*16 + q*4 + r;
          if (gs < nrows) {
            #pragma unroll
            for (int j = 0; j < 2; ++j)
              dst[(size_t)gs*128 + h*64 + nh*32 + j*16 + ln] = f2b(acc[h][i][j][r]);
          }
        }
  }
}

// ---------------------------------------------------------------- mid (v9: static grid-stride items)
// 512 persistent blocks, 80KB LDS. v8's dynamic queue (atomicAdd + global
// broadcast + 2 barriers/item) replaced by a STATIC stride walk: block b
// (xc=b&7) takes items wi = b>>3, b>>3+64, ... of its XCD list. Lists are
// balanced by construction (experts e%8==x, ~96 items/XCD). One barrier at
// item top is sufficient: prior item's last LDS reads (epilogue ldsH) complete
// there; new ldsH writes occur only after the tile-0 staging barrier.
__global__ __launch_bounds__(256, 1) void mid_kernel(
    const ushort_t* __restrict__ t1R, const ushort_t* __restrict__ t2R,
    const ushort_t* __restrict__ t1S, const ushort_t* __restrict__ t2S,
    const ushort_t* __restrict__ Cg, const ushort_t* __restrict__ Cu,
    const ushort_t* __restrict__ Rd,
    const ushort_t* __restrict__ sCg, const ushort_t* __restrict__ sCu,
    const ushort_t* __restrict__ sRd,
    const int* __restrict__ offA, const int* __restrict__ cntA,
    float* __restrict__ rdRp, float* __restrict__ rdSp,
    const int* __restrict__ wn, const int* __restrict__ wl)
{
  __shared__ ushort_t ldsCg[2][64*128];   // 32 KB
  __shared__ ushort_t ldsCu[2][64*128];   // 32 KB
  __shared__ ushort_t ldsH [2][64*64];    // 16 KB  -> 80 KB exactly

  const int tid = threadIdx.x;
  const int lane = tid & 63, ln = lane & 15, q = lane >> 4;
  const int wv = tid >> 6, mh = wv >> 1, nh = wv & 1;
  const int xc = blockIdx.x & 7;
  const int nww = wn[xc];

  for (int wi = blockIdx.x >> 3; wi < nww; wi += 64) {
    __syncthreads();                       // prior item's LDS reads done
    const int item = wl[xc*WLCAP + wi];
    const int by = item >> 16, bz = (item >> 12) & 15, bx = item & 4095;

    const bool shm = (by == NEXP);
    const int nrows = shm ? T_TOK : cntA[by];
    const int s0 = bx * 64;
    const int base = shm ? 0 : offA[by];
    const int Ifull = shm ? ISH : IR;
    const ushort_t* pCg = shm ? sCg : Cg + (size_t)by*IR*128;
    const ushort_t* pCu = shm ? sCu : Cu + (size_t)by*IR*128;
    const ushort_t* pRd = shm ? sRd : Rd;
    const int it0 = bz * MTILES;

    // t1/t2 A-fragments -> registers (held across the K loop)
    short8 t1f[2][4], t2f[2][4];
    const ushort_t* srcT1 = shm ? t1S : (t1R + (size_t)base*128);
    const ushort_t* srcT2 = shm ? t2S : (t2R + (size_t)base*128);
    #pragma unroll
    for (int i = 0; i < 2; ++i) {
      int r = s0 + mh*32 + i*16 + ln; if (r > nrows-1) r = nrows-1;
      #pragma unroll
      for (int c = 0; c < 4; ++c) {
        t1f[i][c] = *(const short8*)(srcT1 + (size_t)r*128 + c*32 + q*8);
        t2f[i][c] = *(const short8*)(srcT2 + (size_t)r*128 + c*32 + q*8);
      }
    }

    load_64x128_swz(pCg + (size_t)it0*64*128, 128, ldsCg[0], tid);
    load_64x128_swz(pCu + (size_t)it0*64*128, 128, ldsCu[0], tid);

    f32x4 rdacc[2][4];
    #pragma unroll
    for (int i = 0; i < 2; ++i)
      #pragma unroll
      for (int j = 0; j < 4; ++j) rdacc[i][j] = (f32x4){0.f,0.f,0.f,0.f};

    const size_t rdRow = (size_t)(nh*64 + ln)*Ifull + q*8;  // + j*16*Ifull + i0 + c2*32

    __syncthreads();   // tile 0 staged

    for (int it = 0; it < MTILES; ++it) {
      const int i0 = (it0 + it) * 64;
      const int cb = it & 1;
      // 1. preload Rd B-frags for phaseB(it-1) FIRST (vmcnt in-order: waiting
      //    for these must not force the gll prefetch issued after them)
      short8 rb[2][4];
      if (it > 0) {
        const int ip = i0 - 64;
        #pragma unroll
        for (int c2 = 0; c2 < 2; ++c2)
          #pragma unroll
          for (int j = 0; j < 4; ++j)
            rb[c2][j] = *(const short8*)(pRd + rdRow + (size_t)(j*16)*Ifull + ip + c2*32);
      }
      // 2. prefetch Cg/Cu(it+1) into the idle buffers (drains at THIS barrier)
      if (it+1 < MTILES) {
        load_64x128_swz(pCg + (size_t)(i0+64)*128, 128, ldsCg[cb^1], tid);
        load_64x128_swz(pCu + (size_t)(i0+64)*128, 128, ldsCu[cb^1], tid);
      }
      // 3. phaseA(it): g,u from regs x ldsCg/Cu[cb]; silu; h -> ldsH[cb]
      f32x4 g[2][2], u[2][2];
      #pragma unroll
      for (int i = 0; i < 2; ++i)
        #pragma unroll
        for (int j = 0; j < 2; ++j) { g[i][j] = (f32x4){0.f,0.f,0.f,0.f}; u[i][j] = (f32x4){0.f,0.f,0.f,0.f}; }
      #pragma unroll
      for (int c = 0; c < 4; ++c) {
        #pragma unroll
        for (int j = 0; j < 2; ++j) {
          int rr = nh*32 + j*16 + ln;
          int off = rr*128 + (((c*4+q) ^ (rr&15)) << 3);
          short8 bg = *(const short8*)(ldsCg[cb] + off);
          short8 bu = *(const short8*)(ldsCu[cb] + off);
          #pragma unroll
          for (int i = 0; i < 2; ++i) {
            g[i][j] = MF(t1f[i][c], bg, g[i][j]);
            u[i][j] = MF(t2f[i][c], bu, u[i][j]);
          }
        }
      }
      #pragma unroll
      for (int i = 0; i < 2; ++i)
        #pragma unroll
        for (int j = 0; j < 2; ++j) {
          float hv[4];
          #pragma unroll
          for (int r = 0; r < 4; ++r) {
            float gv = g[i][j][r];
            hv[r] = gv * fast_rcp(1.f + __expf(-gv)) * u[i][j][r];
          }
          unsigned p01 = cvt_pk_bf16(hv[0], hv[1]);
          unsigned p23 = cvt_pk_bf16(hv[2], hv[3]);
          const int hc = nh*32 + j*16 + ln;
          const int hb = mh*32 + i*16 + q*4;
          #pragma unroll
          for (int r = 0; r < 4; ++r) {
            int hr = hb + r;
            ushort_t v = (r==0) ? (ushort_t)p01 : (r==1) ? (ushort_t)(p01>>16)
                       : (r==2) ? (ushort_t)p23 : (ushort_t)(p23>>16);
            ldsH[cb][hr*64 + (((hc>>3) ^ (hr&7)) << 3) + (hc&7)] = v;
          }
        }
      // 4. phaseB(it-1): rd += h[cb^1] @ Rd (h written last iter, barrier'd)
      if (it > 0) {
        #pragma unroll
        for (int c2 = 0; c2 < 2; ++c2) {
          short8 a[2];
          #pragma unroll
          for (int i = 0; i < 2; ++i) {
            int rr = mh*32 + i*16 + ln;
            a[i] = *(const short8*)(ldsH[cb^1] + rr*64 + (((c2*4+q) ^ (rr&7)) << 3));
          }
          #pragma unroll
          for (int j = 0; j < 4; ++j)
            #pragma unroll
            for (int i = 0; i < 2; ++i) rdacc[i][j] = MF(a[i], rb[c2][j], rdacc[i][j]);
        }
      }
      __syncthreads();   // ONE barrier/iter: h[cb] visible next iter; gll(it+1) landed
    }
    // epilogue: phaseB(MTILES-1)
    {
      const int ip = (it0 + MTILES - 1) * 64;
      const int cb = (MTILES - 1) & 1;
      #pragma unroll
      for (int c2 = 0; c2 < 2; ++c2) {
        short8 a[2];
        #pragma unroll
        for (int i = 0; i < 2; ++i) {
          int rr = mh*32 + i*16 + ln;
          a[i] = *(const short8*)(ldsH[cb] + rr*64 + (((c2*4+q) ^ (rr&7)) << 3));
        }
        #pragma unroll
        for (int j = 0; j < 4; ++j) {
          short8 b = *(const short8*)(pRd + rdRow + (size_t)(j*16)*Ifull + ip + c2*32);
          #pragma unroll
          for (int i = 0; i < 2; ++i) rdacc[i][j] = MF(a[i], b, rdacc[i][j]);
        }
      }
    }

    // plain disjoint stores (no atomics): part bz of 2 (routed) or 4 (shared)
    float* dst = shm ? (rdSp + (size_t)bz*T_TOK*128)
                     : (rdRp + (size_t)bz*NPAIR*128 + (size_t)base*128);
    #pragma unroll
    for (int i = 0; i < 2; ++i) {
      #pragma unroll
      for (int r = 0; r < 4; ++r) {
        int gs = s0 + mh*32 + i*16 + q*4 + r;
        if (gs < nrows) {
          #pragma unroll
          for (int j = 0; j < 4; ++j)
            dst[(size_t)gs*128 + nh*64 + j*16 + ln] = rdacc[i][j][r];
        }
      }
    }
  }
}

// ---------------------------------------------------------------- out
// grid (64, 33, 2). t3 frags in regs; Cd double-buffered via gll; 1 barrier/tile.
// LDS diet (kept): ldsT ALIASES ldsA -> smem 34.8 KB -> 4 blocks/CU.
// Balanced expert-clustered XCD map. NO atomics: routed y -> ybufR (bf16,
// per-slot, unweighted); shared y -> out directly (fp32 plain stores).
__global__ __launch_bounds__(256) void out_kernel(
    const float* __restrict__ rdRp, const float* __restrict__ rdSp,
    const ushort_t* __restrict__ Ud, const ushort_t* __restrict__ Cd,
    const ushort_t* __restrict__ sUd, const ushort_t* __restrict__ sCd,
    const int* __restrict__ offA, const int* __restrict__ cntA,
    ushort_t* __restrict__ ybufR, float* __restrict__ out)
{
  __shared__ ushort_t smem[2*64*SRK];   // prologue: ldsA(=ldsT) | stage ; loop: cd0,cd1
  ushort_t* ldsA  = smem;
  ushort_t* stage = smem + 64*SRK;
  ushort_t* ldsT  = smem;               // aliases ldsA (safe: see header comment)
  ushort_t* cd0   = smem;
  ushort_t* cd1   = smem + 64*128;

  // balanced XCD map (4224 blocks, 528 per XCD):
  //   routed m<512: by=(m>>7)*8+x, bzz=(m>>6)&1, bx=m&63
  //   shared m>=512: by=32, bzz=(m-512)>>3, bx=((m-512)&7)*8+x
  const int hh = blockIdx.x + 64*(blockIdx.y + 33*blockIdx.z);
  const int xc = hh & 7, m = hh >> 3;
  int bx, by, bzz;
  if (m < 512) { by = (m >> 7)*8 + xc; bzz = (m >> 6) & 1; bx = m & 63; }
  else         { int mm = m - 512; by = NEXP; bzz = mm >> 3; bx = ((mm & 7) << 3) + xc; }

  const int tid = threadIdx.x;
  const bool shm = (by == NEXP);
  const int nrows = shm ? T_TOK : cntA[by];
  const int s0 = bx * 64;
  if (s0 >= nrows) return;
  const int base = shm ? 0 : offA[by];
  const int ct0 = bzz * 16;
  const ushort_t* pUd = shm ? sUd : Ud + (size_t)by*128*128;
  const ushort_t* pCd = shm ? sCd : Cd + (size_t)by*HD*128;

  const int lane = tid & 63, ln = lane & 15, q = lane >> 4;
  const int wv = tid >> 6, mh = wv >> 1, nh = wv & 1;

  // gather rd rows: sum the per-bz partials (fp32) -> bf16 ldsA
  for (int li = tid; li < 64*32; li += 256) {
    int r = li >> 5, c4 = li & 31;
    int row = s0 + r; if (row > nrows-1) row = nrows-1;
    float4 v;
    if (shm) {
      const float* p = rdSp + (size_t)row*128 + c4*4;
      v = *(const float4*)p;
      #pragma unroll
      for (int pp = 1; pp < 4; ++pp) {
        float4 w2 = *(const float4*)(p + (size_t)pp*T_TOK*128);
        v.x += w2.x; v.y += w2.y; v.z += w2.z; v.w += w2.w;
      }
    } else {
      const float* p = rdRp + (size_t)(base+row)*128 + c4*4;
      v = *(const float4*)p;
      float4 w2 = *(const float4*)(p + (size_t)NPAIR*128);
      v.x += w2.x; v.y += w2.y; v.z += w2.z; v.w += w2.w;
    }
    ushort4 o; o.x=f2b(v.x); o.y=f2b(v.y); o.z=f2b(v.z); o.w=f2b(v.w);
    *(ushort4*)(ldsA + r*SRK + c4*4) = o;
  }
  __syncthreads();

  f32x4 acc[2][2][2];
  gemm64x128_regs(tid, ldsA, pUd, stage, acc);
  // C -> ldsT (= ldsA; all A-reads done at gemm's last barrier), then extract A-frags
  #pragma unroll
  for (int h = 0; h < 2; ++h)
    #pragma unroll
    for (int i = 0; i < 2; ++i)
      #pragma unroll
      for (int j = 0; j < 2; ++j)
        #pragma unroll
        for (int r = 0; r < 4; ++r)
          ldsT[(mh*32 + i*16 + q*4 + r)*SRK + h*64 + nh*32 + j*16 + ln] = f2b(acc[h][i][j][r]);
  __syncthreads();
  short8 t3f[2][4];
  #pragma unroll
  for (int i = 0; i < 2; ++i)
    #pragma unroll
    for (int c = 0; c < 4; ++c)
      t3f[i][c] = *(const short8*)(ldsT + (mh*32 + i*16 + ln)*SRK + c*32 + q*8);
  __syncthreads();   // smem free for cd buffers

  load_64x128_swz(pCd + (size_t)ct0*64*128, 128, cd0, tid);
  for (int tt = 0; tt < 16; ++tt) {
    __syncthreads();                      // cd[tt&1] ready; prior reads drained
    ushort_t* cur = (tt & 1) ? cd1 : cd0;
    ushort_t* nxt = (tt & 1) ? cd0 : cd1;
    if (tt+1 < 16)
      load_64x128_swz(pCd + (size_t)(ct0+tt+1)*64*128, 128, nxt, tid);
    f32x4 y[2][2];
    #pragma unroll
    for (int i = 0; i < 2; ++i)
      #pragma unroll
      for (int j = 0; j < 2; ++j) y[i][j] = (f32x4){0.f,0.f,0.f,0.f};
    #pragma unroll
    for (int c = 0; c < 4; ++c) {
      #pragma unroll
      for (int j = 0; j < 2; ++j) {
        int rr = nh*32 + j*16 + ln;
        short8 b = *(const short8*)(cur + rr*128 + (((c*4+q) ^ (rr&15)) << 3));
        #pragma unroll
        for (int i = 0; i < 2; ++i) y[i][j] = MF(t3f[i][c], b, y[i][j]);
      }
    }
    #pragma unroll
    for (int i = 0; i < 2; ++i) {
      #pragma unroll
      for (int r = 0; r < 4; ++r) {
        int lr = mh*32 + i*16 + q*4 + r;
        int gs = s0 + lr;
        if (gs < nrows) {
          if (shm) {
            size_t ob = (size_t)gs*HD + (ct0 + tt)*64;
            #pragma unroll
            for (int j = 0; j < 2; ++j)
              out[ob + nh*32 + j*16 + ln] = y[i][j][r];
          } else {
            size_t ob = (size_t)(base + gs)*HD + (ct0 + tt)*64;
            #pragma unroll
            for (int j = 0; j < 2; ++j)
              ybufR[ob + nh*32 + j*16 + ln] = f2b(y[i][j][r]);
          }
        }
      }
    }
  }
}

// ---------------------------------------------------------------- combine
// out[t] = out[t] (shared, already stored) + sum_k w_k * ybufR[slot_of[t,k]]
// One block per token row; fully coalesced, no atomics.
__global__ __launch_bounds__(256) void combine_kernel(
    const ushort_t* __restrict__ ybufR,
    const int* __restrict__ slot_of, const float* __restrict__ topk_w,
    float* __restrict__ out)
{
  __shared__ int   ss[4];
  __shared__ float ww[4];
  const int t = blockIdx.x;
  if (threadIdx.x < 4) {
    ss[threadIdx.x] = slot_of[t*4 + threadIdx.x];
    ww[threadIdx.x] = topk_w[t*4 + threadIdx.x];
  }
  __syncthreads();
  const int c = threadIdx.x * 8;
  const size_t tb = (size_t)t*HD + c;
  float o[8];
  float4 a0 = *(const float4*)(out + tb);
  float4 a1 = *(const float4*)(out + tb + 4);
  o[0]=a0.x; o[1]=a0.y; o[2]=a0.z; o[3]=a0.w;
  o[4]=a1.x; o[5]=a1.y; o[6]=a1.z; o[7]=a1.w;
  #pragma unroll
  for (int k = 0; k < 4; ++k) {
    short8 rv = *(const short8*)(ybufR + (size_t)ss[k]*HD + c);
    float wk = ww[k];
    #pragma unroll
    for (int u = 0; u < 8; ++u)
      o[u] += wk * b2f((ushort_t)rv[u]);
  }
  float4 b0 = {o[0],o[1],o[2],o[3]};
  float4 b1 = {o[4],o[5],o[6],o[7]};
  *(float4*)(out + tb)     = b0;
  *(float4*)(out + tb + 4) = b1;
}

// ---------------------------------------------------------------- launch
extern "C" void kernel_launch(void* const* d_in, const int* in_sizes, int n_in,
                              void* d_out, int out_size, void* d_ws, size_t ws_size,
                              hipStream_t stream) {
  const float* x    = (const float*)d_in[0];
  const float* gw   = (const float*)d_in[1];
  const float* Rg   = (const float*)d_in[2];
  const float* Ru   = (const float*)d_in[3];
  const float* Rd   = (const float*)d_in[4];
  const float* Ug   = (const float*)d_in[5];
  const float* Cg   = (const float*)d_in[6];
  const float* Uu   = (const float*)d_in[7];
  const float* Cu   = (const float*)d_in[8];
  const float* Ud   = (const float*)d_in[9];
  const float* Cd   = (const float*)d_in[10];
  const float* sRg  = (const float*)d_in[11];
  const float* sUg  = (const float*)d_in[12];
  const float* sCg  = (const float*)d_in[13];
  const float* sRu  = (const float*)d_in[14];
  const float* sUu  = (const float*)d_in[15];
  const float* sCu  = (const float*)d_in[16];
  const float* sRd  = (const float*)d_in[17];
  const float* sUd  = (const float*)d_in[18];
  const float* sCd  = (const float*)d_in[19];
  float* out = (float*)d_out;

  char* w = (char*)d_ws;
  auto alloc = [&](size_t bytes) -> void* {
    void* p = (void*)w; w += (bytes + 255) & ~(size_t)255; return p;
  };
  int*   cnt      = (int*)  alloc(NEXP*sizeof(int));
  int*   offA     = (int*)  alloc((NEXP+1)*sizeof(int));
  int*   fill     = (int*)  alloc(NEXP*sizeof(int));
  int*   topk_idx = (int*)  alloc((size_t)T_TOK*4*sizeof(int));
  float* topk_w   = (float*)alloc((size_t)T_TOK*4*sizeof(float));
  int*   list_tok = (int*)  alloc((size_t)NPAIR*sizeof(int));
  int*   slot_of  = (int*)  alloc((size_t)T_TOK*4*sizeof(int));
  int*   wn       = (int*)  alloc(8*sizeof(int));
  int*   wl       = (int*)  alloc((size_t)8*WLCAP*sizeof(int));
  ushort_t* xb   = (ushort_t*)alloc((size_t)T_TOK*HD*2);   // later reused as rdRp (fp32, 2 parts)
  ushort_t* Rgb  = (ushort_t*)alloc((size_t)128*HD*2);
  ushort_t* Rub  = (ushort_t*)alloc((size_t)128*HD*2);
  ushort_t* Rdb  = (ushort_t*)alloc((size_t)128*IR*2);
  ushort_t* Ugb  = (ushort_t*)alloc((size_t)NEXP*128*128*2);
  ushort_t* Cgb  = (ushort_t*)alloc((size_t)NEXP*IR*128*2);
  ushort_t* Uub  = (ushort_t*)alloc((size_t)NEXP*128*128*2);
  ushort_t* Cub  = (ushort_t*)alloc((size_t)NEXP*IR*128*2);
  ushort_t* Udb  = (ushort_t*)alloc((size_t)NEXP*128*128*2);
  ushort_t* Cdb  = (ushort_t*)alloc((size_t)NEXP*HD*128*2);
  ushort_t* sRgb = (ushort_t*)alloc((size_t)128*HD*2);
  ushort_t* sUgb = (ushort_t*)alloc((size_t)128*128*2);
  ushort_t* sCgb = (ushort_t*)alloc((size_t)ISH*128*2);
  ushort_t* sRub = (ushort_t*)alloc((size_t)128*HD*2);
  ushort_t* sUub = (ushort_t*)alloc((size_t)128*128*2);
  ushort_t* sCub = (ushort_t*)alloc((size_t)ISH*128*2);
  ushort_t* sRdb = (ushort_t*)alloc((size_t)128*ISH*2);
  ushort_t* sUdb = (ushort_t*)alloc((size_t)128*128*2);
  ushort_t* sCdb = (ushort_t*)alloc((size_t)HD*128*2);
  ushort_t* rg   = (ushort_t*)alloc((size_t)T_TOK*128*2);
  ushort_t* ru   = (ushort_t*)alloc((size_t)T_TOK*128*2);
  ushort_t* sa   = (ushort_t*)alloc((size_t)T_TOK*128*2);
  ushort_t* su   = (ushort_t*)alloc((size_t)T_TOK*128*2);
  ushort_t* t1R  = (ushort_t*)alloc((size_t)NPAIR*128*2);
  ushort_t* t2R  = (ushort_t*)alloc((size_t)NPAIR*128*2);
  ushort_t* t1S  = (ushort_t*)alloc((size_t)T_TOK*128*2);
  ushort_t* t2S  = (ushort_t*)alloc((size_t)T_TOK*128*2);
  float*    rdSp = (float*)   alloc((size_t)4*T_TOK*128*sizeof(float));  // 4 shared partials
  ushort_t* ybufR= (ushort_t*)alloc((size_t)NPAIR*HD*2);                 // per-slot routed y (bf16)
  (void)ws_size; (void)in_sizes; (void)n_in;

  // routed rd partials (fp32, 2 parts) alias xb exactly:
  // 2*NPAIR*128*4 = 16.78 MB == T_TOK*HD*2. xb is dead after rproj; mid writes it after.
  float* rdRp = (float*)xb;

  hipMemsetAsync(cnt,  0, NEXP*sizeof(int), stream);
  hipMemsetAsync(fill, 0, NEXP*sizeof(int), stream);
  // no out memset: out_kernel's shared path fully writes out; combine RMWs it.

  // fused cvt
  CvtSegs cs;
  const float* ss[NSEG] = {x,Rg,Ru,Rd,Ug,Cg,Uu,Cu,Ud,Cd,sRg,sUg,sCg,sRu,sUu,sCu,sRd,sUd,sCd};
  ushort_t* dd[NSEG] = {xb,Rgb,Rub,Rdb,Ugb,Cgb,Uub,Cub,Udb,Cdb,sRgb,sUgb,sCgb,sRub,sUub,sCub,sRdb,sUdb,sCdb};
  size_t nn[NSEG] = {(size_t)T_TOK*HD,(size_t)128*HD,(size_t)128*HD,(size_t)128*IR,
                     (size_t)NEXP*128*128,(size_t)NEXP*IR*128,(size_t)NEXP*128*128,(size_t)NEXP*IR*128,
                     (size_t)NEXP*128*128,(size_t)NEXP*HD*128,(size_t)128*HD,(size_t)128*128,
                     (size_t)ISH*128,(size_t)128*HD,(size_t)128*128,(size_t)ISH*128,
                     (size_t)128*ISH,(size_t)128*128,(size_t)HD*128};
  int tot_blk = 0;
  for (int k = 0; k < NSEG; ++k) {
    cs.s[k] = ss[k]; cs.d[k] = dd[k];
    cs.n4[k] = (int)(nn[k] >> 2);
    cs.blk0[k] = tot_blk;
    tot_blk += (cs.n4[k] + 255) / 256;
  }
  cs.blk0[NSEG] = tot_blk;
  cvt_all_kernel<<<tot_blk, 256, 0, stream>>>(cs);

  gate_kernel<<<T_TOK/4, 256, 0, stream>>>(x, gw, topk_idx, topk_w, cnt);
  scan_kernel<<<1, 64, 0, stream>>>(cnt, offA);
  plan_kernel<<<1, 256, 0, stream>>>(cnt, wn, wl);
  scatter_kernel<<<T_TOK/256, 256, 0, stream>>>(topk_idx, topk_w, offA, fill, list_tok, slot_of);
  rproj_kernel<<<dim3(T_TOK/64, 4), 256, 0, stream>>>(xb, Rgb, Rub, sRgb, sRub, rg, ru, sa, su);
  pair_proj_kernel<<<dim3(64, NEXP+1), 256, 0, stream>>>(
      rg, ru, sa, su, Ugb, Uub, sUgb, sUub, offA, cnt, list_tok, t1R, t2R, t1S, t2S);
  mid_kernel<<<512, 256, 0, stream>>>(
      t1R, t2R, t1S, t2S, Cgb, Cub, Rdb, sCgb, sCub, sRdb, offA, cnt, rdRp, rdSp,
      wn, wl);
  out_kernel<<<dim3(64, 33, 2), 256, 0, stream>>>(
      rdRp, rdSp, Udb, Cdb, sUdb, sCdb, offA, cnt, ybufR, out);
  combine_kernel<<<T_TOK, 256, 0, stream>>>(ybufR, slot_of, topk_w, out);
}